// Round 4
// baseline (938.987 us; speedup 1.0000x reference)
//
#include <hip/hip_runtime.h>
#include <hip/hip_bf16.h>

#define N_NODES 50000
#define N_EDGES 3200000

typedef __bf16 v8bf __attribute__((ext_vector_type(8)));
typedef float v4f __attribute__((ext_vector_type(4)));
typedef unsigned short u16x8 __attribute__((ext_vector_type(8)));

__device__ __forceinline__ float elu_f(float x) { return x > 0.f ? x : (expf(x) - 1.f); }

// ---------------- fused maxpool(2) + LayerNorm(1024) -> bf16 ----------------
__global__ void pool_ln_kernel(const float* __restrict__ x,
                               const float* __restrict__ ln_w,
                               const float* __restrict__ ln_b,
                               __bf16* __restrict__ h0) {
    int node = blockIdx.x;
    int t = threadIdx.x;
    const float4* xr = (const float4*)(x + (size_t)node * 2048);
    float4 a = xr[t];
    float4 b = xr[t + 256];
    float p0 = fmaxf(a.x, a.y), p1 = fmaxf(a.z, a.w);
    float p2 = fmaxf(b.x, b.y), p3 = fmaxf(b.z, b.w);
    float sum = p0 + p1 + p2 + p3;
    float sq  = p0*p0 + p1*p1 + p2*p2 + p3*p3;
    #pragma unroll
    for (int off = 32; off > 0; off >>= 1) {
        sum += __shfl_down(sum, off);
        sq  += __shfl_down(sq, off);
    }
    __shared__ float red_s[4], red_q[4];
    __shared__ float s_mu, s_rstd;
    int wave = t >> 6, lane = t & 63;
    if (lane == 0) { red_s[wave] = sum; red_q[wave] = sq; }
    __syncthreads();
    if (t == 0) {
        float S = red_s[0] + red_s[1] + red_s[2] + red_s[3];
        float Q = red_q[0] + red_q[1] + red_q[2] + red_q[3];
        float mu = S * (1.f / 1024.f);
        float var = Q * (1.f / 1024.f) - mu * mu;
        s_mu = mu;
        s_rstd = rsqrtf(var + 1e-5f);
    }
    __syncthreads();
    float mu = s_mu, rstd = s_rstd;
    __bf16* out = h0 + (size_t)node * 1024;
    int i0 = 2 * t;
    int i1 = 512 + 2 * t;
    out[i0]     = (__bf16)((p0 - mu) * rstd * ln_w[i0]     + ln_b[i0]);
    out[i0 + 1] = (__bf16)((p1 - mu) * rstd * ln_w[i0 + 1] + ln_b[i0 + 1]);
    out[i1]     = (__bf16)((p2 - mu) * rstd * ln_w[i1]     + ln_b[i1]);
    out[i1 + 1] = (__bf16)((p3 - mu) * rstd * ln_w[i1 + 1] + ln_b[i1 + 1]);
}

// ---------------- W[K][N] fp32 -> WT[N][K] bf16 ----------------
__global__ void wt_kernel(const float* __restrict__ W, __bf16* __restrict__ WT,
                          int K, int N) {
    int idx = blockIdx.x * 256 + threadIdx.x;
    if (idx < K * N) {
        int k = idx / N, n = idx - k * N;
        WT[(size_t)n * K + k] = (__bf16)W[idx];
    }
}

// ---------------- bf16 MFMA GEMM (128x128 tile, BK=32, reg-staged LDS) ------
__global__ __launch_bounds__(256) void mfma_gemm(
    const __bf16* __restrict__ A, const __bf16* __restrict__ BT,
    const float* __restrict__ bias, void* __restrict__ C,
    int M, int N, int K, int do_elu, int out_bf16)
{
    __shared__ unsigned short lds[2 * 128 * 40];
    const int tid  = threadIdx.x;
    const int lane = tid & 63, wave = tid >> 6;
    const int wr = wave >> 1, wc = wave & 1;
    const int m0 = blockIdx.x * 128, n0 = blockIdx.y * 128;

    size_t offA[2], offB[2];
    int dstA[2], dstB[2];
    #pragma unroll
    for (int i = 0; i < 2; ++i) {
        int s = tid + i * 256;
        int r = s >> 2, ks = s & 3;
        int gr = m0 + r; if (gr > M - 1) gr = M - 1;
        offA[i] = (size_t)gr * K + ks * 8;
        dstA[i] = r * 40 + ks * 8;
        int gc = n0 + r; if (gc > N - 1) gc = N - 1;
        offB[i] = (size_t)gc * K + ks * 8;
        dstB[i] = 5120 + r * 40 + ks * 8;
    }

    v4f acc[4][4] = {};
    const int l15 = lane & 15, l4 = lane >> 4;
    const int abase = (wr * 64 + l15) * 40 + l4 * 8;
    const int bbase = 5120 + (wc * 64 + l15) * 40 + l4 * 8;

    u16x8 sa0 = *(const u16x8*)(A + offA[0]);
    u16x8 sa1 = *(const u16x8*)(A + offA[1]);
    u16x8 sb0 = *(const u16x8*)(BT + offB[0]);
    u16x8 sb1 = *(const u16x8*)(BT + offB[1]);

    for (int k0 = 0; k0 < K; k0 += 32) {
        __syncthreads();
        *(u16x8*)&lds[dstA[0]] = sa0;
        *(u16x8*)&lds[dstA[1]] = sa1;
        *(u16x8*)&lds[dstB[0]] = sb0;
        *(u16x8*)&lds[dstB[1]] = sb1;
        if (k0 + 32 < K) {
            sa0 = *(const u16x8*)(A + offA[0] + k0 + 32);
            sa1 = *(const u16x8*)(A + offA[1] + k0 + 32);
            sb0 = *(const u16x8*)(BT + offB[0] + k0 + 32);
            sb1 = *(const u16x8*)(BT + offB[1] + k0 + 32);
        }
        __syncthreads();
        v8bf af[4], bfr[4];
        #pragma unroll
        for (int m = 0; m < 4; ++m) af[m]  = *(const v8bf*)&lds[abase + m * 16 * 40];
        #pragma unroll
        for (int n = 0; n < 4; ++n) bfr[n] = *(const v8bf*)&lds[bbase + n * 16 * 40];
        #pragma unroll
        for (int m = 0; m < 4; ++m)
            #pragma unroll
            for (int n = 0; n < 4; ++n)
                acc[m][n] = __builtin_amdgcn_mfma_f32_16x16x32_bf16(af[m], bfr[n], acc[m][n], 0, 0, 0);
    }

    #pragma unroll
    for (int m = 0; m < 4; ++m) {
        #pragma unroll
        for (int j = 0; j < 4; ++j) {
            int row = m0 + wr * 64 + m * 16 + l4 * 4 + j;
            if (row >= M) continue;
            #pragma unroll
            for (int n = 0; n < 4; ++n) {
                int col = n0 + wc * 64 + n * 16 + l15;
                if (col >= N) continue;
                float v = acc[m][n][j] + bias[col];
                if (do_elu) v = elu_f(v);
                if (out_bf16) ((__bf16*)C)[(size_t)row * N + col] = (__bf16)v;
                else          ((float*)C)[(size_t)row * N + col] = v;
            }
        }
    }
}

// ---------------- small fp32 GEMM, epilogue: v = (acc [+bias]) [*scale[m]] ---
__global__ void gemm_kernel(const float* __restrict__ A, const float* __restrict__ W,
                            const float* __restrict__ bias, const float* __restrict__ scale,
                            float* __restrict__ C, int M, int N, int K, int do_elu) {
    const int BM = 64, BN = 64, BK = 16;
    __shared__ float As[BK][BM + 4];
    __shared__ float Ws[BK][BN + 4];
    int tid = threadIdx.x;
    int tx = tid & 15, ty = tid >> 4;
    int m0 = blockIdx.x * BM;
    int n0 = blockIdx.y * BN;
    float acc[4][4] = {};
    for (int k0 = 0; k0 < K; k0 += BK) {
        #pragma unroll
        for (int l = 0; l < 4; ++l) {
            int idx = tid + l * 256;
            int r = idx >> 4, c = idx & 15;
            int m = m0 + r;
            As[c][r] = (m < M) ? A[(size_t)m * K + k0 + c] : 0.f;
        }
        #pragma unroll
        for (int l = 0; l < 4; ++l) {
            int idx = tid + l * 256;
            int c = idx >> 6, n = idx & 63;
            int nn = n0 + n;
            Ws[c][n] = (nn < N) ? W[(size_t)(k0 + c) * N + nn] : 0.f;
        }
        __syncthreads();
        #pragma unroll
        for (int kk = 0; kk < BK; ++kk) {
            float4 av = *(const float4*)&As[kk][ty * 4];
            float4 wv = *(const float4*)&Ws[kk][tx * 4];
            float ar[4] = {av.x, av.y, av.z, av.w};
            float wrg[4] = {wv.x, wv.y, wv.z, wv.w};
            #pragma unroll
            for (int i = 0; i < 4; ++i)
                #pragma unroll
                for (int j = 0; j < 4; ++j)
                    acc[i][j] += ar[i] * wrg[j];
        }
        __syncthreads();
    }
    #pragma unroll
    for (int i = 0; i < 4; ++i) {
        int m = m0 + ty * 4 + i;
        if (m >= M) continue;
        float sc = scale ? scale[m] : 1.f;
        #pragma unroll
        for (int j = 0; j < 4; ++j) {
            int n = n0 + tx * 4 + j;
            if (n >= N) continue;
            float v = acc[i][j] + (bias ? bias[n] : 0.f);
            if (do_elu) v = elu_f(v);
            C[(size_t)m * N + n] = v * sc;
        }
    }
}

// ---------------- CSR build ----------------
__global__ void zero_cnt_kernel(int* __restrict__ cnt) {
    int i = blockIdx.x * 256 + threadIdx.x;
    if (i < N_NODES) cnt[i] = 0;
}
__global__ void cnt_kernel(const int* __restrict__ col, int* __restrict__ cnt) {
    int e = blockIdx.x * 256 + threadIdx.x;
    if (e < N_EDGES) atomicAdd(&cnt[col[e]], 1);
}
// per-block exclusive scan (512 elems/block), Hillis-Steele in LDS
__global__ void scan_a_kernel(const int* __restrict__ cnt, int* __restrict__ pp,
                              int* __restrict__ bs) {
    __shared__ int s[512];
    int t = threadIdx.x;
    int i = blockIdx.x * 512 + t;
    int v = (i < N_NODES) ? cnt[i] : 0;
    s[t] = v;
    __syncthreads();
    for (int off = 1; off < 512; off <<= 1) {
        int u = (t >= off) ? s[t - off] : 0;
        __syncthreads();
        s[t] += u;
        __syncthreads();
    }
    if (i < N_NODES) pp[i] = s[t] - v;
    if (t == 511) bs[blockIdx.x] = s[511];
}
// scan the 98 block sums (single block)
__global__ void scan_b_kernel(int* __restrict__ bs, int* __restrict__ ptr, int nblk) {
    __shared__ int s[128];
    int t = threadIdx.x;
    int v = (t < nblk) ? bs[t] : 0;
    s[t] = v;
    __syncthreads();
    for (int off = 1; off < 128; off <<= 1) {
        int u = (t >= off) ? s[t - off] : 0;
        __syncthreads();
        s[t] += u;
        __syncthreads();
    }
    if (t < nblk) bs[t] = s[t] - v;
    if (t == 127) ptr[N_NODES] = s[127];
}
// finalize: ptr = fill = pp + blockoffset ; dis = rsqrt(deg+1)
__global__ void scan_c_kernel(const int* __restrict__ pp, const int* __restrict__ bs,
                              const int* __restrict__ cnt, int* __restrict__ ptr,
                              int* __restrict__ fill, float* __restrict__ dis) {
    int i = blockIdx.x * 256 + threadIdx.x;
    if (i < N_NODES) {
        int p = pp[i] + bs[i >> 9];
        ptr[i] = p;
        fill[i] = p;
        dis[i] = rsqrtf((float)(cnt[i] + 1));
    }
}
// csr store via atomicExch: TCC-side 4B write, no 64B line allocate
// (plain store: 196 MB write-through @790 GB/s = 270 us; atomic path ~13 MB)
__global__ void scatter_kernel(const int* __restrict__ row, const int* __restrict__ col,
                               int* __restrict__ fill, int* __restrict__ csr) {
    int e = blockIdx.x * 256 + threadIdx.x;
    if (e < N_EDGES) {
        int pos = atomicAdd(&fill[col[e]], 1);
        atomicExch(&csr[pos], row[e]);
    }
}

// ---------------- CSR gather aggregation ----------------
// thread = (node, feat); xws already scaled by dis[row]; self-loop = own row.
__global__ void gather_kernel(const float* __restrict__ xws, const int* __restrict__ csr,
                              const int* __restrict__ ptr, const float* __restrict__ dis,
                              const float* __restrict__ bias, float* __restrict__ out,
                              int fshift, int do_elu) {
    int idx = blockIdx.x * 256 + threadIdx.x;
    int node = idx >> fshift;
    if (node >= N_NODES) return;
    int f = idx & ((1 << fshift) - 1);
    int s = ptr[node], e = ptr[node + 1];
    float acc = xws[((size_t)node << fshift) + f];  // self-loop (dis[node]*xw[node])
    for (int i = s; i < e; ++i) {
        int r = csr[i];
        acc += xws[((size_t)r << fshift) + f];
    }
    float v = dis[node] * acc + bias[f];
    out[idx] = do_elu ? elu_f(v) : v;
}

extern "C" void kernel_launch(void* const* d_in, const int* in_sizes, int n_in,
                              void* d_out, int out_size, void* d_ws, size_t ws_size,
                              hipStream_t stream) {
    const float* x    = (const float*)d_in[0];
    const int*   ei   = (const int*)d_in[1];
    const int*   row  = ei;
    const int*   col  = ei + N_EDGES;
    const float* ln_w = (const float*)d_in[2];
    const float* ln_b = (const float*)d_in[3];
    const float* w0   = (const float*)d_in[4];
    const float* b0   = (const float*)d_in[5];
    const float* w1   = (const float*)d_in[6];
    const float* b1   = (const float*)d_in[7];
    const float* w2   = (const float*)d_in[8];
    const float* b2   = (const float*)d_in[9];
    const float* g1w  = (const float*)d_in[10];
    const float* g1b  = (const float*)d_in[11];
    const float* g2w  = (const float*)d_in[12];
    const float* g2b  = (const float*)d_in[13];
    float* out = (float*)d_out;

    char* W = (char*)d_ws;
    __bf16* h0  = (__bf16*)(W + 0);          // 50000*1024 bf16 (dead after GEMM0)
    __bf16* h1  = (__bf16*)(W + 102400000);  // 50000*512 bf16
    __bf16* h2  = (__bf16*)(W + 153600000);  // 50000*128 bf16
    float*  h3  = (float*) (W + 166400000);  // 50000*64 f32
    float*  dis = (float*) (W + 179200000);  // 50000 f32
    float*  xw1 = (float*) (W + 179400192);  // 50000*32 f32 (dis-scaled)
    float*  agg1= (float*) (W + 185800192);  // 50000*32 f32
    float*  xw2 = (float*) (W + 192200192);  // 50000*16 f32 (dis-scaled)
    __bf16* w0t = (__bf16*)(W + 195400192);  // 512*1024 bf16
    __bf16* w1t = (__bf16*)(W + 196448768);  // 128*512 bf16
    __bf16* w2t = (__bf16*)(W + 196579840);  // 64*128 bf16
    // CSR structures overlay h0 (written only after GEMM0 consumed h0)
    int*    csr = (int*)(W + 0);             // 3.2M int
    int*    ptr = (int*)(W + 12800000);      // 50001 int
    int*    fill= (int*)(W + 13000064);      // 50000 int
    int*    pp  = (int*)(W + 13200128);      // 50000 int
    int*    bs  = (int*)(W + 13400192);      // 128 int
    int*    cnt = (int*)(W + 13600256);      // 50000 int

    const int NBLK_SCAN = (N_NODES + 511) / 512;  // 98

    // weight transposes (tiny)
    wt_kernel<<<(1024 * 512 + 255) / 256, 256, 0, stream>>>(w0, w0t, 1024, 512);
    wt_kernel<<<(512 * 128 + 255) / 256, 256, 0, stream>>>(w1, w1t, 512, 128);
    wt_kernel<<<(128 * 64 + 255) / 256, 256, 0, stream>>>(w2, w2t, 128, 64);

    // 1. pool + layernorm -> bf16
    pool_ln_kernel<<<N_NODES, 256, 0, stream>>>(x, ln_w, ln_b, h0);

    // 2. GEMM0 (h0 -> h1); h0 dead afterwards
    {
        dim3 g((N_NODES + 127) / 128, 4);
        mfma_gemm<<<g, 256, 0, stream>>>(h0, w0t, b0, h1, N_NODES, 512, 1024, 1, 1);
    }

    // 3. CSR build (overlays h0 region)
    zero_cnt_kernel<<<(N_NODES + 255) / 256, 256, 0, stream>>>(cnt);
    cnt_kernel<<<(N_EDGES + 255) / 256, 256, 0, stream>>>(col, cnt);
    scan_a_kernel<<<NBLK_SCAN, 512, 0, stream>>>(cnt, pp, bs);
    scan_b_kernel<<<1, 128, 0, stream>>>(bs, ptr, NBLK_SCAN);
    scan_c_kernel<<<(N_NODES + 255) / 256, 256, 0, stream>>>(pp, bs, cnt, ptr, fill, dis);
    scatter_kernel<<<(N_EDGES + 255) / 256, 256, 0, stream>>>(row, col, fill, csr);

    // 4. rest of MLP
    {
        dim3 g((N_NODES + 127) / 128, 1);
        mfma_gemm<<<g, 256, 0, stream>>>(h1, w1t, b1, h2, N_NODES, 128, 512, 1, 1);
    }
    {
        dim3 g((N_NODES + 127) / 128, 1);
        mfma_gemm<<<g, 256, 0, stream>>>(h2, w2t, b2, h3, N_NODES, 64, 128, 1, 0);
    }

    // 5. GCN1: xw1 = dis[r] * (h3 @ g1w); gather; +bias, ELU
    {
        dim3 g((N_NODES + 63) / 64, 1);
        gemm_kernel<<<g, 256, 0, stream>>>(h3, g1w, nullptr, dis, xw1, N_NODES, 32, 64, 0);
    }
    gather_kernel<<<((N_NODES * 32) + 255) / 256, 256, 0, stream>>>(
        xw1, csr, ptr, dis, g1b, agg1, 5, 1);

    // 6. GCN2: xw2 = dis[r] * (agg1 @ g2w); gather into out; +bias
    {
        dim3 g((N_NODES + 63) / 64, 1);
        gemm_kernel<<<g, 256, 0, stream>>>(agg1, g2w, nullptr, dis, xw2, N_NODES, 16, 32, 0);
    }
    gather_kernel<<<((N_NODES * 16) + 255) / 256, 256, 0, stream>>>(
        xw2, csr, ptr, dis, g2b, out, 4, 0);
}

// Round 5
// 736.706 us; speedup vs baseline: 1.2746x; 1.2746x over previous
//
#include <hip/hip_runtime.h>
#include <hip/hip_bf16.h>

#define N_NODES 50000
#define N_EDGES 3200000
#define NB1 196            // (N_NODES-1)>>8 + 1
#define NBLK1 782          // ceil(N_EDGES/4096)
#define HSZ (NB1 * NBLK1)  // 153272

typedef __bf16 v8bf __attribute__((ext_vector_type(8)));
typedef float v4f __attribute__((ext_vector_type(4)));
typedef unsigned short u16x8 __attribute__((ext_vector_type(8)));

__device__ __forceinline__ float elu_f(float x) { return x > 0.f ? x : (expf(x) - 1.f); }

// ---------------- fused maxpool(2) + LayerNorm(1024) -> bf16 ----------------
__global__ void pool_ln_kernel(const float* __restrict__ x,
                               const float* __restrict__ ln_w,
                               const float* __restrict__ ln_b,
                               __bf16* __restrict__ h0) {
    int node = blockIdx.x;
    int t = threadIdx.x;
    const float4* xr = (const float4*)(x + (size_t)node * 2048);
    float4 a = xr[t];
    float4 b = xr[t + 256];
    float p0 = fmaxf(a.x, a.y), p1 = fmaxf(a.z, a.w);
    float p2 = fmaxf(b.x, b.y), p3 = fmaxf(b.z, b.w);
    float sum = p0 + p1 + p2 + p3;
    float sq  = p0*p0 + p1*p1 + p2*p2 + p3*p3;
    #pragma unroll
    for (int off = 32; off > 0; off >>= 1) {
        sum += __shfl_down(sum, off);
        sq  += __shfl_down(sq, off);
    }
    __shared__ float red_s[4], red_q[4];
    __shared__ float s_mu, s_rstd;
    int wave = t >> 6, lane = t & 63;
    if (lane == 0) { red_s[wave] = sum; red_q[wave] = sq; }
    __syncthreads();
    if (t == 0) {
        float S = red_s[0] + red_s[1] + red_s[2] + red_s[3];
        float Q = red_q[0] + red_q[1] + red_q[2] + red_q[3];
        float mu = S * (1.f / 1024.f);
        float var = Q * (1.f / 1024.f) - mu * mu;
        s_mu = mu;
        s_rstd = rsqrtf(var + 1e-5f);
    }
    __syncthreads();
    float mu = s_mu, rstd = s_rstd;
    __bf16* out = h0 + (size_t)node * 1024;
    int i0 = 2 * t;
    int i1 = 512 + 2 * t;
    out[i0]     = (__bf16)((p0 - mu) * rstd * ln_w[i0]     + ln_b[i0]);
    out[i0 + 1] = (__bf16)((p1 - mu) * rstd * ln_w[i0 + 1] + ln_b[i0 + 1]);
    out[i1]     = (__bf16)((p2 - mu) * rstd * ln_w[i1]     + ln_b[i1]);
    out[i1 + 1] = (__bf16)((p3 - mu) * rstd * ln_w[i1 + 1] + ln_b[i1 + 1]);
}

// ---------------- W[K][N] fp32 -> WT[N][K] bf16 ----------------
__global__ void wt_kernel(const float* __restrict__ W, __bf16* __restrict__ WT,
                          int K, int N) {
    int idx = blockIdx.x * 256 + threadIdx.x;
    if (idx < K * N) {
        int k = idx / N, n = idx - k * N;
        WT[(size_t)n * K + k] = (__bf16)W[idx];
    }
}

// ---------------- bf16 MFMA GEMM (128x128 tile, BK=32, reg-staged LDS) ------
__global__ __launch_bounds__(256) void mfma_gemm(
    const __bf16* __restrict__ A, const __bf16* __restrict__ BT,
    const float* __restrict__ bias, void* __restrict__ C,
    int M, int N, int K, int do_elu, int out_bf16)
{
    __shared__ unsigned short lds[2 * 128 * 40];
    const int tid  = threadIdx.x;
    const int lane = tid & 63, wave = tid >> 6;
    const int wr = wave >> 1, wc = wave & 1;
    const int m0 = blockIdx.x * 128, n0 = blockIdx.y * 128;

    size_t offA[2], offB[2];
    int dstA[2], dstB[2];
    #pragma unroll
    for (int i = 0; i < 2; ++i) {
        int s = tid + i * 256;
        int r = s >> 2, ks = s & 3;
        int gr = m0 + r; if (gr > M - 1) gr = M - 1;
        offA[i] = (size_t)gr * K + ks * 8;
        dstA[i] = r * 40 + ks * 8;
        int gc = n0 + r; if (gc > N - 1) gc = N - 1;
        offB[i] = (size_t)gc * K + ks * 8;
        dstB[i] = 5120 + r * 40 + ks * 8;
    }

    v4f acc[4][4] = {};
    const int l15 = lane & 15, l4 = lane >> 4;
    const int abase = (wr * 64 + l15) * 40 + l4 * 8;
    const int bbase = 5120 + (wc * 64 + l15) * 40 + l4 * 8;

    u16x8 sa0 = *(const u16x8*)(A + offA[0]);
    u16x8 sa1 = *(const u16x8*)(A + offA[1]);
    u16x8 sb0 = *(const u16x8*)(BT + offB[0]);
    u16x8 sb1 = *(const u16x8*)(BT + offB[1]);

    for (int k0 = 0; k0 < K; k0 += 32) {
        __syncthreads();
        *(u16x8*)&lds[dstA[0]] = sa0;
        *(u16x8*)&lds[dstA[1]] = sa1;
        *(u16x8*)&lds[dstB[0]] = sb0;
        *(u16x8*)&lds[dstB[1]] = sb1;
        if (k0 + 32 < K) {
            sa0 = *(const u16x8*)(A + offA[0] + k0 + 32);
            sa1 = *(const u16x8*)(A + offA[1] + k0 + 32);
            sb0 = *(const u16x8*)(BT + offB[0] + k0 + 32);
            sb1 = *(const u16x8*)(BT + offB[1] + k0 + 32);
        }
        __syncthreads();
        v8bf af[4], bfr[4];
        #pragma unroll
        for (int m = 0; m < 4; ++m) af[m]  = *(const v8bf*)&lds[abase + m * 16 * 40];
        #pragma unroll
        for (int n = 0; n < 4; ++n) bfr[n] = *(const v8bf*)&lds[bbase + n * 16 * 40];
        #pragma unroll
        for (int m = 0; m < 4; ++m)
            #pragma unroll
            for (int n = 0; n < 4; ++n)
                acc[m][n] = __builtin_amdgcn_mfma_f32_16x16x32_bf16(af[m], bfr[n], acc[m][n], 0, 0, 0);
    }

    #pragma unroll
    for (int m = 0; m < 4; ++m) {
        #pragma unroll
        for (int j = 0; j < 4; ++j) {
            int row = m0 + wr * 64 + m * 16 + l4 * 4 + j;
            if (row >= M) continue;
            #pragma unroll
            for (int n = 0; n < 4; ++n) {
                int col = n0 + wc * 64 + n * 16 + l15;
                if (col >= N) continue;
                float v = acc[m][n][j] + bias[col];
                if (do_elu) v = elu_f(v);
                if (out_bf16) ((__bf16*)C)[(size_t)row * N + col] = (__bf16)v;
                else          ((float*)C)[(size_t)row * N + col] = v;
            }
        }
    }
}

// ---------------- small fp32 GEMM, epilogue: v = (acc [+bias]) [*scale[m]] ---
__global__ void gemm_kernel(const float* __restrict__ A, const float* __restrict__ W,
                            const float* __restrict__ bias, const float* __restrict__ scale,
                            float* __restrict__ C, int M, int N, int K, int do_elu) {
    const int BM = 64, BN = 64, BK = 16;
    __shared__ float As[BK][BM + 4];
    __shared__ float Ws[BK][BN + 4];
    int tid = threadIdx.x;
    int tx = tid & 15, ty = tid >> 4;
    int m0 = blockIdx.x * BM;
    int n0 = blockIdx.y * BN;
    float acc[4][4] = {};
    for (int k0 = 0; k0 < K; k0 += BK) {
        #pragma unroll
        for (int l = 0; l < 4; ++l) {
            int idx = tid + l * 256;
            int r = idx >> 4, c = idx & 15;
            int m = m0 + r;
            As[c][r] = (m < M) ? A[(size_t)m * K + k0 + c] : 0.f;
        }
        #pragma unroll
        for (int l = 0; l < 4; ++l) {
            int idx = tid + l * 256;
            int c = idx >> 6, n = idx & 63;
            int nn = n0 + n;
            Ws[c][n] = (nn < N) ? W[(size_t)(k0 + c) * N + nn] : 0.f;
        }
        __syncthreads();
        #pragma unroll
        for (int kk = 0; kk < BK; ++kk) {
            float4 av = *(const float4*)&As[kk][ty * 4];
            float4 wv = *(const float4*)&Ws[kk][tx * 4];
            float ar[4] = {av.x, av.y, av.z, av.w};
            float wrg[4] = {wv.x, wv.y, wv.z, wv.w};
            #pragma unroll
            for (int i = 0; i < 4; ++i)
                #pragma unroll
                for (int j = 0; j < 4; ++j)
                    acc[i][j] += ar[i] * wrg[j];
        }
        __syncthreads();
    }
    #pragma unroll
    for (int i = 0; i < 4; ++i) {
        int m = m0 + ty * 4 + i;
        if (m >= M) continue;
        float sc = scale ? scale[m] : 1.f;
        #pragma unroll
        for (int j = 0; j < 4; ++j) {
            int n = n0 + tx * 4 + j;
            if (n >= N) continue;
            float v = acc[i][j] + (bias ? bias[n] : 0.f);
            if (do_elu) v = elu_f(v);
            C[(size_t)m * N + n] = v * sc;
        }
    }
}

// ---------------- degree count + ptr scan ----------------
__global__ void zero_cnt_kernel(int* __restrict__ cnt) {
    int i = blockIdx.x * 256 + threadIdx.x;
    if (i < N_NODES) cnt[i] = 0;
}
__global__ void cnt_kernel(const int* __restrict__ col, int* __restrict__ cnt) {
    int e = blockIdx.x * 256 + threadIdx.x;
    if (e < N_EDGES) atomicAdd(&cnt[col[e]], 1);
}
__global__ void scan_a_kernel(const int* __restrict__ cnt, int* __restrict__ pp,
                              int* __restrict__ bs) {
    __shared__ int s[512];
    int t = threadIdx.x;
    int i = blockIdx.x * 512 + t;
    int v = (i < N_NODES) ? cnt[i] : 0;
    s[t] = v;
    __syncthreads();
    for (int off = 1; off < 512; off <<= 1) {
        int u = (t >= off) ? s[t - off] : 0;
        __syncthreads();
        s[t] += u;
        __syncthreads();
    }
    if (i < N_NODES) pp[i] = s[t] - v;
    if (t == 511) bs[blockIdx.x] = s[511];
}
__global__ void scan_b_kernel(int* __restrict__ bs, int* __restrict__ ptr, int nblk) {
    __shared__ int s[128];
    int t = threadIdx.x;
    int v = (t < nblk) ? bs[t] : 0;
    s[t] = v;
    __syncthreads();
    for (int off = 1; off < 128; off <<= 1) {
        int u = (t >= off) ? s[t - off] : 0;
        __syncthreads();
        s[t] += u;
        __syncthreads();
    }
    if (t < nblk) bs[t] = s[t] - v;
    if (t == 127) ptr[N_NODES] = s[127];
}
__global__ void scan_c_kernel(const int* __restrict__ pp, const int* __restrict__ bs,
                              const int* __restrict__ cnt, int* __restrict__ ptr,
                              float* __restrict__ dis) {
    int i = blockIdx.x * 256 + threadIdx.x;
    if (i < N_NODES) {
        ptr[i] = pp[i] + bs[i >> 9];
        dis[i] = rsqrtf((float)(cnt[i] + 1));
    }
}

// ---------------- CSR build: 2-pass bucketed counting sort -------------------
// pass1: bin = col>>8 (NB1 bins). per-block LDS hist -> bin-major scan ->
// scatter with LDS fetch-add (stores land in ~21-elem runs, L2-coalesced).
__global__ void p1_hist_kernel(const int* __restrict__ col, int* __restrict__ hist) {
    __shared__ int h[NB1];
    int t = threadIdx.x, b = blockIdx.x;
    if (t < NB1) h[t] = 0;
    __syncthreads();
    int base = b * 4096;
    #pragma unroll
    for (int j = 0; j < 16; ++j) {
        int e = base + j * 256 + t;
        if (e < N_EDGES) atomicAdd(&h[col[e] >> 8], 1);
    }
    __syncthreads();
    if (t < NB1) hist[t * NBLK1 + b] = h[t];
}
// generic scans for the HSZ-long hist array
__global__ void hscan_a_kernel(const int* __restrict__ in, int* __restrict__ pp,
                               int* __restrict__ bsum) {
    __shared__ int s[512];
    int t = threadIdx.x;
    int i = blockIdx.x * 512 + t;
    int v = (i < HSZ) ? in[i] : 0;
    s[t] = v;
    __syncthreads();
    for (int off = 1; off < 512; off <<= 1) {
        int u = (t >= off) ? s[t - off] : 0;
        __syncthreads();
        s[t] += u;
        __syncthreads();
    }
    if (i < HSZ) pp[i] = s[t] - v;
    if (t == 511) bsum[blockIdx.x] = s[511];
}
__global__ void hscan_b_kernel(int* __restrict__ bsum, int nblk) {
    __shared__ int s[512];
    int t = threadIdx.x;
    int v = (t < nblk) ? bsum[t] : 0;
    s[t] = v;
    __syncthreads();
    for (int off = 1; off < 512; off <<= 1) {
        int u = (t >= off) ? s[t - off] : 0;
        __syncthreads();
        s[t] += u;
        __syncthreads();
    }
    if (t < nblk) bsum[t] = s[t] - v;
}
__global__ void hscan_c_kernel(const int* __restrict__ pp, const int* __restrict__ bsum,
                               int* __restrict__ base, int* __restrict__ seg_ptr) {
    int i = blockIdx.x * 256 + threadIdx.x;
    if (i < HSZ) {
        int v = pp[i] + bsum[i >> 9];
        base[i] = v;
        if (i % NBLK1 == 0) seg_ptr[i / NBLK1] = v;
        if (i == 0) seg_ptr[NB1] = N_EDGES;
    }
}
__global__ void p1_scatter_kernel(const int* __restrict__ row, const int* __restrict__ col,
                                  const int* __restrict__ base, unsigned int* __restrict__ tmp) {
    __shared__ int bl[NB1];
    int t = threadIdx.x, b = blockIdx.x;
    if (t < NB1) bl[t] = base[t * NBLK1 + b];
    __syncthreads();
    int s = b * 4096;
    #pragma unroll
    for (int j = 0; j < 16; ++j) {
        int e = s + j * 256 + t;
        if (e < N_EDGES) {
            int c = col[e];
            int pos = atomicAdd(&bl[c >> 8], 1);
            tmp[pos] = ((unsigned int)c << 16) | (unsigned int)row[e];
        }
    }
}
// pass2: one block per bin segment (~16.3K edges); group by col&255 via LDS
__global__ void p2_kernel(const unsigned int* __restrict__ tmp,
                          const int* __restrict__ seg_ptr, int* __restrict__ csr) {
    __shared__ int h2[256], b2[256], s2[256];
    int seg = blockIdx.x;
    int start = seg_ptr[seg], end = seg_ptr[seg + 1];
    int t = threadIdx.x;
    if (t < 256) h2[t] = 0;
    __syncthreads();
    for (int i = start + t; i < end; i += 1024)
        atomicAdd(&h2[(tmp[i] >> 16) & 255], 1);
    __syncthreads();
    if (t < 256) s2[t] = h2[t];
    __syncthreads();
    for (int off = 1; off < 256; off <<= 1) {
        int u = 0;
        if (t < 256 && t >= off) u = s2[t - off];
        __syncthreads();
        if (t < 256) s2[t] += u;
        __syncthreads();
    }
    if (t < 256) b2[t] = start + s2[t] - h2[t];
    __syncthreads();
    for (int i = start + t; i < end; i += 1024) {
        unsigned int v = tmp[i];
        int pos = atomicAdd(&b2[(v >> 16) & 255], 1);
        csr[pos] = (int)(v & 0xFFFFu);
    }
}

// ---------------- CSR gather aggregation ----------------
__global__ void gather_kernel(const float* __restrict__ xws, const int* __restrict__ csr,
                              const int* __restrict__ ptr, const float* __restrict__ dis,
                              const float* __restrict__ bias, float* __restrict__ out,
                              int fshift, int do_elu) {
    int idx = blockIdx.x * 256 + threadIdx.x;
    int node = idx >> fshift;
    if (node >= N_NODES) return;
    int f = idx & ((1 << fshift) - 1);
    int s = ptr[node], e = ptr[node + 1];
    float acc = xws[((size_t)node << fshift) + f];  // self-loop (dis[node]*xw[node])
    for (int i = s; i < e; ++i) {
        int r = csr[i];
        acc += xws[((size_t)r << fshift) + f];
    }
    float v = dis[node] * acc + bias[f];
    out[idx] = do_elu ? elu_f(v) : v;
}

extern "C" void kernel_launch(void* const* d_in, const int* in_sizes, int n_in,
                              void* d_out, int out_size, void* d_ws, size_t ws_size,
                              hipStream_t stream) {
    const float* x    = (const float*)d_in[0];
    const int*   ei   = (const int*)d_in[1];
    const int*   row  = ei;
    const int*   col  = ei + N_EDGES;
    const float* ln_w = (const float*)d_in[2];
    const float* ln_b = (const float*)d_in[3];
    const float* w0   = (const float*)d_in[4];
    const float* b0   = (const float*)d_in[5];
    const float* w1   = (const float*)d_in[6];
    const float* b1   = (const float*)d_in[7];
    const float* w2   = (const float*)d_in[8];
    const float* b2   = (const float*)d_in[9];
    const float* g1w  = (const float*)d_in[10];
    const float* g1b  = (const float*)d_in[11];
    const float* g2w  = (const float*)d_in[12];
    const float* g2b  = (const float*)d_in[13];
    float* out = (float*)d_out;

    char* W = (char*)d_ws;
    __bf16* h0  = (__bf16*)(W + 0);          // 50000*1024 bf16 (dead after GEMM0)
    __bf16* h1  = (__bf16*)(W + 102400000);  // 50000*512 bf16
    __bf16* h2  = (__bf16*)(W + 153600000);  // 50000*128 bf16
    float*  h3  = (float*) (W + 166400000);  // 50000*64 f32
    float*  dis = (float*) (W + 179200000);  // 50000 f32
    float*  xw1 = (float*) (W + 179400192);  // 50000*32 f32 (dis-scaled)
    float*  agg1= (float*) (W + 185800192);  // 50000*32 f32
    float*  xw2 = (float*) (W + 192200192);  // 50000*16 f32 (dis-scaled)
    __bf16* w0t = (__bf16*)(W + 195400192);  // 512*1024 bf16
    __bf16* w1t = (__bf16*)(W + 196448768);  // 128*512 bf16
    __bf16* w2t = (__bf16*)(W + 196579840);  // 64*128 bf16
    // CSR structures overlay h0 (written only after GEMM0 consumed h0)
    int*    csr  = (int*)(W + 0);            // 3.2M int
    int*    ptr  = (int*)(W + 12800000);     // 50001 int
    int*    pp   = (int*)(W + 13200128);     // 50000 int
    int*    bs   = (int*)(W + 13400192);     // 128 int
    int*    cnt  = (int*)(W + 13600256);     // 50000 int
    unsigned int* tmp = (unsigned int*)(W + 16000000);  // 3.2M u32
    int*    hist = (int*)(W + 29000000);     // HSZ int (reused as bases)
    int*    pp_h = (int*)(W + 30000000);     // HSZ int
    int*    hbs  = (int*)(W + 31000000);     // 300 int
    int*    segp = (int*)(W + 31100000);     // NB1+1 int

    const int NBLK_SCAN  = (N_NODES + 511) / 512;   // 98
    const int NBLK_HSCAN = (HSZ + 511) / 512;       // 300

    // weight transposes (tiny)
    wt_kernel<<<(1024 * 512 + 255) / 256, 256, 0, stream>>>(w0, w0t, 1024, 512);
    wt_kernel<<<(512 * 128 + 255) / 256, 256, 0, stream>>>(w1, w1t, 512, 128);
    wt_kernel<<<(128 * 64 + 255) / 256, 256, 0, stream>>>(w2, w2t, 128, 64);

    // 1. pool + layernorm -> bf16
    pool_ln_kernel<<<N_NODES, 256, 0, stream>>>(x, ln_w, ln_b, h0);

    // 2. GEMM0 (h0 -> h1); h0 dead afterwards
    {
        dim3 g((N_NODES + 127) / 128, 4);
        mfma_gemm<<<g, 256, 0, stream>>>(h0, w0t, b0, h1, N_NODES, 512, 1024, 1, 1);
    }

    // 3a. degree counts -> ptr, dis
    zero_cnt_kernel<<<(N_NODES + 255) / 256, 256, 0, stream>>>(cnt);
    cnt_kernel<<<(N_EDGES + 255) / 256, 256, 0, stream>>>(col, cnt);
    scan_a_kernel<<<NBLK_SCAN, 512, 0, stream>>>(cnt, pp, bs);
    scan_b_kernel<<<1, 128, 0, stream>>>(bs, ptr, NBLK_SCAN);
    scan_c_kernel<<<(N_NODES + 255) / 256, 256, 0, stream>>>(pp, bs, cnt, ptr, dis);

    // 3b. CSR via 2-pass bucketed counting sort (coalesced, no returning atomics)
    p1_hist_kernel<<<NBLK1, 256, 0, stream>>>(col, hist);
    hscan_a_kernel<<<NBLK_HSCAN, 512, 0, stream>>>(hist, pp_h, hbs);
    hscan_b_kernel<<<1, 512, 0, stream>>>(hbs, NBLK_HSCAN);
    hscan_c_kernel<<<(HSZ + 255) / 256, 256, 0, stream>>>(pp_h, hbs, hist, segp);
    p1_scatter_kernel<<<NBLK1, 256, 0, stream>>>(row, col, hist, tmp);
    p2_kernel<<<NB1, 1024, 0, stream>>>(tmp, segp, csr);

    // 4. rest of MLP
    {
        dim3 g((N_NODES + 127) / 128, 1);
        mfma_gemm<<<g, 256, 0, stream>>>(h1, w1t, b1, h2, N_NODES, 128, 512, 1, 1);
    }
    {
        dim3 g((N_NODES + 127) / 128, 1);
        mfma_gemm<<<g, 256, 0, stream>>>(h2, w2t, b2, h3, N_NODES, 64, 128, 1, 0);
    }

    // 5. GCN1: xw1 = dis[r] * (h3 @ g1w); gather; +bias, ELU
    {
        dim3 g((N_NODES + 63) / 64, 1);
        gemm_kernel<<<g, 256, 0, stream>>>(h3, g1w, nullptr, dis, xw1, N_NODES, 32, 64, 0);
    }
    gather_kernel<<<((N_NODES * 32) + 255) / 256, 256, 0, stream>>>(
        xw1, csr, ptr, dis, g1b, agg1, 5, 1);

    // 6. GCN2: xw2 = dis[r] * (agg1 @ g2w); gather into out; +bias
    {
        dim3 g((N_NODES + 63) / 64, 1);
        gemm_kernel<<<g, 256, 0, stream>>>(agg1, g2w, nullptr, dis, xw2, N_NODES, 16, 32, 0);
    }
    gather_kernel<<<((N_NODES * 16) + 255) / 256, 256, 0, stream>>>(
        xw2, csr, ptr, dis, g2b, out, 4, 0);
}

// Round 6
// 504.067 us; speedup vs baseline: 1.8628x; 1.4615x over previous
//
#include <hip/hip_runtime.h>
#include <hip/hip_bf16.h>

#define N_NODES 50000
#define N_EDGES 3200000
#define NB1 196            // (N_NODES-1)>>8 + 1
#define NBLK1 782          // ceil(N_EDGES/4096)
#define HSZ (NB1 * NBLK1)  // 153272

typedef __bf16 v8bf __attribute__((ext_vector_type(8)));
typedef float v4f __attribute__((ext_vector_type(4)));

__device__ __forceinline__ float elu_f(float x) { return x > 0.f ? x : (expf(x) - 1.f); }

// async global->LDS, 16B per lane; LDS dest = wave-uniform base + lane*16
#define GL16(gp, lp) __builtin_amdgcn_global_load_lds( \
    (const __attribute__((address_space(1))) void*)(gp), \
    (__attribute__((address_space(3))) void*)(lp), 16, 0, 0)

// ---------------- fused maxpool(2) + LayerNorm(1024) -> bf16 ----------------
__global__ void pool_ln_kernel(const float* __restrict__ x,
                               const float* __restrict__ ln_w,
                               const float* __restrict__ ln_b,
                               __bf16* __restrict__ h0) {
    int node = blockIdx.x;
    int t = threadIdx.x;
    const float4* xr = (const float4*)(x + (size_t)node * 2048);
    float4 a = xr[t];
    float4 b = xr[t + 256];
    float p0 = fmaxf(a.x, a.y), p1 = fmaxf(a.z, a.w);
    float p2 = fmaxf(b.x, b.y), p3 = fmaxf(b.z, b.w);
    float sum = p0 + p1 + p2 + p3;
    float sq  = p0*p0 + p1*p1 + p2*p2 + p3*p3;
    #pragma unroll
    for (int off = 32; off > 0; off >>= 1) {
        sum += __shfl_down(sum, off);
        sq  += __shfl_down(sq, off);
    }
    __shared__ float red_s[4], red_q[4];
    __shared__ float s_mu, s_rstd;
    int wave = t >> 6, lane = t & 63;
    if (lane == 0) { red_s[wave] = sum; red_q[wave] = sq; }
    __syncthreads();
    if (t == 0) {
        float S = red_s[0] + red_s[1] + red_s[2] + red_s[3];
        float Q = red_q[0] + red_q[1] + red_q[2] + red_q[3];
        float mu = S * (1.f / 1024.f);
        float var = Q * (1.f / 1024.f) - mu * mu;
        s_mu = mu;
        s_rstd = rsqrtf(var + 1e-5f);
    }
    __syncthreads();
    float mu = s_mu, rstd = s_rstd;
    __bf16* out = h0 + (size_t)node * 1024;
    int i0 = 2 * t;
    int i1 = 512 + 2 * t;
    out[i0]     = (__bf16)((p0 - mu) * rstd * ln_w[i0]     + ln_b[i0]);
    out[i0 + 1] = (__bf16)((p1 - mu) * rstd * ln_w[i0 + 1] + ln_b[i0 + 1]);
    out[i1]     = (__bf16)((p2 - mu) * rstd * ln_w[i1]     + ln_b[i1]);
    out[i1 + 1] = (__bf16)((p3 - mu) * rstd * ln_w[i1 + 1] + ln_b[i1 + 1]);
}

// ---------------- all 3 weight transposes in one dispatch ----------------
__global__ void wt_all_kernel(const float* __restrict__ w0, const float* __restrict__ w1,
                              const float* __restrict__ w2,
                              __bf16* __restrict__ w0t, __bf16* __restrict__ w1t,
                              __bf16* __restrict__ w2t) {
    int idx = blockIdx.x * 256 + threadIdx.x;
    if (idx < 524288) {            // w0: 1024x512
        int k = idx >> 9, n = idx & 511;
        w0t[(size_t)n * 1024 + k] = (__bf16)w0[idx];
    } else if (idx < 524288 + 65536) {  // w1: 512x128
        int j = idx - 524288;
        int k = j >> 7, n = j & 127;
        w1t[(size_t)n * 512 + k] = (__bf16)w1[j];
    } else if (idx < 524288 + 65536 + 8192) {  // w2: 128x64
        int j = idx - 524288 - 65536;
        int k = j >> 6, n = j & 63;
        w2t[(size_t)n * 128 + k] = (__bf16)w2[j];
    }
}

// ---------------- bf16 MFMA GEMM (m97-style: global_load_lds, linear LDS) ---
// A bf16 [M][K], BT bf16 [N][K]. 128x128 tile, BK=32, 4 waves (2x2).
__global__ __launch_bounds__(256) void mfma_gemm(
    const __bf16* __restrict__ A, const __bf16* __restrict__ BT,
    const float* __restrict__ bias, void* __restrict__ C,
    int M, int N, int K, int do_elu, int out_bf16)
{
    __shared__ unsigned short lds[8192];  // A: [0,4096), B: [4096,8192), linear [128][32]
    const int tid  = threadIdx.x;
    const int lane = tid & 63, wave = tid >> 6;
    const int wr = wave >> 1, wc = wave & 1;
    const int m0 = blockIdx.x * 128, n0 = blockIdx.y * 128;

    // seg s (0..511) <-> row s>>2, kseg s&3; lds byte = s*16 (linear)
    const int s0 = tid, s1 = tid + 256;
    int gr0 = m0 + (s0 >> 2); if (gr0 > M - 1) gr0 = M - 1;
    int gr1 = m0 + (s1 >> 2); if (gr1 > M - 1) gr1 = M - 1;
    int gc0 = n0 + (s0 >> 2); if (gc0 > N - 1) gc0 = N - 1;
    int gc1 = n0 + (s1 >> 2); if (gc1 > N - 1) gc1 = N - 1;
    const __bf16* a0 = A + (size_t)gr0 * K + (s0 & 3) * 8;
    const __bf16* a1 = A + (size_t)gr1 * K + (s1 & 3) * 8;
    const __bf16* b0 = BT + (size_t)gc0 * K + (s0 & 3) * 8;
    const __bf16* b1 = BT + (size_t)gc1 * K + (s1 & 3) * 8;
    char* ldsA0 = (char*)lds + s0 * 16;
    char* ldsA1 = (char*)lds + s1 * 16;
    char* ldsB0 = (char*)lds + 8192 + s0 * 16;
    char* ldsB1 = (char*)lds + 8192 + s1 * 16;

    v4f acc[4][4] = {};
    const int l15 = lane & 15, l4 = lane >> 4;
    const int abase = (wr * 64 + l15) * 32 + l4 * 8;
    const int bbase = 4096 + (wc * 64 + l15) * 32 + l4 * 8;

    for (int k0 = 0; k0 < K; k0 += 32) {
        GL16(a0 + k0, ldsA0);
        GL16(a1 + k0, ldsA1);
        GL16(b0 + k0, ldsB0);
        GL16(b1 + k0, ldsB1);
        __syncthreads();  // drains vmcnt -> tile resident
        v8bf af[4], bfr[4];
        #pragma unroll
        for (int m = 0; m < 4; ++m) af[m]  = *(const v8bf*)&lds[abase + m * 16 * 32];
        #pragma unroll
        for (int n = 0; n < 4; ++n) bfr[n] = *(const v8bf*)&lds[bbase + n * 16 * 32];
        #pragma unroll
        for (int m = 0; m < 4; ++m)
            #pragma unroll
            for (int n = 0; n < 4; ++n)
                acc[m][n] = __builtin_amdgcn_mfma_f32_16x16x32_bf16(af[m], bfr[n], acc[m][n], 0, 0, 0);
        __syncthreads();  // all waves done reading before next overwrite
    }

    // C/D layout: col = lane&15, row = (lane>>4)*4 + j
    #pragma unroll
    for (int m = 0; m < 4; ++m) {
        #pragma unroll
        for (int j = 0; j < 4; ++j) {
            int row = m0 + wr * 64 + m * 16 + l4 * 4 + j;
            if (row >= M) continue;
            #pragma unroll
            for (int n = 0; n < 4; ++n) {
                int col = n0 + wc * 64 + n * 16 + l15;
                if (col >= N) continue;
                float v = acc[m][n][j] + bias[col];
                if (do_elu) v = elu_f(v);
                if (out_bf16) ((__bf16*)C)[(size_t)row * N + col] = (__bf16)v;
                else          ((float*)C)[(size_t)row * N + col] = v;
            }
        }
    }
}

// ---------------- small fp32 GEMM, epilogue: v = (acc [+bias]) [*scale[m]] ---
__global__ void gemm_kernel(const float* __restrict__ A, const float* __restrict__ W,
                            const float* __restrict__ bias, const float* __restrict__ scale,
                            float* __restrict__ C, int M, int N, int K, int do_elu) {
    const int BM = 64, BN = 64, BK = 16;
    __shared__ float As[BK][BM + 4];
    __shared__ float Ws[BK][BN + 4];
    int tid = threadIdx.x;
    int tx = tid & 15, ty = tid >> 4;
    int m0 = blockIdx.x * BM;
    int n0 = blockIdx.y * BN;
    float acc[4][4] = {};
    for (int k0 = 0; k0 < K; k0 += BK) {
        #pragma unroll
        for (int l = 0; l < 4; ++l) {
            int idx = tid + l * 256;
            int r = idx >> 4, c = idx & 15;
            int m = m0 + r;
            As[c][r] = (m < M) ? A[(size_t)m * K + k0 + c] : 0.f;
        }
        #pragma unroll
        for (int l = 0; l < 4; ++l) {
            int idx = tid + l * 256;
            int c = idx >> 6, n = idx & 63;
            int nn = n0 + n;
            Ws[c][n] = (nn < N) ? W[(size_t)(k0 + c) * N + nn] : 0.f;
        }
        __syncthreads();
        #pragma unroll
        for (int kk = 0; kk < BK; ++kk) {
            float4 av = *(const float4*)&As[kk][ty * 4];
            float4 wv = *(const float4*)&Ws[kk][tx * 4];
            float ar[4] = {av.x, av.y, av.z, av.w};
            float wrg[4] = {wv.x, wv.y, wv.z, wv.w};
            #pragma unroll
            for (int i = 0; i < 4; ++i)
                #pragma unroll
                for (int j = 0; j < 4; ++j)
                    acc[i][j] += ar[i] * wrg[j];
        }
        __syncthreads();
    }
    #pragma unroll
    for (int i = 0; i < 4; ++i) {
        int m = m0 + ty * 4 + i;
        if (m >= M) continue;
        float sc = scale ? scale[m] : 1.f;
        #pragma unroll
        for (int j = 0; j < 4; ++j) {
            int n = n0 + tx * 4 + j;
            if (n >= N) continue;
            float v = acc[i][j] + (bias ? bias[n] : 0.f);
            if (do_elu) v = elu_f(v);
            C[(size_t)m * N + n] = v * sc;
        }
    }
}

// ---------------- CSR build: 2-pass bucketed counting sort -------------------
__global__ void p1_hist_kernel(const int* __restrict__ col, int* __restrict__ hist) {
    __shared__ int h[NB1];
    int t = threadIdx.x, b = blockIdx.x;
    if (t < NB1) h[t] = 0;
    __syncthreads();
    int base = b * 4096;
    #pragma unroll
    for (int j = 0; j < 16; ++j) {
        int e = base + j * 256 + t;
        if (e < N_EDGES) atomicAdd(&h[col[e] >> 8], 1);
    }
    __syncthreads();
    if (t < NB1) hist[t * NBLK1 + b] = h[t];
}
__global__ void hscan_a_kernel(const int* __restrict__ in, int* __restrict__ pp,
                               int* __restrict__ bsum) {
    __shared__ int s[512];
    int t = threadIdx.x;
    int i = blockIdx.x * 512 + t;
    int v = (i < HSZ) ? in[i] : 0;
    s[t] = v;
    __syncthreads();
    for (int off = 1; off < 512; off <<= 1) {
        int u = (t >= off) ? s[t - off] : 0;
        __syncthreads();
        s[t] += u;
        __syncthreads();
    }
    if (i < HSZ) pp[i] = s[t] - v;
    if (t == 511) bsum[blockIdx.x] = s[511];
}
__global__ void hscan_b_kernel(int* __restrict__ bsum, int nblk) {
    __shared__ int s[512];
    int t = threadIdx.x;
    int v = (t < nblk) ? bsum[t] : 0;
    s[t] = v;
    __syncthreads();
    for (int off = 1; off < 512; off <<= 1) {
        int u = (t >= off) ? s[t - off] : 0;
        __syncthreads();
        s[t] += u;
        __syncthreads();
    }
    if (t < nblk) bsum[t] = s[t] - v;
}
__global__ void hscan_c_kernel(const int* __restrict__ pp, const int* __restrict__ bsum,
                               int* __restrict__ base, int* __restrict__ seg_ptr,
                               int* __restrict__ ptr) {
    int i = blockIdx.x * 256 + threadIdx.x;
    if (i < HSZ) {
        int v = pp[i] + bsum[i >> 9];
        base[i] = v;
        if (i % NBLK1 == 0) seg_ptr[i / NBLK1] = v;
        if (i == 0) { seg_ptr[NB1] = N_EDGES; ptr[N_NODES] = N_EDGES; }
    }
}
__global__ void p1_scatter_kernel(const int* __restrict__ row, const int* __restrict__ col,
                                  const int* __restrict__ base, unsigned int* __restrict__ tmp) {
    __shared__ int bl[NB1];
    int t = threadIdx.x, b = blockIdx.x;
    if (t < NB1) bl[t] = base[t * NBLK1 + b];
    __syncthreads();
    int s = b * 4096;
    #pragma unroll
    for (int j = 0; j < 16; ++j) {
        int e = s + j * 256 + t;
        if (e < N_EDGES) {
            int c = col[e];
            int pos = atomicAdd(&bl[c >> 8], 1);
            tmp[pos] = ((unsigned int)c << 16) | (unsigned int)row[e];
        }
    }
}
// pass2: group by col&255; ALSO emits ptr[node] (global CSR offset) and dis.
__global__ void p2_kernel(const unsigned int* __restrict__ tmp,
                          const int* __restrict__ seg_ptr, int* __restrict__ csr,
                          int* __restrict__ ptr, float* __restrict__ dis) {
    __shared__ int h2[256], b2[256], s2[256];
    int seg = blockIdx.x;
    int start = seg_ptr[seg], end = seg_ptr[seg + 1];
    int t = threadIdx.x;
    if (t < 256) h2[t] = 0;
    __syncthreads();
    for (int i = start + t; i < end; i += 1024)
        atomicAdd(&h2[(tmp[i] >> 16) & 255], 1);
    __syncthreads();
    if (t < 256) s2[t] = h2[t];
    __syncthreads();
    for (int off = 1; off < 256; off <<= 1) {
        int u = 0;
        if (t < 256 && t >= off) u = s2[t - off];
        __syncthreads();
        if (t < 256) s2[t] += u;
        __syncthreads();
    }
    if (t < 256) {
        int p = start + s2[t] - h2[t];
        b2[t] = p;
        int node = (seg << 8) + t;
        if (node < N_NODES) {
            ptr[node] = p;
            dis[node] = rsqrtf((float)(h2[t] + 1));
        }
    }
    __syncthreads();
    for (int i = start + t; i < end; i += 1024) {
        unsigned int v = tmp[i];
        int pos = atomicAdd(&b2[(v >> 16) & 255], 1);
        csr[pos] = (int)(v & 0xFFFFu);
    }
}

// ---------------- CSR gather aggregation (float4 per thread) ----------------
__global__ void gather_kernel(const float* __restrict__ xws, const int* __restrict__ csr,
                              const int* __restrict__ ptr, const float* __restrict__ dis,
                              const float* __restrict__ bias, float* __restrict__ out,
                              int f4shift, int do_elu) {
    int idx = blockIdx.x * 256 + threadIdx.x;
    int node = idx >> f4shift;
    if (node >= N_NODES) return;
    int q = idx & ((1 << f4shift) - 1);
    int s = ptr[node], e = ptr[node + 1];
    const float4* xw4 = (const float4*)xws;
    float4 acc = xw4[((size_t)node << f4shift) + q];  // self-loop
    for (int i = s; i < e; ++i) {
        int r = csr[i];
        float4 v = xw4[((size_t)r << f4shift) + q];
        acc.x += v.x; acc.y += v.y; acc.z += v.z; acc.w += v.w;
    }
    float d = dis[node];
    float4 bb = ((const float4*)bias)[q];
    float4 o;
    o.x = d * acc.x + bb.x; o.y = d * acc.y + bb.y;
    o.z = d * acc.z + bb.z; o.w = d * acc.w + bb.w;
    if (do_elu) { o.x = elu_f(o.x); o.y = elu_f(o.y); o.z = elu_f(o.z); o.w = elu_f(o.w); }
    ((float4*)out)[idx] = o;
}

extern "C" void kernel_launch(void* const* d_in, const int* in_sizes, int n_in,
                              void* d_out, int out_size, void* d_ws, size_t ws_size,
                              hipStream_t stream) {
    const float* x    = (const float*)d_in[0];
    const int*   ei   = (const int*)d_in[1];
    const int*   row  = ei;
    const int*   col  = ei + N_EDGES;
    const float* ln_w = (const float*)d_in[2];
    const float* ln_b = (const float*)d_in[3];
    const float* w0   = (const float*)d_in[4];
    const float* b0   = (const float*)d_in[5];
    const float* w1   = (const float*)d_in[6];
    const float* b1   = (const float*)d_in[7];
    const float* w2   = (const float*)d_in[8];
    const float* b2   = (const float*)d_in[9];
    const float* g1w  = (const float*)d_in[10];
    const float* g1b  = (const float*)d_in[11];
    const float* g2w  = (const float*)d_in[12];
    const float* g2b  = (const float*)d_in[13];
    float* out = (float*)d_out;

    char* W = (char*)d_ws;
    __bf16* h0  = (__bf16*)(W + 0);          // 50000*1024 bf16 (dead after GEMM0)
    __bf16* h1  = (__bf16*)(W + 102400000);  // 50000*512 bf16
    __bf16* h2  = (__bf16*)(W + 153600000);  // 50000*128 bf16
    float*  h3  = (float*) (W + 166400000);  // 50000*64 f32
    float*  dis = (float*) (W + 179200000);  // 50000 f32
    float*  xw1 = (float*) (W + 179400192);  // 50000*32 f32 (dis-scaled)
    float*  agg1= (float*) (W + 185800192);  // 50000*32 f32
    float*  xw2 = (float*) (W + 192200192);  // 50000*16 f32 (dis-scaled)
    __bf16* w0t = (__bf16*)(W + 195400192);  // 512*1024 bf16
    __bf16* w1t = (__bf16*)(W + 196448768);  // 128*512 bf16
    __bf16* w2t = (__bf16*)(W + 196579840);  // 64*128 bf16
    // CSR structures overlay h0 (written only after GEMM0 consumed h0)
    int*    csr  = (int*)(W + 0);            // 3.2M int
    int*    ptr  = (int*)(W + 12800000);     // 50001 int
    unsigned int* tmp = (unsigned int*)(W + 16000000);  // 3.2M u32
    int*    hist = (int*)(W + 29000000);     // HSZ int (reused as bases)
    int*    pp_h = (int*)(W + 30000000);     // HSZ int
    int*    hbs  = (int*)(W + 31000000);     // 300 int
    int*    segp = (int*)(W + 31100000);     // NB1+1 int

    const int NBLK_HSCAN = (HSZ + 511) / 512;       // 300

    // weight transposes (one dispatch)
    wt_all_kernel<<<(598016 + 255) / 256, 256, 0, stream>>>(w0, w1, w2, w0t, w1t, w2t);

    // 1. pool + layernorm -> bf16
    pool_ln_kernel<<<N_NODES, 256, 0, stream>>>(x, ln_w, ln_b, h0);

    // 2. GEMM0 (h0 -> h1); h0 dead afterwards
    {
        dim3 g((N_NODES + 127) / 128, 4);
        mfma_gemm<<<g, 256, 0, stream>>>(h0, w0t, b0, h1, N_NODES, 512, 1024, 1, 1);
    }

    // 3. CSR via 2-pass bucketed counting sort; p2 also emits ptr + dis
    p1_hist_kernel<<<NBLK1, 256, 0, stream>>>(col, hist);
    hscan_a_kernel<<<NBLK_HSCAN, 512, 0, stream>>>(hist, pp_h, hbs);
    hscan_b_kernel<<<1, 512, 0, stream>>>(hbs, NBLK_HSCAN);
    hscan_c_kernel<<<(HSZ + 255) / 256, 256, 0, stream>>>(pp_h, hbs, hist, segp, ptr);
    p1_scatter_kernel<<<NBLK1, 256, 0, stream>>>(row, col, hist, tmp);
    p2_kernel<<<NB1, 1024, 0, stream>>>(tmp, segp, csr, ptr, dis);

    // 4. rest of MLP
    {
        dim3 g((N_NODES + 127) / 128, 1);
        mfma_gemm<<<g, 256, 0, stream>>>(h1, w1t, b1, h2, N_NODES, 128, 512, 1, 1);
    }
    {
        dim3 g((N_NODES + 127) / 128, 1);
        mfma_gemm<<<g, 256, 0, stream>>>(h2, w2t, b2, h3, N_NODES, 64, 128, 1, 0);
    }

    // 5. GCN1: xw1 = dis[r] * (h3 @ g1w); gather; +bias, ELU
    {
        dim3 g((N_NODES + 63) / 64, 1);
        gemm_kernel<<<g, 256, 0, stream>>>(h3, g1w, nullptr, dis, xw1, N_NODES, 32, 64, 0);
    }
    gather_kernel<<<((N_NODES * 8) + 255) / 256, 256, 0, stream>>>(
        xw1, csr, ptr, dis, g1b, agg1, 3, 1);

    // 6. GCN2: xw2 = dis[r] * (agg1 @ g2w); gather into out; +bias
    {
        dim3 g((N_NODES + 63) / 64, 1);
        gemm_kernel<<<g, 256, 0, stream>>>(agg1, g2w, nullptr, dis, xw2, N_NODES, 16, 32, 0);
    }
    gather_kernel<<<((N_NODES * 4) + 255) / 256, 256, 0, stream>>>(
        xw2, csr, ptr, dis, g2b, out, 2, 0);
}

// Round 7
// 435.658 us; speedup vs baseline: 2.1553x; 1.1570x over previous
//
#include <hip/hip_runtime.h>
#include <hip/hip_bf16.h>

#define N_NODES 50000
#define N_EDGES 3200000
#define NB1 196            // (N_NODES-1)>>8 + 1
#define NBLK1 782          // ceil(N_EDGES/4096)
#define CAP 20480          // per-bin tmp capacity (avg 16327, sigma ~128)

typedef __bf16 v8bf __attribute__((ext_vector_type(8)));
typedef __bf16 v4bf __attribute__((ext_vector_type(4)));
typedef float v4f __attribute__((ext_vector_type(4)));

__device__ __forceinline__ float elu_f(float x) { return x > 0.f ? x : (expf(x) - 1.f); }

// async global->LDS, 16B per lane; LDS dest = wave-uniform base + lane*16
#define GL16(gp, lp) __builtin_amdgcn_global_load_lds( \
    (const __attribute__((address_space(1))) void*)(gp), \
    (__attribute__((address_space(3))) void*)(lp), 16, 0, 0)

// ---------------- fused maxpool(2) + LayerNorm(1024) -> bf16 ----------------
// thread t: 8 consecutive f32 (32B read) -> 4 pooled bf16 (8B store)
__global__ void pool_ln_kernel(const float* __restrict__ x,
                               const float* __restrict__ ln_w,
                               const float* __restrict__ ln_b,
                               __bf16* __restrict__ h0) {
    int node = blockIdx.x;
    int t = threadIdx.x;
    const float4* xr = (const float4*)(x + (size_t)node * 2048);
    float4 v0 = xr[2 * t];
    float4 v1 = xr[2 * t + 1];
    float p0 = fmaxf(v0.x, v0.y), p1 = fmaxf(v0.z, v0.w);
    float p2 = fmaxf(v1.x, v1.y), p3 = fmaxf(v1.z, v1.w);
    float sum = p0 + p1 + p2 + p3;
    float sq  = p0*p0 + p1*p1 + p2*p2 + p3*p3;
    #pragma unroll
    for (int off = 32; off > 0; off >>= 1) {
        sum += __shfl_down(sum, off);
        sq  += __shfl_down(sq, off);
    }
    __shared__ float red_s[4], red_q[4];
    __shared__ float s_mu, s_rstd;
    int wave = t >> 6, lane = t & 63;
    if (lane == 0) { red_s[wave] = sum; red_q[wave] = sq; }
    __syncthreads();
    if (t == 0) {
        float S = red_s[0] + red_s[1] + red_s[2] + red_s[3];
        float Q = red_q[0] + red_q[1] + red_q[2] + red_q[3];
        float mu = S * (1.f / 1024.f);
        float var = Q * (1.f / 1024.f) - mu * mu;
        s_mu = mu;
        s_rstd = rsqrtf(var + 1e-5f);
    }
    __syncthreads();
    float mu = s_mu, rstd = s_rstd;
    float4 w4 = ((const float4*)ln_w)[t];
    float4 b4 = ((const float4*)ln_b)[t];
    v4bf o;
    o[0] = (__bf16)((p0 - mu) * rstd * w4.x + b4.x);
    o[1] = (__bf16)((p1 - mu) * rstd * w4.y + b4.y);
    o[2] = (__bf16)((p2 - mu) * rstd * w4.z + b4.z);
    o[3] = (__bf16)((p3 - mu) * rstd * w4.w + b4.w);
    *(v4bf*)(h0 + (size_t)node * 1024 + 4 * t) = o;
}

// ---------------- all 3 weight transposes + fill196 init (one dispatch) -----
__global__ void wt_all_kernel(const float* __restrict__ w0, const float* __restrict__ w1,
                              const float* __restrict__ w2,
                              __bf16* __restrict__ w0t, __bf16* __restrict__ w1t,
                              __bf16* __restrict__ w2t, int* __restrict__ fill196) {
    int idx = blockIdx.x * 256 + threadIdx.x;
    if (idx < NB1) fill196[idx] = idx * CAP;
    if (idx < 524288) {            // w0: 1024x512
        int k = idx >> 9, n = idx & 511;
        w0t[(size_t)n * 1024 + k] = (__bf16)w0[idx];
    } else if (idx < 524288 + 65536) {  // w1: 512x128
        int j = idx - 524288;
        int k = j >> 7, n = j & 127;
        w1t[(size_t)n * 512 + k] = (__bf16)w1[j];
    } else if (idx < 524288 + 65536 + 8192) {  // w2: 128x64
        int j = idx - 524288 - 65536;
        int k = j >> 6, n = j & 63;
        w2t[(size_t)n * 128 + k] = (__bf16)w2[j];
    }
}

// ---------------- GEMM0: 128x256 tile, 512 threads (8 waves 2x4), K=1024 ----
__global__ __launch_bounds__(512) void mfma_gemm0(
    const __bf16* __restrict__ A, const __bf16* __restrict__ BT,
    const float* __restrict__ bias, __bf16* __restrict__ C, int M)
{
    const int K = 1024, N = 512;
    __shared__ unsigned short lds[12288];  // A:[0,4096) shorts, B:[4096,12288)
    const int tid = threadIdx.x;
    const int lane = tid & 63, w = tid >> 6;
    const int wr = w >> 2, wc = w & 3;
    const int m0 = blockIdx.x * 128, n0 = blockIdx.y * 256;

    // A: 512 segs (row s>>2, kseg s&3), one per thread
    int grA = m0 + (tid >> 2); if (grA > M - 1) grA = M - 1;
    const __bf16* aP = A + (size_t)grA * K + (tid & 3) * 8;
    char* ldsA = (char*)lds + tid * 16;
    // B: 1024 segs, two per thread (s = tid, tid+512); N=512 exact, no clamp
    const __bf16* bP0 = BT + (size_t)(n0 + (tid >> 2)) * K + (tid & 3) * 8;
    const __bf16* bP1 = BT + (size_t)(n0 + ((tid + 512) >> 2)) * K + (tid & 3) * 8;
    char* ldsB0 = (char*)lds + 8192 + tid * 16;
    char* ldsB1 = (char*)lds + 16384 + tid * 16;

    v4f acc[4][4] = {};
    const int l15 = lane & 15, l4 = lane >> 4;
    const int abase = (wr * 64 + l15) * 32 + l4 * 8;
    const int bbase = 4096 + (wc * 64 + l15) * 32 + l4 * 8;

    for (int k0 = 0; k0 < K; k0 += 32) {
        GL16(aP + k0, ldsA);
        GL16(bP0 + k0, ldsB0);
        GL16(bP1 + k0, ldsB1);
        __syncthreads();
        v8bf af[4], bfr[4];
        #pragma unroll
        for (int m = 0; m < 4; ++m) af[m]  = *(const v8bf*)&lds[abase + m * 16 * 32];
        #pragma unroll
        for (int n = 0; n < 4; ++n) bfr[n] = *(const v8bf*)&lds[bbase + n * 16 * 32];
        #pragma unroll
        for (int m = 0; m < 4; ++m)
            #pragma unroll
            for (int n = 0; n < 4; ++n)
                acc[m][n] = __builtin_amdgcn_mfma_f32_16x16x32_bf16(af[m], bfr[n], acc[m][n], 0, 0, 0);
        __syncthreads();
    }

    #pragma unroll
    for (int m = 0; m < 4; ++m) {
        #pragma unroll
        for (int j = 0; j < 4; ++j) {
            int row = m0 + wr * 64 + m * 16 + l4 * 4 + j;
            if (row >= M) continue;
            #pragma unroll
            for (int n = 0; n < 4; ++n) {
                int col = n0 + wc * 64 + n * 16 + l15;
                float v = acc[m][n][j] + bias[col];
                C[(size_t)row * N + col] = (__bf16)elu_f(v);
            }
        }
    }
}

// ---------------- generic bf16 MFMA GEMM (128x128, gl_lds, linear LDS) ------
__global__ __launch_bounds__(256) void mfma_gemm(
    const __bf16* __restrict__ A, const __bf16* __restrict__ BT,
    const float* __restrict__ bias, void* __restrict__ C,
    int M, int N, int K, int do_elu, int out_bf16)
{
    __shared__ unsigned short lds[8192];
    const int tid  = threadIdx.x;
    const int lane = tid & 63, wave = tid >> 6;
    const int wr = wave >> 1, wc = wave & 1;
    const int m0 = blockIdx.x * 128, n0 = blockIdx.y * 128;

    const int s0 = tid, s1 = tid + 256;
    int gr0 = m0 + (s0 >> 2); if (gr0 > M - 1) gr0 = M - 1;
    int gr1 = m0 + (s1 >> 2); if (gr1 > M - 1) gr1 = M - 1;
    int gc0 = n0 + (s0 >> 2); if (gc0 > N - 1) gc0 = N - 1;
    int gc1 = n0 + (s1 >> 2); if (gc1 > N - 1) gc1 = N - 1;
    const __bf16* a0 = A + (size_t)gr0 * K + (s0 & 3) * 8;
    const __bf16* a1 = A + (size_t)gr1 * K + (s1 & 3) * 8;
    const __bf16* b0 = BT + (size_t)gc0 * K + (s0 & 3) * 8;
    const __bf16* b1 = BT + (size_t)gc1 * K + (s1 & 3) * 8;
    char* ldsA0 = (char*)lds + s0 * 16;
    char* ldsA1 = (char*)lds + s1 * 16;
    char* ldsB0 = (char*)lds + 8192 + s0 * 16;
    char* ldsB1 = (char*)lds + 8192 + s1 * 16;

    v4f acc[4][4] = {};
    const int l15 = lane & 15, l4 = lane >> 4;
    const int abase = (wr * 64 + l15) * 32 + l4 * 8;
    const int bbase = 4096 + (wc * 64 + l15) * 32 + l4 * 8;

    for (int k0 = 0; k0 < K; k0 += 32) {
        GL16(a0 + k0, ldsA0);
        GL16(a1 + k0, ldsA1);
        GL16(b0 + k0, ldsB0);
        GL16(b1 + k0, ldsB1);
        __syncthreads();
        v8bf af[4], bfr[4];
        #pragma unroll
        for (int m = 0; m < 4; ++m) af[m]  = *(const v8bf*)&lds[abase + m * 16 * 32];
        #pragma unroll
        for (int n = 0; n < 4; ++n) bfr[n] = *(const v8bf*)&lds[bbase + n * 16 * 32];
        #pragma unroll
        for (int m = 0; m < 4; ++m)
            #pragma unroll
            for (int n = 0; n < 4; ++n)
                acc[m][n] = __builtin_amdgcn_mfma_f32_16x16x32_bf16(af[m], bfr[n], acc[m][n], 0, 0, 0);
        __syncthreads();
    }

    #pragma unroll
    for (int m = 0; m < 4; ++m) {
        #pragma unroll
        for (int j = 0; j < 4; ++j) {
            int row = m0 + wr * 64 + m * 16 + l4 * 4 + j;
            if (row >= M) continue;
            #pragma unroll
            for (int n = 0; n < 4; ++n) {
                int col = n0 + wc * 64 + n * 16 + l15;
                if (col >= N) continue;
                float v = acc[m][n][j] + bias[col];
                if (do_elu) v = elu_f(v);
                if (out_bf16) ((__bf16*)C)[(size_t)row * N + col] = (__bf16)v;
                else          ((float*)C)[(size_t)row * N + col] = v;
            }
        }
    }
}

// ---------------- small fp32 GEMM, epilogue: v = (acc [+bias]) [*scale[m]] ---
__global__ void gemm_kernel(const float* __restrict__ A, const float* __restrict__ W,
                            const float* __restrict__ bias, const float* __restrict__ scale,
                            float* __restrict__ C, int M, int N, int K, int do_elu) {
    const int BM = 64, BN = 64, BK = 16;
    __shared__ float As[BK][BM + 4];
    __shared__ float Ws[BK][BN + 4];
    int tid = threadIdx.x;
    int tx = tid & 15, ty = tid >> 4;
    int m0 = blockIdx.x * BM;
    int n0 = blockIdx.y * BN;
    float acc[4][4] = {};
    for (int k0 = 0; k0 < K; k0 += BK) {
        #pragma unroll
        for (int l = 0; l < 4; ++l) {
            int idx = tid + l * 256;
            int r = idx >> 4, c = idx & 15;
            int m = m0 + r;
            As[c][r] = (m < M) ? A[(size_t)m * K + k0 + c] : 0.f;
        }
        #pragma unroll
        for (int l = 0; l < 4; ++l) {
            int idx = tid + l * 256;
            int c = idx >> 6, n = idx & 63;
            int nn = n0 + n;
            Ws[c][n] = (nn < N) ? W[(size_t)(k0 + c) * N + nn] : 0.f;
        }
        __syncthreads();
        #pragma unroll
        for (int kk = 0; kk < BK; ++kk) {
            float4 av = *(const float4*)&As[kk][ty * 4];
            float4 wv = *(const float4*)&Ws[kk][tx * 4];
            float ar[4] = {av.x, av.y, av.z, av.w};
            float wrg[4] = {wv.x, wv.y, wv.z, wv.w};
            #pragma unroll
            for (int i = 0; i < 4; ++i)
                #pragma unroll
                for (int j = 0; j < 4; ++j)
                    acc[i][j] += ar[i] * wrg[j];
        }
        __syncthreads();
    }
    #pragma unroll
    for (int i = 0; i < 4; ++i) {
        int m = m0 + ty * 4 + i;
        if (m >= M) continue;
        float sc = scale ? scale[m] : 1.f;
        #pragma unroll
        for (int j = 0; j < 4; ++j) {
            int n = n0 + tx * 4 + j;
            if (n >= N) continue;
            float v = acc[i][j] + (bias ? bias[n] : 0.f);
            if (do_elu) v = elu_f(v);
            C[(size_t)m * N + n] = v * sc;
        }
    }
}

// ---------------- CSR build: bucket scatter with atomic reservation ---------
// pass1: per-block LDS hist over NB1 bins -> one atomicAdd/bin reserves a run
// in the bin's fixed-capacity region of tmp -> coalesced packed writes.
__global__ void p1_scatter_kernel(const int* __restrict__ row, const int* __restrict__ col,
                                  int* __restrict__ fill196, unsigned int* __restrict__ tmp) {
    __shared__ int h[NB1], bl[NB1];
    int t = threadIdx.x, b = blockIdx.x;
    if (t < NB1) h[t] = 0;
    __syncthreads();
    int base = b * 4096;
    int cc[16];
    #pragma unroll
    for (int j = 0; j < 16; ++j) {
        int e = base + j * 256 + t;
        cc[j] = (e < N_EDGES) ? col[e] : -1;
        if (cc[j] >= 0) atomicAdd(&h[cc[j] >> 8], 1);
    }
    __syncthreads();
    if (t < NB1 && h[t] > 0) bl[t] = atomicAdd(&fill196[t], h[t]);
    __syncthreads();
    #pragma unroll
    for (int j = 0; j < 16; ++j) {
        if (cc[j] >= 0) {
            int e = base + j * 256 + t;
            int pos = atomicAdd(&bl[cc[j] >> 8], 1);
            tmp[pos] = ((unsigned int)cc[j] << 16) | (unsigned int)row[e];
        }
    }
}
// tiny scan of the 196 bin counts -> contiguous output bases
__global__ void scan196_kernel(const int* __restrict__ fill196, int* __restrict__ segbase,
                               int* __restrict__ ptr) {
    __shared__ int s[256];
    int t = threadIdx.x;
    int c = (t < NB1) ? (fill196[t] - t * CAP) : 0;
    s[t] = c;
    __syncthreads();
    for (int off = 1; off < 256; off <<= 1) {
        int u = (t >= off) ? s[t - off] : 0;
        __syncthreads();
        s[t] += u;
        __syncthreads();
    }
    if (t < NB1) segbase[t] = s[t] - c;
    if (t == 0) { segbase[NB1] = N_EDGES; ptr[N_NODES] = N_EDGES; }
}
// pass2: group by col&255 within bin; emit csr + ptr + dis
__global__ void p2_kernel(const unsigned int* __restrict__ tmp, const int* __restrict__ fill196,
                          const int* __restrict__ segbase, int* __restrict__ csr,
                          int* __restrict__ ptr, float* __restrict__ dis) {
    __shared__ int h2[256], b2[256], s2[256];
    int seg = blockIdx.x;
    int start = seg * CAP, end = fill196[seg];
    int outb = segbase[seg];
    int t = threadIdx.x;
    if (t < 256) h2[t] = 0;
    __syncthreads();
    for (int i = start + t; i < end; i += 1024)
        atomicAdd(&h2[(tmp[i] >> 16) & 255], 1);
    __syncthreads();
    if (t < 256) s2[t] = h2[t];
    __syncthreads();
    for (int off = 1; off < 256; off <<= 1) {
        int u = 0;
        if (t < 256 && t >= off) u = s2[t - off];
        __syncthreads();
        if (t < 256) s2[t] += u;
        __syncthreads();
    }
    if (t < 256) {
        int p = outb + s2[t] - h2[t];
        b2[t] = p;
        int node = (seg << 8) + t;
        if (node < N_NODES) {
            ptr[node] = p;
            dis[node] = rsqrtf((float)(h2[t] + 1));
        }
    }
    __syncthreads();
    for (int i = start + t; i < end; i += 1024) {
        unsigned int v = tmp[i];
        int pos = atomicAdd(&b2[(v >> 16) & 255], 1);
        csr[pos] = (int)(v & 0xFFFFu);
    }
}

// ---------------- CSR gather aggregation (float4/thread, 2x unroll) ---------
__global__ void gather_kernel(const float* __restrict__ xws, const int* __restrict__ csr,
                              const int* __restrict__ ptr, const float* __restrict__ dis,
                              const float* __restrict__ bias, float* __restrict__ out,
                              int f4shift, int do_elu) {
    int idx = blockIdx.x * 256 + threadIdx.x;
    int node = idx >> f4shift;
    if (node >= N_NODES) return;
    int q = idx & ((1 << f4shift) - 1);
    int s = ptr[node], e = ptr[node + 1];
    const float4* xw4 = (const float4*)xws;
    float4 acc = xw4[((size_t)node << f4shift) + q];  // self-loop
    int i = s;
    for (; i + 2 <= e; i += 2) {
        int r0 = csr[i], r1 = csr[i + 1];
        float4 va = xw4[((size_t)r0 << f4shift) + q];
        float4 vb = xw4[((size_t)r1 << f4shift) + q];
        acc.x += va.x + vb.x; acc.y += va.y + vb.y;
        acc.z += va.z + vb.z; acc.w += va.w + vb.w;
    }
    if (i < e) {
        int r = csr[i];
        float4 v = xw4[((size_t)r << f4shift) + q];
        acc.x += v.x; acc.y += v.y; acc.z += v.z; acc.w += v.w;
    }
    float d = dis[node];
    float4 bb = ((const float4*)bias)[q];
    float4 o;
    o.x = d * acc.x + bb.x; o.y = d * acc.y + bb.y;
    o.z = d * acc.z + bb.z; o.w = d * acc.w + bb.w;
    if (do_elu) { o.x = elu_f(o.x); o.y = elu_f(o.y); o.z = elu_f(o.z); o.w = elu_f(o.w); }
    ((float4*)out)[idx] = o;
}

extern "C" void kernel_launch(void* const* d_in, const int* in_sizes, int n_in,
                              void* d_out, int out_size, void* d_ws, size_t ws_size,
                              hipStream_t stream) {
    const float* x    = (const float*)d_in[0];
    const int*   ei   = (const int*)d_in[1];
    const int*   row  = ei;
    const int*   col  = ei + N_EDGES;
    const float* ln_w = (const float*)d_in[2];
    const float* ln_b = (const float*)d_in[3];
    const float* w0   = (const float*)d_in[4];
    const float* b0   = (const float*)d_in[5];
    const float* w1   = (const float*)d_in[6];
    const float* b1   = (const float*)d_in[7];
    const float* w2   = (const float*)d_in[8];
    const float* b2   = (const float*)d_in[9];
    const float* g1w  = (const float*)d_in[10];
    const float* g1b  = (const float*)d_in[11];
    const float* g2w  = (const float*)d_in[12];
    const float* g2b  = (const float*)d_in[13];
    float* out = (float*)d_out;

    char* W = (char*)d_ws;
    __bf16* h0  = (__bf16*)(W + 0);          // 50000*1024 bf16
    __bf16* h1  = (__bf16*)(W + 102400000);  // 50000*512 bf16
    __bf16* h2  = (__bf16*)(W + 153600000);  // 50000*128 bf16
    float*  h3  = (float*) (W + 166400000);  // 50000*64 f32
    float*  dis = (float*) (W + 179200000);  // 50000 f32
    float*  xw1 = (float*) (W + 179400192);  // 50000*32 f32 (dis-scaled)
    float*  agg1= (float*) (W + 185800192);  // 50000*32 f32
    float*  xw2 = (float*) (W + 192200192);  // 50000*16 f32 (dis-scaled)
    __bf16* w0t = (__bf16*)(W + 195400192);  // 512*1024 bf16
    __bf16* w1t = (__bf16*)(W + 196448768);  // 128*512 bf16
    __bf16* w2t = (__bf16*)(W + 196579840);  // 64*128 bf16
    // sort structures in their own region (ws ~1.6GB; no overlay needed)
    int*    csr  = (int*)(W + 200000000);    // 3.2M int
    int*    ptr  = (int*)(W + 213000192);    // 50001 int
    unsigned int* tmp = (unsigned int*)(W + 214000128);  // NB1*CAP u32 (16.06 MB)
    int*    fill196 = (int*)(W + 231000064); // 196 int
    int*    segbase = (int*)(W + 231001088); // 197 int

    // weight transposes + fill196 init (one dispatch)
    wt_all_kernel<<<(598016 + 255) / 256, 256, 0, stream>>>(w0, w1, w2, w0t, w1t, w2t, fill196);

    // 1. pool + layernorm -> bf16
    pool_ln_kernel<<<N_NODES, 256, 0, stream>>>(x, ln_w, ln_b, h0);

    // 2. GEMM0 (h0 -> h1), 128x256 tile
    {
        dim3 g((N_NODES + 127) / 128, 2);
        mfma_gemm0<<<g, 512, 0, stream>>>(h0, w0t, b0, h1, N_NODES);
    }

    // 3. CSR build: reservation scatter -> tiny scan -> p2 (also ptr + dis)
    p1_scatter_kernel<<<NBLK1, 256, 0, stream>>>(row, col, fill196, tmp);
    scan196_kernel<<<1, 256, 0, stream>>>(fill196, segbase, ptr);
    p2_kernel<<<NB1, 1024, 0, stream>>>(tmp, fill196, segbase, csr, ptr, dis);

    // 4. rest of MLP
    {
        dim3 g((N_NODES + 127) / 128, 1);
        mfma_gemm<<<g, 256, 0, stream>>>(h1, w1t, b1, h2, N_NODES, 128, 512, 1, 1);
    }
    {
        dim3 g((N_NODES + 127) / 128, 1);
        mfma_gemm<<<g, 256, 0, stream>>>(h2, w2t, b2, h3, N_NODES, 64, 128, 1, 0);
    }

    // 5. GCN1: xw1 = dis[r] * (h3 @ g1w); gather; +bias, ELU
    {
        dim3 g((N_NODES + 63) / 64, 1);
        gemm_kernel<<<g, 256, 0, stream>>>(h3, g1w, nullptr, dis, xw1, N_NODES, 32, 64, 0);
    }
    gather_kernel<<<((N_NODES * 8) + 255) / 256, 256, 0, stream>>>(
        xw1, csr, ptr, dis, g1b, agg1, 3, 1);

    // 6. GCN2: xw2 = dis[r] * (agg1 @ g2w); gather into out; +bias
    {
        dim3 g((N_NODES + 63) / 64, 1);
        gemm_kernel<<<g, 256, 0, stream>>>(agg1, g2w, nullptr, dis, xw2, N_NODES, 16, 32, 0);
    }
    gather_kernel<<<((N_NODES * 4) + 255) / 256, 256, 0, stream>>>(
        xw2, csr, ptr, dis, g2b, out, 2, 0);
}

// Round 8
// 405.795 us; speedup vs baseline: 2.3139x; 1.0736x over previous
//
#include <hip/hip_runtime.h>
#include <hip/hip_bf16.h>

#define N_NODES 50000
#define N_EDGES 3200000
#define NB1 196            // (N_NODES-1)>>8 + 1
#define NBLK1 782          // ceil(N_EDGES/4096)
#define CAP 20480          // per-bin tmp capacity (avg 16327, sigma ~128)

typedef __bf16 v8bf __attribute__((ext_vector_type(8)));
typedef __bf16 v2bf __attribute__((ext_vector_type(2)));
typedef float v4f __attribute__((ext_vector_type(4)));

__device__ __forceinline__ float elu_f(float x) { return x > 0.f ? x : (expf(x) - 1.f); }

// async global->LDS, 16B per lane; LDS dest = wave-uniform base + lane*16
#define GL16(gp, lp) __builtin_amdgcn_global_load_lds( \
    (const __attribute__((address_space(1))) void*)(gp), \
    (__attribute__((address_space(3))) void*)(lp), 16, 0, 0)

// ---------------- fused maxpool(2) + LayerNorm(1024) -> bf16 ----------------
// one WAVE per node; lane i, iter j reads float4 at elem j*256+i*4 (coalesced
// 1KB/instr, 8 loads in flight); wave-only shfl reduction, no LDS/barriers.
__global__ void pool_ln_kernel(const float* __restrict__ x,
                               const float* __restrict__ ln_w,
                               const float* __restrict__ ln_b,
                               __bf16* __restrict__ h0) {
    int wave = threadIdx.x >> 6, lane = threadIdx.x & 63;
    int node = blockIdx.x * 4 + wave;
    const float4* xr = (const float4*)(x + (size_t)node * 2048);
    float4 v[8];
    #pragma unroll
    for (int j = 0; j < 8; ++j) v[j] = xr[j * 64 + lane];
    float p[16];
    float sum = 0.f, sq = 0.f;
    #pragma unroll
    for (int j = 0; j < 8; ++j) {
        p[2 * j]     = fmaxf(v[j].x, v[j].y);
        p[2 * j + 1] = fmaxf(v[j].z, v[j].w);
        sum += p[2 * j] + p[2 * j + 1];
        sq  += p[2 * j] * p[2 * j] + p[2 * j + 1] * p[2 * j + 1];
    }
    #pragma unroll
    for (int off = 32; off > 0; off >>= 1) {
        sum += __shfl_xor(sum, off);
        sq  += __shfl_xor(sq, off);
    }
    float mu = sum * (1.f / 1024.f);
    float var = sq * (1.f / 1024.f) - mu * mu;
    float rstd = rsqrtf(var + 1e-5f);
    const float2* w2p = (const float2*)ln_w;
    const float2* b2p = (const float2*)ln_b;
    #pragma unroll
    for (int j = 0; j < 8; ++j) {
        int c2 = j * 64 + lane;          // pooled pair index (col = 2*c2)
        float2 w = w2p[c2], b = b2p[c2];
        v2bf o;
        o[0] = (__bf16)((p[2 * j]     - mu) * rstd * w.x + b.x);
        o[1] = (__bf16)((p[2 * j + 1] - mu) * rstd * w.y + b.y);
        *(v2bf*)(h0 + (size_t)node * 1024 + 2 * c2) = o;
    }
}

// ---------------- all 3 weight transposes + fill196 init (one dispatch) -----
__global__ void wt_all_kernel(const float* __restrict__ w0, const float* __restrict__ w1,
                              const float* __restrict__ w2,
                              __bf16* __restrict__ w0t, __bf16* __restrict__ w1t,
                              __bf16* __restrict__ w2t, int* __restrict__ fill196) {
    int idx = blockIdx.x * 256 + threadIdx.x;
    if (idx < NB1) fill196[idx] = idx * CAP;
    if (idx < 524288) {            // w0: 1024x512
        int k = idx >> 9, n = idx & 511;
        w0t[(size_t)n * 1024 + k] = (__bf16)w0[idx];
    } else if (idx < 524288 + 65536) {  // w1: 512x128
        int j = idx - 524288;
        int k = j >> 7, n = j & 127;
        w1t[(size_t)n * 512 + k] = (__bf16)w1[j];
    } else if (idx < 524288 + 65536 + 8192) {  // w2: 128x64
        int j = idx - 524288 - 65536;
        int k = j >> 6, n = j & 63;
        w2t[(size_t)n * 128 + k] = (__bf16)w2[j];
    }
}

// ---------------- GEMM0: 128x256 tile, 512 threads (8 waves 2x4), K=1024 ----
__global__ __launch_bounds__(512) void mfma_gemm0(
    const __bf16* __restrict__ A, const __bf16* __restrict__ BT,
    const float* __restrict__ bias, __bf16* __restrict__ C, int M)
{
    const int K = 1024, N = 512;
    __shared__ unsigned short lds[12288];  // A:[0,4096) shorts, B:[4096,12288)
    const int tid = threadIdx.x;
    const int lane = tid & 63, w = tid >> 6;
    const int wr = w >> 2, wc = w & 3;
    const int m0 = blockIdx.x * 128, n0 = blockIdx.y * 256;

    int grA = m0 + (tid >> 2); if (grA > M - 1) grA = M - 1;
    const __bf16* aP = A + (size_t)grA * K + (tid & 3) * 8;
    char* ldsA = (char*)lds + tid * 16;
    const __bf16* bP0 = BT + (size_t)(n0 + (tid >> 2)) * K + (tid & 3) * 8;
    const __bf16* bP1 = BT + (size_t)(n0 + ((tid + 512) >> 2)) * K + (tid & 3) * 8;
    char* ldsB0 = (char*)lds + 8192 + tid * 16;
    char* ldsB1 = (char*)lds + 16384 + tid * 16;

    v4f acc[4][4] = {};
    const int l15 = lane & 15, l4 = lane >> 4;
    const int abase = (wr * 64 + l15) * 32 + l4 * 8;
    const int bbase = 4096 + (wc * 64 + l15) * 32 + l4 * 8;

    for (int k0 = 0; k0 < K; k0 += 32) {
        GL16(aP + k0, ldsA);
        GL16(bP0 + k0, ldsB0);
        GL16(bP1 + k0, ldsB1);
        __syncthreads();
        v8bf af[4], bfr[4];
        #pragma unroll
        for (int m = 0; m < 4; ++m) af[m]  = *(const v8bf*)&lds[abase + m * 16 * 32];
        #pragma unroll
        for (int n = 0; n < 4; ++n) bfr[n] = *(const v8bf*)&lds[bbase + n * 16 * 32];
        #pragma unroll
        for (int m = 0; m < 4; ++m)
            #pragma unroll
            for (int n = 0; n < 4; ++n)
                acc[m][n] = __builtin_amdgcn_mfma_f32_16x16x32_bf16(af[m], bfr[n], acc[m][n], 0, 0, 0);
        __syncthreads();
    }

    #pragma unroll
    for (int m = 0; m < 4; ++m) {
        #pragma unroll
        for (int j = 0; j < 4; ++j) {
            int row = m0 + wr * 64 + m * 16 + l4 * 4 + j;
            if (row >= M) continue;
            #pragma unroll
            for (int n = 0; n < 4; ++n) {
                int col = n0 + wc * 64 + n * 16 + l15;
                float v = acc[m][n][j] + bias[col];
                C[(size_t)row * N + col] = (__bf16)elu_f(v);
            }
        }
    }
}

// ---------------- fused MLP tail: h1 -> xw1 = dis * (elu(elu(h1@W1)@W2) @ g1w)
// Per block: 128 rows. Stage A: GEMM1 (MFMA, K=512) -> T bf16 LDS (swizzled).
// Stage B: GEMM2 (MFMA from LDS, K=128, w2t from L2) -> H3 f32 LDS (swizzled).
// Stage C: fp32 VALU 64->32 with dis scale -> xw1.
// LDS: [0,32768) staging(first 16KB) then H3; [32768,40960) g1w; [40960,73728) T
__global__ __launch_bounds__(256) void mlp_tail_kernel(
    const __bf16* __restrict__ h1, const __bf16* __restrict__ w1t,
    const float* __restrict__ b1, const __bf16* __restrict__ w2t,
    const float* __restrict__ b2, const float* __restrict__ g1w,
    const float* __restrict__ dis, float* __restrict__ xw1, int M)
{
    extern __shared__ char smem[];
    const int G1OFF = 32768, TOFF = 40960;
    const int tid = threadIdx.x;
    const int lane = tid & 63, wave = tid >> 6;
    const int l15 = lane & 15, l4 = lane >> 4;
    const int m0 = blockIdx.x * 128;

    // stage g1w (64x32 f32 = 8KB) into LDS
    {
        const float4* g4 = (const float4*)g1w;
        float4* d4 = (float4*)(smem + G1OFF);
        d4[tid] = g4[tid];
        d4[tid + 256] = g4[tid + 256];
    }

    // ---- stage A: GEMM1 rows m0..m0+127, N=128, K=512 ----
    const int wr = wave >> 1, wc = wave & 1;
    const int s0 = tid, s1 = tid + 256;
    int gr0 = m0 + (s0 >> 2); if (gr0 > M - 1) gr0 = M - 1;
    int gr1 = m0 + (s1 >> 2); if (gr1 > M - 1) gr1 = M - 1;
    const __bf16* a0p = h1 + (size_t)gr0 * 512 + (s0 & 3) * 8;
    const __bf16* a1p = h1 + (size_t)gr1 * 512 + (s1 & 3) * 8;
    const __bf16* b0p = w1t + (size_t)(s0 >> 2) * 512 + (s0 & 3) * 8;
    const __bf16* b1p = w1t + (size_t)(s1 >> 2) * 512 + (s1 & 3) * 8;
    char* stA0 = smem + s0 * 16;
    char* stA1 = smem + s1 * 16;
    char* stB0 = smem + 8192 + s0 * 16;
    char* stB1 = smem + 8192 + s1 * 16;
    const int aoff = (wr * 64 + l15) * 64 + l4 * 16;
    const int boff = 8192 + (wc * 64 + l15) * 64 + l4 * 16;

    v4f acc1[4][4] = {};
    for (int k0 = 0; k0 < 512; k0 += 32) {
        GL16(a0p + k0, stA0);
        GL16(a1p + k0, stA1);
        GL16(b0p + k0, stB0);
        GL16(b1p + k0, stB1);
        __syncthreads();
        v8bf af[4], bfr[4];
        #pragma unroll
        for (int m = 0; m < 4; ++m) af[m]  = *(const v8bf*)(smem + aoff + m * 1024);
        #pragma unroll
        for (int n = 0; n < 4; ++n) bfr[n] = *(const v8bf*)(smem + boff + n * 1024);
        #pragma unroll
        for (int m = 0; m < 4; ++m)
            #pragma unroll
            for (int n = 0; n < 4; ++n)
                acc1[m][n] = __builtin_amdgcn_mfma_f32_16x16x32_bf16(af[m], bfr[n], acc1[m][n], 0, 0, 0);
        __syncthreads();
    }
    // bias+ELU -> T bf16 (swizzled: byte ^= (row&7)<<4)
    float b1c[4];
    #pragma unroll
    for (int n = 0; n < 4; ++n) b1c[n] = b1[wc * 64 + n * 16 + l15];
    #pragma unroll
    for (int m = 0; m < 4; ++m) {
        #pragma unroll
        for (int j = 0; j < 4; ++j) {
            int row = wr * 64 + m * 16 + l4 * 4 + j;
            int rx = (row & 7) << 4;
            #pragma unroll
            for (int n = 0; n < 4; ++n) {
                int colb = (wc * 64 + n * 16 + l15) * 2;
                float v = elu_f(acc1[m][n][j] + b1c[n]);
                *(__bf16*)(smem + TOFF + row * 256 + (colb ^ rx)) = (__bf16)v;
            }
        }
    }
    __syncthreads();

    // ---- stage B: GEMM2 128x64, K=128, A from T, B=w2t from global/L2 ----
    const int wr2 = wave >> 1, wc2 = wave & 1;
    v4f acc2[4][2] = {};
    #pragma unroll
    for (int ks = 0; ks < 4; ++ks) {
        v8bf af2[4], bf2[2];
        #pragma unroll
        for (int m2 = 0; m2 < 4; ++m2) {
            int row = wr2 * 64 + m2 * 16 + l15;
            af2[m2] = *(const v8bf*)(smem + TOFF + row * 256 + ((ks * 64 + l4 * 16) ^ ((row & 7) << 4)));
        }
        #pragma unroll
        for (int n2 = 0; n2 < 2; ++n2) {
            int nn = wc2 * 32 + n2 * 16 + l15;
            bf2[n2] = *(const v8bf*)(w2t + nn * 128 + ks * 32 + l4 * 8);
        }
        #pragma unroll
        for (int m2 = 0; m2 < 4; ++m2)
            #pragma unroll
            for (int n2 = 0; n2 < 2; ++n2)
                acc2[m2][n2] = __builtin_amdgcn_mfma_f32_16x16x32_bf16(af2[m2], bf2[n2], acc2[m2][n2], 0, 0, 0);
    }
    __syncthreads();  // staging region fully dead; H3 overlays it
    // bias+ELU -> H3 f32 (swizzled)
    float b2c[2];
    #pragma unroll
    for (int n2 = 0; n2 < 2; ++n2) b2c[n2] = b2[wc2 * 32 + n2 * 16 + l15];
    #pragma unroll
    for (int m2 = 0; m2 < 4; ++m2) {
        #pragma unroll
        for (int j = 0; j < 4; ++j) {
            int row = wr2 * 64 + m2 * 16 + l4 * 4 + j;
            int rx = (row & 7) << 4;
            #pragma unroll
            for (int n2 = 0; n2 < 2; ++n2) {
                int col = wc2 * 32 + n2 * 16 + l15;
                float v = elu_f(acc2[m2][n2][j] + b2c[n2]);
                *(float*)(smem + row * 256 + ((col * 4) ^ rx)) = v;
            }
        }
    }
    __syncthreads();

    // ---- stage C: xw1[r][n] = dis * sum_k H3[r][k] * g1w[k][n] ----
    int r = tid >> 1;
    int nb = (tid & 1) * 16;
    int gr = m0 + r;
    float o[16] = {};
    int rx = (r & 7) << 4;
    #pragma unroll 4
    for (int k4 = 0; k4 < 16; ++k4) {
        float4 h4 = *(const float4*)(smem + r * 256 + ((k4 * 16) ^ rx));
        #pragma unroll
        for (int e = 0; e < 4; ++e) {
            const float4* gp = (const float4*)(smem + G1OFF + (k4 * 4 + e) * 128 + nb * 4);
            float hv = (e == 0) ? h4.x : (e == 1) ? h4.y : (e == 2) ? h4.z : h4.w;
            #pragma unroll
            for (int q = 0; q < 4; ++q) {
                float4 g = gp[q];
                o[4 * q + 0] += hv * g.x;
                o[4 * q + 1] += hv * g.y;
                o[4 * q + 2] += hv * g.z;
                o[4 * q + 3] += hv * g.w;
            }
        }
    }
    if (gr < M) {
        float d = dis[gr];
        #pragma unroll
        for (int q = 0; q < 4; ++q) {
            float4 v;
            v.x = o[4 * q + 0] * d; v.y = o[4 * q + 1] * d;
            v.z = o[4 * q + 2] * d; v.w = o[4 * q + 3] * d;
            *(float4*)(xw1 + (size_t)gr * 32 + nb + 4 * q) = v;
        }
    }
}

// ---------------- small fp32 GEMM, epilogue: v = (acc [+bias]) [*scale[m]] ---
__global__ void gemm_kernel(const float* __restrict__ A, const float* __restrict__ W,
                            const float* __restrict__ bias, const float* __restrict__ scale,
                            float* __restrict__ C, int M, int N, int K, int do_elu) {
    const int BM = 64, BN = 64, BK = 16;
    __shared__ float As[BK][BM + 4];
    __shared__ float Ws[BK][BN + 4];
    int tid = threadIdx.x;
    int tx = tid & 15, ty = tid >> 4;
    int m0 = blockIdx.x * BM;
    int n0 = blockIdx.y * BN;
    float acc[4][4] = {};
    for (int k0 = 0; k0 < K; k0 += BK) {
        #pragma unroll
        for (int l = 0; l < 4; ++l) {
            int idx = tid + l * 256;
            int r = idx >> 4, c = idx & 15;
            int m = m0 + r;
            As[c][r] = (m < M) ? A[(size_t)m * K + k0 + c] : 0.f;
        }
        #pragma unroll
        for (int l = 0; l < 4; ++l) {
            int idx = tid + l * 256;
            int c = idx >> 6, n = idx & 63;
            int nn = n0 + n;
            Ws[c][n] = (nn < N) ? W[(size_t)(k0 + c) * N + nn] : 0.f;
        }
        __syncthreads();
        #pragma unroll
        for (int kk = 0; kk < BK; ++kk) {
            float4 av = *(const float4*)&As[kk][ty * 4];
            float4 wv = *(const float4*)&Ws[kk][tx * 4];
            float ar[4] = {av.x, av.y, av.z, av.w};
            float wrg[4] = {wv.x, wv.y, wv.z, wv.w};
            #pragma unroll
            for (int i = 0; i < 4; ++i)
                #pragma unroll
                for (int j = 0; j < 4; ++j)
                    acc[i][j] += ar[i] * wrg[j];
        }
        __syncthreads();
    }
    #pragma unroll
    for (int i = 0; i < 4; ++i) {
        int m = m0 + ty * 4 + i;
        if (m >= M) continue;
        float sc = scale ? scale[m] : 1.f;
        #pragma unroll
        for (int j = 0; j < 4; ++j) {
            int n = n0 + tx * 4 + j;
            if (n >= N) continue;
            float v = acc[i][j] + (bias ? bias[n] : 0.f);
            if (do_elu) v = elu_f(v);
            C[(size_t)m * N + n] = v * sc;
        }
    }
}

// ---------------- CSR build: bucket scatter with atomic reservation ---------
__global__ void p1_scatter_kernel(const int* __restrict__ row, const int* __restrict__ col,
                                  int* __restrict__ fill196, unsigned int* __restrict__ tmp) {
    __shared__ int h[NB1], bl[NB1];
    int t = threadIdx.x, b = blockIdx.x;
    if (t < NB1) h[t] = 0;
    __syncthreads();
    int base = b * 4096;
    int cc[16];
    #pragma unroll
    for (int j = 0; j < 16; ++j) {
        int e = base + j * 256 + t;
        cc[j] = (e < N_EDGES) ? col[e] : -1;
        if (cc[j] >= 0) atomicAdd(&h[cc[j] >> 8], 1);
    }
    __syncthreads();
    if (t < NB1 && h[t] > 0) bl[t] = atomicAdd(&fill196[t], h[t]);
    __syncthreads();
    #pragma unroll
    for (int j = 0; j < 16; ++j) {
        if (cc[j] >= 0) {
            int e = base + j * 256 + t;
            int pos = atomicAdd(&bl[cc[j] >> 8], 1);
            tmp[pos] = ((unsigned int)cc[j] << 16) | (unsigned int)row[e];
        }
    }
}
// pass2: group by col&255 within bin; computes own output base; emits csr+ptr+dis
__global__ void p2_kernel(const unsigned int* __restrict__ tmp, const int* __restrict__ fill196,
                          int* __restrict__ csr, int* __restrict__ ptr, float* __restrict__ dis) {
    __shared__ int h2[256], b2[256], s2[256];
    __shared__ int sh_outb;
    int seg = blockIdx.x;
    int start = seg * CAP, end = fill196[seg];
    int t = threadIdx.x;
    // outb = sum of counts of segments before this one
    if (t < 256) s2[t] = (t < seg) ? (fill196[t] - t * CAP) : 0;
    __syncthreads();
    for (int off = 128; off > 0; off >>= 1) {
        if (t < off) s2[t] += s2[t + off];
        __syncthreads();
    }
    if (t == 0) sh_outb = s2[0];
    if (t < 256) h2[t] = 0;
    __syncthreads();
    for (int i = start + t; i < end; i += 1024)
        atomicAdd(&h2[(tmp[i] >> 16) & 255], 1);
    __syncthreads();
    if (t < 256) s2[t] = h2[t];
    __syncthreads();
    for (int off = 1; off < 256; off <<= 1) {
        int u = 0;
        if (t < 256 && t >= off) u = s2[t - off];
        __syncthreads();
        if (t < 256) s2[t] += u;
        __syncthreads();
    }
    if (t < 256) {
        int p = sh_outb + s2[t] - h2[t];
        b2[t] = p;
        int node = (seg << 8) + t;
        if (node < N_NODES) {
            ptr[node] = p;
            dis[node] = rsqrtf((float)(h2[t] + 1));
        }
    }
    if (seg == NB1 - 1 && t == 0) ptr[N_NODES] = N_EDGES;
    __syncthreads();
    for (int i = start + t; i < end; i += 1024) {
        unsigned int v = tmp[i];
        int pos = atomicAdd(&b2[(v >> 16) & 255], 1);
        csr[pos] = (int)(v & 0xFFFFu);
    }
}

// ---------------- CSR gather aggregation (float4/thread, 4x unroll) ---------
__global__ void gather_kernel(const float* __restrict__ xws, const int* __restrict__ csr,
                              const int* __restrict__ ptr, const float* __restrict__ dis,
                              const float* __restrict__ bias, float* __restrict__ out,
                              int f4shift, int do_elu) {
    int idx = blockIdx.x * 256 + threadIdx.x;
    int node = idx >> f4shift;
    if (node >= N_NODES) return;
    int q = idx & ((1 << f4shift) - 1);
    int s = ptr[node], e = ptr[node + 1];
    const float4* xw4 = (const float4*)xws;
    float4 acc = xw4[((size_t)node << f4shift) + q];  // self-loop
    int i = s;
    for (; i + 4 <= e; i += 4) {
        int r0 = csr[i], r1 = csr[i + 1], r2 = csr[i + 2], r3 = csr[i + 3];
        float4 va = xw4[((size_t)r0 << f4shift) + q];
        float4 vb = xw4[((size_t)r1 << f4shift) + q];
        float4 vc = xw4[((size_t)r2 << f4shift) + q];
        float4 vd = xw4[((size_t)r3 << f4shift) + q];
        acc.x += (va.x + vb.x) + (vc.x + vd.x);
        acc.y += (va.y + vb.y) + (vc.y + vd.y);
        acc.z += (va.z + vb.z) + (vc.z + vd.z);
        acc.w += (va.w + vb.w) + (vc.w + vd.w);
    }
    for (; i < e; ++i) {
        int r = csr[i];
        float4 v = xw4[((size_t)r << f4shift) + q];
        acc.x += v.x; acc.y += v.y; acc.z += v.z; acc.w += v.w;
    }
    float d = dis[node];
    float4 bb = ((const float4*)bias)[q];
    float4 o;
    o.x = d * acc.x + bb.x; o.y = d * acc.y + bb.y;
    o.z = d * acc.z + bb.z; o.w = d * acc.w + bb.w;
    if (do_elu) { o.x = elu_f(o.x); o.y = elu_f(o.y); o.z = elu_f(o.z); o.w = elu_f(o.w); }
    ((float4*)out)[idx] = o;
}

extern "C" void kernel_launch(void* const* d_in, const int* in_sizes, int n_in,
                              void* d_out, int out_size, void* d_ws, size_t ws_size,
                              hipStream_t stream) {
    const float* x    = (const float*)d_in[0];
    const int*   ei   = (const int*)d_in[1];
    const int*   row  = ei;
    const int*   col  = ei + N_EDGES;
    const float* ln_w = (const float*)d_in[2];
    const float* ln_b = (const float*)d_in[3];
    const float* w0   = (const float*)d_in[4];
    const float* b0   = (const float*)d_in[5];
    const float* w1   = (const float*)d_in[6];
    const float* b1   = (const float*)d_in[7];
    const float* w2   = (const float*)d_in[8];
    const float* b2   = (const float*)d_in[9];
    const float* g1w  = (const float*)d_in[10];
    const float* g1b  = (const float*)d_in[11];
    const float* g2w  = (const float*)d_in[12];
    const float* g2b  = (const float*)d_in[13];
    float* out = (float*)d_out;

    char* W = (char*)d_ws;
    __bf16* h0  = (__bf16*)(W + 0);          // 50000*1024 bf16
    __bf16* h1  = (__bf16*)(W + 102400000);  // 50000*512 bf16
    float*  dis = (float*) (W + 179200000);  // 50000 f32
    float*  xw1 = (float*) (W + 179400192);  // 50000*32 f32 (dis-scaled)
    float*  agg1= (float*) (W + 185800192);  // 50000*32 f32
    float*  xw2 = (float*) (W + 192200192);  // 50000*16 f32 (dis-scaled)
    __bf16* w0t = (__bf16*)(W + 195400192);  // 512*1024 bf16
    __bf16* w1t = (__bf16*)(W + 196448768);  // 128*512 bf16
    __bf16* w2t = (__bf16*)(W + 196579840);  // 64*128 bf16
    int*    csr  = (int*)(W + 200000000);    // 3.2M int
    int*    ptr  = (int*)(W + 213000192);    // 50001 int
    unsigned int* tmp = (unsigned int*)(W + 214000128);  // NB1*CAP u32 (16.06 MB)
    int*    fill196 = (int*)(W + 231000064); // 196 int

    // weight transposes + fill196 init
    wt_all_kernel<<<(598016 + 255) / 256, 256, 0, stream>>>(w0, w1, w2, w0t, w1t, w2t, fill196);

    // 1. pool + layernorm -> bf16 (wave per node)
    pool_ln_kernel<<<N_NODES / 4, 256, 0, stream>>>(x, ln_w, ln_b, h0);

    // 2. GEMM0 (h0 -> h1), 128x256 tile
    {
        dim3 g((N_NODES + 127) / 128, 2);
        mfma_gemm0<<<g, 512, 0, stream>>>(h0, w0t, b0, h1, N_NODES);
    }

    // 3. CSR build: reservation scatter -> p2 (csr + ptr + dis)
    p1_scatter_kernel<<<NBLK1, 256, 0, stream>>>(row, col, fill196, tmp);
    p2_kernel<<<NB1, 1024, 0, stream>>>(tmp, fill196, csr, ptr, dis);

    // 4. fused MLP tail: h1 -> xw1 (GEMM1 + GEMM2 + g1w transform + dis scale)
    mlp_tail_kernel<<<(N_NODES + 127) / 128, 256, 73728, stream>>>(
        h1, w1t, b1, w2t, b2, g1w, dis, xw1, N_NODES);

    // 5. GCN1 gather; +bias, ELU
    gather_kernel<<<((N_NODES * 8) + 255) / 256, 256, 0, stream>>>(
        xw1, csr, ptr, dis, g1b, agg1, 3, 1);

    // 6. GCN2: xw2 = dis[r] * (agg1 @ g2w); gather into out; +bias
    {
        dim3 g((N_NODES + 63) / 64, 1);
        gemm_kernel<<<g, 256, 0, stream>>>(agg1, g2w, nullptr, dis, xw2, N_NODES, 16, 32, 0);
    }
    gather_kernel<<<((N_NODES * 4) + 255) / 256, 256, 0, stream>>>(
        xw2, csr, ptr, dis, g2b, out, 2, 0);
}

// Round 9
// 376.744 us; speedup vs baseline: 2.4924x; 1.0771x over previous
//
#include <hip/hip_runtime.h>
#include <hip/hip_bf16.h>

#define N_NODES 50000
#define N_EDGES 3200000
#define NB1 196            // (N_NODES-1)>>8 + 1
#define NBLK1 782          // ceil(N_EDGES/4096)
#define CAP 20480          // per-bin tmp capacity (avg 16327, sigma ~128)

typedef __bf16 v8bf __attribute__((ext_vector_type(8)));
typedef __bf16 v2bf __attribute__((ext_vector_type(2)));
typedef float v4f __attribute__((ext_vector_type(4)));

__device__ __forceinline__ float elu_f(float x) { return x > 0.f ? x : (expf(x) - 1.f); }

__device__ __forceinline__ float4 bf4f(ushort4 u) {
    float4 r;
    r.x = __uint_as_float(((unsigned)u.x) << 16);
    r.y = __uint_as_float(((unsigned)u.y) << 16);
    r.z = __uint_as_float(((unsigned)u.z) << 16);
    r.w = __uint_as_float(((unsigned)u.w) << 16);
    return r;
}

// async global->LDS, 16B per lane; LDS dest = wave-uniform base + lane*16
#define GL16(gp, lp) __builtin_amdgcn_global_load_lds( \
    (const __attribute__((address_space(1))) void*)(gp), \
    (__attribute__((address_space(3))) void*)(lp), 16, 0, 0)

// ---------------- fused maxpool(2)+LayerNorm -> bf16 ; + weight prep --------
// one WAVE per node; lane i iter j reads float4 at elem j*256+i*4 (coalesced).
// First 2336 blocks also transpose w0/w1/w2 -> bf16 and init fill196 (hidden
// under the 409MB x stream).
__global__ void pool_ln_kernel(const float* __restrict__ x,
                               const float* __restrict__ ln_w,
                               const float* __restrict__ ln_b,
                               __bf16* __restrict__ h0,
                               const float* __restrict__ w0, const float* __restrict__ w1,
                               const float* __restrict__ w2,
                               __bf16* __restrict__ w0t, __bf16* __restrict__ w1t,
                               __bf16* __restrict__ w2t, int* __restrict__ fill196) {
    int t = threadIdx.x;
    // --- weight-prep side work ---
    if (blockIdx.x < 2336) {
        int idx = blockIdx.x * 256 + t;
        if (idx < NB1) fill196[idx] = idx * CAP;
        if (idx < 524288) {            // w0: 1024x512
            int k = idx >> 9, n = idx & 511;
            w0t[(size_t)n * 1024 + k] = (__bf16)w0[idx];
        } else if (idx < 524288 + 65536) {  // w1: 512x128
            int j = idx - 524288;
            int k = j >> 7, n = j & 127;
            w1t[(size_t)n * 512 + k] = (__bf16)w1[j];
        } else if (idx < 524288 + 65536 + 8192) {  // w2: 128x64
            int j = idx - 524288 - 65536;
            int k = j >> 6, n = j & 63;
            w2t[(size_t)n * 128 + k] = (__bf16)w2[j];
        }
    }
    // --- pool + LN ---
    int wave = t >> 6, lane = t & 63;
    int node = blockIdx.x * 4 + wave;
    const float4* xr = (const float4*)(x + (size_t)node * 2048);
    float4 v[8];
    #pragma unroll
    for (int j = 0; j < 8; ++j) v[j] = xr[j * 64 + lane];
    float p[16];
    float sum = 0.f, sq = 0.f;
    #pragma unroll
    for (int j = 0; j < 8; ++j) {
        p[2 * j]     = fmaxf(v[j].x, v[j].y);
        p[2 * j + 1] = fmaxf(v[j].z, v[j].w);
        sum += p[2 * j] + p[2 * j + 1];
        sq  += p[2 * j] * p[2 * j] + p[2 * j + 1] * p[2 * j + 1];
    }
    #pragma unroll
    for (int off = 32; off > 0; off >>= 1) {
        sum += __shfl_xor(sum, off);
        sq  += __shfl_xor(sq, off);
    }
    float mu = sum * (1.f / 1024.f);
    float var = sq * (1.f / 1024.f) - mu * mu;
    float rstd = rsqrtf(var + 1e-5f);
    const float2* w2p = (const float2*)ln_w;
    const float2* b2p = (const float2*)ln_b;
    #pragma unroll
    for (int j = 0; j < 8; ++j) {
        int c2 = j * 64 + lane;          // pooled pair index (col = 2*c2)
        float2 w = w2p[c2], b = b2p[c2];
        v2bf o;
        o[0] = (__bf16)((p[2 * j]     - mu) * rstd * w.x + b.x);
        o[1] = (__bf16)((p[2 * j + 1] - mu) * rstd * w.y + b.y);
        *(v2bf*)(h0 + (size_t)node * 1024 + 2 * c2) = o;
    }
}

// ---------------- GEMM0: 128x256 tile, 512 threads (8 waves 2x4), K=1024 ----
__global__ __launch_bounds__(512) void mfma_gemm0(
    const __bf16* __restrict__ A, const __bf16* __restrict__ BT,
    const float* __restrict__ bias, __bf16* __restrict__ C, int M)
{
    const int K = 1024, N = 512;
    __shared__ unsigned short lds[12288];  // A:[0,4096) shorts, B:[4096,12288)
    const int tid = threadIdx.x;
    const int lane = tid & 63, w = tid >> 6;
    const int wr = w >> 2, wc = w & 3;
    const int m0 = blockIdx.x * 128, n0 = blockIdx.y * 256;

    int grA = m0 + (tid >> 2); if (grA > M - 1) grA = M - 1;
    const __bf16* aP = A + (size_t)grA * K + (tid & 3) * 8;
    char* ldsA = (char*)lds + tid * 16;
    const __bf16* bP0 = BT + (size_t)(n0 + (tid >> 2)) * K + (tid & 3) * 8;
    const __bf16* bP1 = BT + (size_t)(n0 + ((tid + 512) >> 2)) * K + (tid & 3) * 8;
    char* ldsB0 = (char*)lds + 8192 + tid * 16;
    char* ldsB1 = (char*)lds + 16384 + tid * 16;

    v4f acc[4][4] = {};
    const int l15 = lane & 15, l4 = lane >> 4;
    const int abase = (wr * 64 + l15) * 32 + l4 * 8;
    const int bbase = 4096 + (wc * 64 + l15) * 32 + l4 * 8;

    for (int k0 = 0; k0 < K; k0 += 32) {
        GL16(aP + k0, ldsA);
        GL16(bP0 + k0, ldsB0);
        GL16(bP1 + k0, ldsB1);
        __syncthreads();
        v8bf af[4], bfr[4];
        #pragma unroll
        for (int m = 0; m < 4; ++m) af[m]  = *(const v8bf*)&lds[abase + m * 16 * 32];
        #pragma unroll
        for (int n = 0; n < 4; ++n) bfr[n] = *(const v8bf*)&lds[bbase + n * 16 * 32];
        #pragma unroll
        for (int m = 0; m < 4; ++m)
            #pragma unroll
            for (int n = 0; n < 4; ++n)
                acc[m][n] = __builtin_amdgcn_mfma_f32_16x16x32_bf16(af[m], bfr[n], acc[m][n], 0, 0, 0);
        __syncthreads();
    }

    #pragma unroll
    for (int m = 0; m < 4; ++m) {
        #pragma unroll
        for (int j = 0; j < 4; ++j) {
            int row = m0 + wr * 64 + m * 16 + l4 * 4 + j;
            if (row >= M) continue;
            #pragma unroll
            for (int n = 0; n < 4; ++n) {
                int col = n0 + wc * 64 + n * 16 + l15;
                float v = acc[m][n][j] + bias[col];
                C[(size_t)row * N + col] = (__bf16)elu_f(v);
            }
        }
    }
}

// ---------------- fused MLP tail: h1 -> xw1b = bf16(dis*(elu(elu(h1@W1)@W2)@g1w))
__global__ __launch_bounds__(256) void mlp_tail_kernel(
    const __bf16* __restrict__ h1, const __bf16* __restrict__ w1t,
    const float* __restrict__ b1, const __bf16* __restrict__ w2t,
    const float* __restrict__ b2, const float* __restrict__ g1w,
    const float* __restrict__ dis, __bf16* __restrict__ xw1b, int M)
{
    extern __shared__ char smem[];
    const int G1OFF = 32768, TOFF = 40960;
    const int tid = threadIdx.x;
    const int lane = tid & 63, wave = tid >> 6;
    const int l15 = lane & 15, l4 = lane >> 4;
    const int m0 = blockIdx.x * 128;

    // stage g1w (64x32 f32 = 8KB) into LDS
    {
        const float4* g4 = (const float4*)g1w;
        float4* d4 = (float4*)(smem + G1OFF);
        d4[tid] = g4[tid];
        d4[tid + 256] = g4[tid + 256];
    }

    // ---- stage A: GEMM1 rows m0..m0+127, N=128, K=512 ----
    const int wr = wave >> 1, wc = wave & 1;
    const int s0 = tid, s1 = tid + 256;
    int gr0 = m0 + (s0 >> 2); if (gr0 > M - 1) gr0 = M - 1;
    int gr1 = m0 + (s1 >> 2); if (gr1 > M - 1) gr1 = M - 1;
    const __bf16* a0p = h1 + (size_t)gr0 * 512 + (s0 & 3) * 8;
    const __bf16* a1p = h1 + (size_t)gr1 * 512 + (s1 & 3) * 8;
    const __bf16* b0p = w1t + (size_t)(s0 >> 2) * 512 + (s0 & 3) * 8;
    const __bf16* b1p = w1t + (size_t)(s1 >> 2) * 512 + (s1 & 3) * 8;
    char* stA0 = smem + s0 * 16;
    char* stA1 = smem + s1 * 16;
    char* stB0 = smem + 8192 + s0 * 16;
    char* stB1 = smem + 8192 + s1 * 16;
    const int aoff = (wr * 64 + l15) * 64 + l4 * 16;
    const int boff = 8192 + (wc * 64 + l15) * 64 + l4 * 16;

    v4f acc1[4][4] = {};
    for (int k0 = 0; k0 < 512; k0 += 32) {
        GL16(a0p + k0, stA0);
        GL16(a1p + k0, stA1);
        GL16(b0p + k0, stB0);
        GL16(b1p + k0, stB1);
        __syncthreads();
        v8bf af[4], bfr[4];
        #pragma unroll
        for (int m = 0; m < 4; ++m) af[m]  = *(const v8bf*)(smem + aoff + m * 1024);
        #pragma unroll
        for (int n = 0; n < 4; ++n) bfr[n] = *(const v8bf*)(smem + boff + n * 1024);
        #pragma unroll
        for (int m = 0; m < 4; ++m)
            #pragma unroll
            for (int n = 0; n < 4; ++n)
                acc1[m][n] = __builtin_amdgcn_mfma_f32_16x16x32_bf16(af[m], bfr[n], acc1[m][n], 0, 0, 0);
        __syncthreads();
    }
    // bias+ELU -> T bf16 (swizzled: byte ^= (row&7)<<4)
    float b1c[4];
    #pragma unroll
    for (int n = 0; n < 4; ++n) b1c[n] = b1[wc * 64 + n * 16 + l15];
    #pragma unroll
    for (int m = 0; m < 4; ++m) {
        #pragma unroll
        for (int j = 0; j < 4; ++j) {
            int row = wr * 64 + m * 16 + l4 * 4 + j;
            int rx = (row & 7) << 4;
            #pragma unroll
            for (int n = 0; n < 4; ++n) {
                int colb = (wc * 64 + n * 16 + l15) * 2;
                float v = elu_f(acc1[m][n][j] + b1c[n]);
                *(__bf16*)(smem + TOFF + row * 256 + (colb ^ rx)) = (__bf16)v;
            }
        }
    }
    __syncthreads();

    // ---- stage B: GEMM2 128x64, K=128, A from T, B=w2t from global/L2 ----
    const int wr2 = wave >> 1, wc2 = wave & 1;
    v4f acc2[4][2] = {};
    #pragma unroll
    for (int ks = 0; ks < 4; ++ks) {
        v8bf af2[4], bf2[2];
        #pragma unroll
        for (int m2 = 0; m2 < 4; ++m2) {
            int row = wr2 * 64 + m2 * 16 + l15;
            af2[m2] = *(const v8bf*)(smem + TOFF + row * 256 + ((ks * 64 + l4 * 16) ^ ((row & 7) << 4)));
        }
        #pragma unroll
        for (int n2 = 0; n2 < 2; ++n2) {
            int nn = wc2 * 32 + n2 * 16 + l15;
            bf2[n2] = *(const v8bf*)(w2t + nn * 128 + ks * 32 + l4 * 8);
        }
        #pragma unroll
        for (int m2 = 0; m2 < 4; ++m2)
            #pragma unroll
            for (int n2 = 0; n2 < 2; ++n2)
                acc2[m2][n2] = __builtin_amdgcn_mfma_f32_16x16x32_bf16(af2[m2], bf2[n2], acc2[m2][n2], 0, 0, 0);
    }
    __syncthreads();  // staging region fully dead; H3 overlays it
    // bias+ELU -> H3 f32 (swizzled)
    float b2c[2];
    #pragma unroll
    for (int n2 = 0; n2 < 2; ++n2) b2c[n2] = b2[wc2 * 32 + n2 * 16 + l15];
    #pragma unroll
    for (int m2 = 0; m2 < 4; ++m2) {
        #pragma unroll
        for (int j = 0; j < 4; ++j) {
            int row = wr2 * 64 + m2 * 16 + l4 * 4 + j;
            int rx = (row & 7) << 4;
            #pragma unroll
            for (int n2 = 0; n2 < 2; ++n2) {
                int col = wc2 * 32 + n2 * 16 + l15;
                float v = elu_f(acc2[m2][n2][j] + b2c[n2]);
                *(float*)(smem + row * 256 + ((col * 4) ^ rx)) = v;
            }
        }
    }
    __syncthreads();

    // ---- stage C: xw1b[r][n] = bf16( dis * sum_k H3[r][k] * g1w[k][n] ) ----
    int r = tid >> 1;
    int nb = (tid & 1) * 16;
    int gr = m0 + r;
    float o[16] = {};
    int rx = (r & 7) << 4;
    #pragma unroll 4
    for (int k4 = 0; k4 < 16; ++k4) {
        float4 h4 = *(const float4*)(smem + r * 256 + ((k4 * 16) ^ rx));
        #pragma unroll
        for (int e = 0; e < 4; ++e) {
            const float4* gp = (const float4*)(smem + G1OFF + (k4 * 4 + e) * 128 + nb * 4);
            float hv = (e == 0) ? h4.x : (e == 1) ? h4.y : (e == 2) ? h4.z : h4.w;
            #pragma unroll
            for (int q = 0; q < 4; ++q) {
                float4 g = gp[q];
                o[4 * q + 0] += hv * g.x;
                o[4 * q + 1] += hv * g.y;
                o[4 * q + 2] += hv * g.z;
                o[4 * q + 3] += hv * g.w;
            }
        }
    }
    if (gr < M) {
        float d = dis[gr];
        v8bf pk0, pk1;
        #pragma unroll
        for (int j2 = 0; j2 < 8; ++j2) {
            pk0[j2] = (__bf16)(o[j2] * d);
            pk1[j2] = (__bf16)(o[8 + j2] * d);
        }
        *(v8bf*)(xw1b + (size_t)gr * 32 + nb) = pk0;
        *(v8bf*)(xw1b + (size_t)gr * 32 + nb + 8) = pk1;
    }
}

// ---------------- CSR build: bucket scatter with atomic reservation ---------
__global__ void p1_scatter_kernel(const int* __restrict__ row, const int* __restrict__ col,
                                  int* __restrict__ fill196, unsigned int* __restrict__ tmp) {
    __shared__ int h[NB1], bl[NB1];
    int t = threadIdx.x, b = blockIdx.x;
    if (t < NB1) h[t] = 0;
    __syncthreads();
    int base = b * 4096;
    int cc[16];
    #pragma unroll
    for (int j = 0; j < 16; ++j) {
        int e = base + j * 256 + t;
        cc[j] = (e < N_EDGES) ? col[e] : -1;
        if (cc[j] >= 0) atomicAdd(&h[cc[j] >> 8], 1);
    }
    __syncthreads();
    if (t < NB1 && h[t] > 0) bl[t] = atomicAdd(&fill196[t], h[t]);
    __syncthreads();
    #pragma unroll
    for (int j = 0; j < 16; ++j) {
        if (cc[j] >= 0) {
            int e = base + j * 256 + t;
            int pos = atomicAdd(&bl[cc[j] >> 8], 1);
            tmp[pos] = ((unsigned int)cc[j] << 16) | (unsigned int)row[e];
        }
    }
}
// pass2: group by col&255 within bin; computes own output base; emits csr+ptr+dis
__global__ void p2_kernel(const unsigned int* __restrict__ tmp, const int* __restrict__ fill196,
                          int* __restrict__ csr, int* __restrict__ ptr, float* __restrict__ dis) {
    __shared__ int h2[256], b2[256], s2[256];
    __shared__ int sh_outb;
    int seg = blockIdx.x;
    int start = seg * CAP, end = fill196[seg];
    int t = threadIdx.x;
    if (t < 256) s2[t] = (t < seg) ? (fill196[t] - t * CAP) : 0;
    __syncthreads();
    for (int off = 128; off > 0; off >>= 1) {
        if (t < off) s2[t] += s2[t + off];
        __syncthreads();
    }
    if (t == 0) sh_outb = s2[0];
    if (t < 256) h2[t] = 0;
    __syncthreads();
    for (int i = start + t; i < end; i += 1024)
        atomicAdd(&h2[(tmp[i] >> 16) & 255], 1);
    __syncthreads();
    if (t < 256) s2[t] = h2[t];
    __syncthreads();
    for (int off = 1; off < 256; off <<= 1) {
        int u = 0;
        if (t < 256 && t >= off) u = s2[t - off];
        __syncthreads();
        if (t < 256) s2[t] += u;
        __syncthreads();
    }
    if (t < 256) {
        int p = sh_outb + s2[t] - h2[t];
        b2[t] = p;
        int node = (seg << 8) + t;
        if (node < N_NODES) {
            ptr[node] = p;
            dis[node] = rsqrtf((float)(h2[t] + 1));
        }
    }
    if (seg == NB1 - 1 && t == 0) ptr[N_NODES] = N_EDGES;
    __syncthreads();
    for (int i = start + t; i < end; i += 1024) {
        unsigned int v = tmp[i];
        int pos = atomicAdd(&b2[(v >> 16) & 255], 1);
        csr[pos] = (int)(v & 0xFFFFu);
    }
}

// ---------------- gather1 + GCN2 transform fused ----------------------------
// 8 lanes per node (feats 4q..4q+3). agg = elu(dis*sum + g1b); then
// xw2 = dis * (agg @ g2w) via LDS g2w^T + 8-lane shfl reduction. bf16 in/out.
__global__ void gather1_kernel(const unsigned short* __restrict__ xw1b,
                               const int* __restrict__ csr, const int* __restrict__ ptr,
                               const float* __restrict__ dis, const float* __restrict__ g1b,
                               const float* __restrict__ g2w, __bf16* __restrict__ xw2b) {
    __shared__ float g2t[512];  // transposed: g2t[n*32+k] = g2w[k*16+n]
    int t = threadIdx.x;
    {
        int k = t >> 4, n = t & 15;
        g2t[n * 32 + k] = g2w[t];
        int j = t + 256;
        k = j >> 4; n = j & 15;
        g2t[n * 32 + k] = g2w[j];
    }
    __syncthreads();
    int idx = blockIdx.x * 256 + t;
    int node = idx >> 3, q = idx & 7;
    if (node >= N_NODES) return;
    int s = ptr[node], e = ptr[node + 1];
    const ushort4* base = (const ushort4*)xw1b;  // 8 ushort4 per row
    float4 acc = bf4f(base[(size_t)node * 8 + q]);  // self-loop
    int i = s;
    for (; i + 4 <= e; i += 4) {
        float4 a = bf4f(base[(size_t)csr[i] * 8 + q]);
        float4 b = bf4f(base[(size_t)csr[i + 1] * 8 + q]);
        float4 c = bf4f(base[(size_t)csr[i + 2] * 8 + q]);
        float4 d4 = bf4f(base[(size_t)csr[i + 3] * 8 + q]);
        acc.x += (a.x + b.x) + (c.x + d4.x);
        acc.y += (a.y + b.y) + (c.y + d4.y);
        acc.z += (a.z + b.z) + (c.z + d4.z);
        acc.w += (a.w + b.w) + (c.w + d4.w);
    }
    for (; i < e; ++i) {
        float4 v = bf4f(base[(size_t)csr[i] * 8 + q]);
        acc.x += v.x; acc.y += v.y; acc.z += v.z; acc.w += v.w;
    }
    float d = dis[node];
    float4 bb = ((const float4*)g1b)[q];
    float a0 = elu_f(d * acc.x + bb.x);
    float a1 = elu_f(d * acc.y + bb.y);
    float a2 = elu_f(d * acc.z + bb.z);
    float a3 = elu_f(d * acc.w + bb.w);
    float p[16];
    const int k0 = 4 * q;
    #pragma unroll
    for (int n = 0; n < 16; ++n) {
        const float* g = &g2t[n * 32 + k0];
        p[n] = a0 * g[0] + a1 * g[1] + a2 * g[2] + a3 * g[3];
    }
    #pragma unroll
    for (int off = 1; off < 8; off <<= 1)
        #pragma unroll
        for (int n = 0; n < 16; ++n)
            p[n] += __shfl_xor(p[n], off);
    v2bf o2;
    o2[0] = (__bf16)(d * p[2 * q]);
    o2[1] = (__bf16)(d * p[2 * q + 1]);
    *(v2bf*)(xw2b + (size_t)node * 16 + 2 * q) = o2;
}

// ---------------- gather2: final aggregation into out -----------------------
// 4 lanes per node (feats 4q..4q+3), bf16 in, f32 out + bias.
__global__ void gather2_kernel(const unsigned short* __restrict__ xw2b,
                               const int* __restrict__ csr, const int* __restrict__ ptr,
                               const float* __restrict__ dis, const float* __restrict__ g2b,
                               float* __restrict__ out) {
    int idx = blockIdx.x * 256 + threadIdx.x;
    int node = idx >> 2, q = idx & 3;
    if (node >= N_NODES) return;
    int s = ptr[node], e = ptr[node + 1];
    const ushort4* base = (const ushort4*)xw2b;  // 4 ushort4 per row
    float4 acc = bf4f(base[(size_t)node * 4 + q]);  // self-loop
    int i = s;
    for (; i + 4 <= e; i += 4) {
        float4 a = bf4f(base[(size_t)csr[i] * 4 + q]);
        float4 b = bf4f(base[(size_t)csr[i + 1] * 4 + q]);
        float4 c = bf4f(base[(size_t)csr[i + 2] * 4 + q]);
        float4 d4 = bf4f(base[(size_t)csr[i + 3] * 4 + q]);
        acc.x += (a.x + b.x) + (c.x + d4.x);
        acc.y += (a.y + b.y) + (c.y + d4.y);
        acc.z += (a.z + b.z) + (c.z + d4.z);
        acc.w += (a.w + b.w) + (c.w + d4.w);
    }
    for (; i < e; ++i) {
        float4 v = bf4f(base[(size_t)csr[i] * 4 + q]);
        acc.x += v.x; acc.y += v.y; acc.z += v.z; acc.w += v.w;
    }
    float d = dis[node];
    float4 bb = ((const float4*)g2b)[q];
    float4 o;
    o.x = d * acc.x + bb.x; o.y = d * acc.y + bb.y;
    o.z = d * acc.z + bb.z; o.w = d * acc.w + bb.w;
    ((float4*)out)[idx] = o;
}

extern "C" void kernel_launch(void* const* d_in, const int* in_sizes, int n_in,
                              void* d_out, int out_size, void* d_ws, size_t ws_size,
                              hipStream_t stream) {
    const float* x    = (const float*)d_in[0];
    const int*   ei   = (const int*)d_in[1];
    const int*   row  = ei;
    const int*   col  = ei + N_EDGES;
    const float* ln_w = (const float*)d_in[2];
    const float* ln_b = (const float*)d_in[3];
    const float* w0   = (const float*)d_in[4];
    const float* b0   = (const float*)d_in[5];
    const float* w1   = (const float*)d_in[6];
    const float* b1   = (const float*)d_in[7];
    const float* w2   = (const float*)d_in[8];
    const float* b2   = (const float*)d_in[9];
    const float* g1w  = (const float*)d_in[10];
    const float* g1b  = (const float*)d_in[11];
    const float* g2w  = (const float*)d_in[12];
    const float* g2b  = (const float*)d_in[13];
    float* out = (float*)d_out;

    char* W = (char*)d_ws;
    __bf16* h0   = (__bf16*)(W + 0);          // 50000*1024 bf16
    __bf16* h1   = (__bf16*)(W + 102400000);  // 50000*512 bf16
    float*  dis  = (float*) (W + 179200000);  // 50000 f32
    __bf16* xw1b = (__bf16*)(W + 179400192);  // 50000*32 bf16 (dis-scaled)
    __bf16* xw2b = (__bf16*)(W + 185800192);  // 50000*16 bf16 (dis-scaled)
    __bf16* w0t  = (__bf16*)(W + 195400192);  // 512*1024 bf16
    __bf16* w1t  = (__bf16*)(W + 196448768);  // 128*512 bf16
    __bf16* w2t  = (__bf16*)(W + 196579840);  // 64*128 bf16
    int*    csr  = (int*)(W + 200000000);     // 3.2M int
    int*    ptr  = (int*)(W + 213000192);     // 50001 int
    unsigned int* tmp = (unsigned int*)(W + 214000128);  // NB1*CAP u32
    int*    fill196 = (int*)(W + 231000064);  // 196 int

    // 1. pool + layernorm -> bf16 (wave per node) + weight prep side-work
    pool_ln_kernel<<<N_NODES / 4, 256, 0, stream>>>(
        x, ln_w, ln_b, h0, w0, w1, w2, w0t, w1t, w2t, fill196);

    // 2. GEMM0 (h0 -> h1), 128x256 tile
    {
        dim3 g((N_NODES + 127) / 128, 2);
        mfma_gemm0<<<g, 512, 0, stream>>>(h0, w0t, b0, h1, N_NODES);
    }

    // 3. CSR build: reservation scatter -> p2 (csr + ptr + dis)
    p1_scatter_kernel<<<NBLK1, 256, 0, stream>>>(row, col, fill196, tmp);
    p2_kernel<<<NB1, 1024, 0, stream>>>(tmp, fill196, csr, ptr, dis);

    // 4. fused MLP tail: h1 -> xw1b (GEMM1 + GEMM2 + g1w transform + dis scale)
    mlp_tail_kernel<<<(N_NODES + 127) / 128, 256, 73728, stream>>>(
        h1, w1t, b1, w2t, b2, g1w, dis, xw1b, N_NODES);

    // 5. gather1 + GCN1 bias/ELU + GCN2 transform -> xw2b
    gather1_kernel<<<((N_NODES * 8) + 255) / 256, 256, 0, stream>>>(
        (const unsigned short*)xw1b, csr, ptr, dis, g1b, g2w, xw2b);

    // 6. gather2 -> out (+g2b)
    gather2_kernel<<<((N_NODES * 4) + 255) / 256, 256, 0, stream>>>(
        (const unsigned short*)xw2b, csr, ptr, dis, g2b, out);
}

// Round 10
// 356.315 us; speedup vs baseline: 2.6353x; 1.0573x over previous
//
#include <hip/hip_runtime.h>
#include <hip/hip_bf16.h>

#define N_NODES 50000
#define N_EDGES 3200000
#define NB1 196            // (N_NODES-1)>>8 + 1
#define NBLK1 782          // ceil(N_EDGES/4096)
#define CAP 20480          // per-bin tmp capacity (avg 16327, sigma ~128)
#define WT_BLKS 2336       // weight-transpose side-work blocks
#define G0_BLKS 782        // GEMM0 blocks (391 x 2)

typedef __bf16 v8bf __attribute__((ext_vector_type(8)));
typedef __bf16 v2bf __attribute__((ext_vector_type(2)));
typedef float v4f __attribute__((ext_vector_type(4)));

__device__ __forceinline__ float elu_f(float x) { return x > 0.f ? x : (expf(x) - 1.f); }

__device__ __forceinline__ float4 bf4f(ushort4 u) {
    float4 r;
    r.x = __uint_as_float(((unsigned)u.x) << 16);
    r.y = __uint_as_float(((unsigned)u.y) << 16);
    r.z = __uint_as_float(((unsigned)u.z) << 16);
    r.w = __uint_as_float(((unsigned)u.w) << 16);
    return r;
}

// async global->LDS, 16B per lane; LDS dest = wave-uniform base + lane*16
#define GL16(gp, lp) __builtin_amdgcn_global_load_lds( \
    (const __attribute__((address_space(1))) void*)(gp), \
    (__attribute__((address_space(3))) void*)(lp), 16, 0, 0)

// ---------------- fused maxpool(2)+LayerNorm -> bf16 ; + wt prep + p1 -------
// one WAVE per node. Side work hidden under the 409MB x stream:
//   blocks [0, 2336):      w0/w1/w2 transpose -> bf16
//   blocks [2336, 3118):   p1 bucket scatter chunk (edges -> tmp, binned)
__global__ void pool_ln_kernel(const float* __restrict__ x,
                               const float* __restrict__ ln_w,
                               const float* __restrict__ ln_b,
                               __bf16* __restrict__ h0,
                               const float* __restrict__ w0, const float* __restrict__ w1,
                               const float* __restrict__ w2,
                               __bf16* __restrict__ w0t, __bf16* __restrict__ w1t,
                               __bf16* __restrict__ w2t, int* __restrict__ fill196,
                               const int* __restrict__ erow, const int* __restrict__ ecol,
                               unsigned int* __restrict__ tmp) {
    __shared__ int h[NB1], bl[NB1];
    int t = threadIdx.x;
    // --- pool + LN (all blocks) ---
    {
        int wave = t >> 6, lane = t & 63;
        int node = blockIdx.x * 4 + wave;
        const float4* xr = (const float4*)(x + (size_t)node * 2048);
        float4 v[8];
        #pragma unroll
        for (int j = 0; j < 8; ++j) v[j] = xr[j * 64 + lane];
        float p[16];
        float sum = 0.f, sq = 0.f;
        #pragma unroll
        for (int j = 0; j < 8; ++j) {
            p[2 * j]     = fmaxf(v[j].x, v[j].y);
            p[2 * j + 1] = fmaxf(v[j].z, v[j].w);
            sum += p[2 * j] + p[2 * j + 1];
            sq  += p[2 * j] * p[2 * j] + p[2 * j + 1] * p[2 * j + 1];
        }
        #pragma unroll
        for (int off = 32; off > 0; off >>= 1) {
            sum += __shfl_xor(sum, off);
            sq  += __shfl_xor(sq, off);
        }
        float mu = sum * (1.f / 1024.f);
        float var = sq * (1.f / 1024.f) - mu * mu;
        float rstd = rsqrtf(var + 1e-5f);
        const float2* w2p = (const float2*)ln_w;
        const float2* b2p = (const float2*)ln_b;
        #pragma unroll
        for (int j = 0; j < 8; ++j) {
            int c2 = j * 64 + lane;
            float2 w = w2p[c2], b = b2p[c2];
            v2bf o;
            o[0] = (__bf16)((p[2 * j]     - mu) * rstd * w.x + b.x);
            o[1] = (__bf16)((p[2 * j + 1] - mu) * rstd * w.y + b.y);
            *(v2bf*)(h0 + (size_t)node * 1024 + 2 * c2) = o;
        }
    }
    // --- side work ---
    if (blockIdx.x < WT_BLKS) {
        int idx = blockIdx.x * 256 + t;
        if (idx < 524288) {            // w0: 1024x512
            int k = idx >> 9, n = idx & 511;
            w0t[(size_t)n * 1024 + k] = (__bf16)w0[idx];
        } else if (idx < 524288 + 65536) {  // w1: 512x128
            int j = idx - 524288;
            int k = j >> 7, n = j & 127;
            w1t[(size_t)n * 512 + k] = (__bf16)w1[j];
        } else if (idx < 524288 + 65536 + 8192) {  // w2: 128x64
            int j = idx - 524288 - 65536;
            int k = j >> 6, n = j & 63;
            w2t[(size_t)n * 128 + k] = (__bf16)w2[j];
        }
    } else if (blockIdx.x < WT_BLKS + NBLK1) {
        int cb = blockIdx.x - WT_BLKS;  // edge chunk id
        if (t < NB1) h[t] = 0;
        __syncthreads();
        int base = cb * 4096;
        int cc[16];
        #pragma unroll
        for (int j = 0; j < 16; ++j) {
            int e = base + j * 256 + t;
            cc[j] = (e < N_EDGES) ? ecol[e] : -1;
            if (cc[j] >= 0) atomicAdd(&h[cc[j] >> 8], 1);
        }
        __syncthreads();
        if (t < NB1 && h[t] > 0)
            bl[t] = t * CAP + atomicAdd(&fill196[t], h[t]);  // fill196 zero-init
        __syncthreads();
        #pragma unroll
        for (int j = 0; j < 16; ++j) {
            if (cc[j] >= 0) {
                int e = base + j * 256 + t;
                int pos = atomicAdd(&bl[cc[j] >> 8], 1);
                tmp[pos] = ((unsigned int)cc[j] << 16) | (unsigned int)erow[e];
            }
        }
    }
}

// ---------------- GEMM0 (XCD-swizzled 128x256 tiles) + p2 tail blocks -------
// blocks [0,782): GEMM0; blocks [782, 978): p2 (csr + ptr + dis), 512 threads.
__global__ __launch_bounds__(512) void gemm0_p2_kernel(
    const __bf16* __restrict__ A, const __bf16* __restrict__ BT,
    const float* __restrict__ bias, __bf16* __restrict__ C, int M,
    const unsigned int* __restrict__ tmp, const int* __restrict__ fill196,
    int* __restrict__ csr, int* __restrict__ ptr, float* __restrict__ dis)
{
    __shared__ char smem[24576];
    const int tid = threadIdx.x;
    int b = blockIdx.x;

    if (b >= G0_BLKS) {
        // ---- p2: group bin by col&255; emit csr + ptr + dis ----
        int seg = b - G0_BLKS;
        int* h2 = (int*)smem;          // 256
        int* b2 = (int*)smem + 256;    // 256
        int* s2 = (int*)smem + 512;    // 256
        int* shp = (int*)smem + 768;   // 1
        int start = seg * CAP;
        int cnt = fill196[seg];
        int end = start + cnt;
        int t = tid;
        if (t < 256) s2[t] = (t < seg) ? fill196[t] : 0;
        __syncthreads();
        for (int off = 128; off > 0; off >>= 1) {
            if (t < off) s2[t] += s2[t + off];
            __syncthreads();
        }
        if (t == 0) shp[0] = s2[0];
        if (t < 256) h2[t] = 0;
        __syncthreads();
        for (int i = start + t; i < end; i += 512)
            atomicAdd(&h2[(tmp[i] >> 16) & 255], 1);
        __syncthreads();
        if (t < 256) s2[t] = h2[t];
        __syncthreads();
        for (int off = 1; off < 256; off <<= 1) {
            int u = 0;
            if (t < 256 && t >= off) u = s2[t - off];
            __syncthreads();
            if (t < 256) s2[t] += u;
            __syncthreads();
        }
        if (t < 256) {
            int p = shp[0] + s2[t] - h2[t];
            b2[t] = p;
            int node = (seg << 8) + t;
            if (node < N_NODES) {
                ptr[node] = p;
                dis[node] = rsqrtf((float)(h2[t] + 1));
            }
        }
        if (seg == NB1 - 1 && t == 0) ptr[N_NODES] = N_EDGES;
        __syncthreads();
        for (int i = start + t; i < end; i += 512) {
            unsigned int v = tmp[i];
            int pos = atomicAdd(&b2[(v >> 16) & 255], 1);
            csr[pos] = (int)(v & 0xFFFFu);
        }
        return;
    }

    // ---- GEMM0: bijective XCD-chunk swizzle (782 = 8*97+6), pairs share A ----
    {
        const int q = 97, r = 6;
        int xcd = b & 7, pos = b >> 3;
        int wg = (xcd < r ? xcd * (q + 1) : r * (q + 1) + (xcd - r) * q) + pos;
        b = wg;
    }
    const int K = 1024, N = 512;
    unsigned short* lds = (unsigned short*)smem;
    const int lane = tid & 63, w = tid >> 6;
    const int wr = w >> 2, wc = w & 3;
    const int m0 = (b >> 1) * 128, n0 = (b & 1) * 256;

    int grA = m0 + (tid >> 2); if (grA > M - 1) grA = M - 1;
    const __bf16* aP = A + (size_t)grA * K + (tid & 3) * 8;
    char* ldsA = (char*)lds + tid * 16;
    const __bf16* bP0 = BT + (size_t)(n0 + (tid >> 2)) * K + (tid & 3) * 8;
    const __bf16* bP1 = BT + (size_t)(n0 + ((tid + 512) >> 2)) * K + (tid & 3) * 8;
    char* ldsB0 = (char*)lds + 8192 + tid * 16;
    char* ldsB1 = (char*)lds + 16384 + tid * 16;

    v4f acc[4][4] = {};
    const int l15 = lane & 15, l4 = lane >> 4;
    const int abase = (wr * 64 + l15) * 32 + l4 * 8;
    const int bbase = 4096 + (wc * 64 + l15) * 32 + l4 * 8;

    for (int k0 = 0; k0 < K; k0 += 32) {
        GL16(aP + k0, ldsA);
        GL16(bP0 + k0, ldsB0);
        GL16(bP1 + k0, ldsB1);
        __syncthreads();
        v8bf af[4], bfr[4];
        #pragma unroll
        for (int m = 0; m < 4; ++m) af[m]  = *(const v8bf*)&lds[abase + m * 16 * 32];
        #pragma unroll
        for (int n = 0; n < 4; ++n) bfr[n] = *(const v8bf*)&lds[bbase + n * 16 * 32];
        #pragma unroll
        for (int m = 0; m < 4; ++m)
            #pragma unroll
            for (int n = 0; n < 4; ++n)
                acc[m][n] = __builtin_amdgcn_mfma_f32_16x16x32_bf16(af[m], bfr[n], acc[m][n], 0, 0, 0);
        __syncthreads();
    }

    #pragma unroll
    for (int m = 0; m < 4; ++m) {
        #pragma unroll
        for (int j = 0; j < 4; ++j) {
            int row = m0 + wr * 64 + m * 16 + l4 * 4 + j;
            if (row >= M) continue;
            #pragma unroll
            for (int n = 0; n < 4; ++n) {
                int col = n0 + wc * 64 + n * 16 + l15;
                float v = acc[m][n][j] + bias[col];
                C[(size_t)row * N + col] = (__bf16)elu_f(v);
            }
        }
    }
}

// ---------------- fused MLP tail: h1 -> xw1b = bf16(dis*(elu(elu(h1@W1)@W2)@g1w))
__global__ __launch_bounds__(256) void mlp_tail_kernel(
    const __bf16* __restrict__ h1, const __bf16* __restrict__ w1t,
    const float* __restrict__ b1, const __bf16* __restrict__ w2t,
    const float* __restrict__ b2, const float* __restrict__ g1w,
    const float* __restrict__ dis, __bf16* __restrict__ xw1b, int M)
{
    extern __shared__ char smem[];
    const int G1OFF = 32768, TOFF = 40960;
    const int tid = threadIdx.x;
    const int lane = tid & 63, wave = tid >> 6;
    const int l15 = lane & 15, l4 = lane >> 4;
    const int m0 = blockIdx.x * 128;

    {
        const float4* g4 = (const float4*)g1w;
        float4* d4 = (float4*)(smem + G1OFF);
        d4[tid] = g4[tid];
        d4[tid + 256] = g4[tid + 256];
    }

    // ---- stage A: GEMM1 rows m0..m0+127, N=128, K=512 ----
    const int wr = wave >> 1, wc = wave & 1;
    const int s0 = tid, s1 = tid + 256;
    int gr0 = m0 + (s0 >> 2); if (gr0 > M - 1) gr0 = M - 1;
    int gr1 = m0 + (s1 >> 2); if (gr1 > M - 1) gr1 = M - 1;
    const __bf16* a0p = h1 + (size_t)gr0 * 512 + (s0 & 3) * 8;
    const __bf16* a1p = h1 + (size_t)gr1 * 512 + (s1 & 3) * 8;
    const __bf16* b0p = w1t + (size_t)(s0 >> 2) * 512 + (s0 & 3) * 8;
    const __bf16* b1p = w1t + (size_t)(s1 >> 2) * 512 + (s1 & 3) * 8;
    char* stA0 = smem + s0 * 16;
    char* stA1 = smem + s1 * 16;
    char* stB0 = smem + 8192 + s0 * 16;
    char* stB1 = smem + 8192 + s1 * 16;
    const int aoff = (wr * 64 + l15) * 64 + l4 * 16;
    const int boff = 8192 + (wc * 64 + l15) * 64 + l4 * 16;

    v4f acc1[4][4] = {};
    for (int k0 = 0; k0 < 512; k0 += 32) {
        GL16(a0p + k0, stA0);
        GL16(a1p + k0, stA1);
        GL16(b0p + k0, stB0);
        GL16(b1p + k0, stB1);
        __syncthreads();
        v8bf af[4], bfr[4];
        #pragma unroll
        for (int m = 0; m < 4; ++m) af[m]  = *(const v8bf*)(smem + aoff + m * 1024);
        #pragma unroll
        for (int n = 0; n < 4; ++n) bfr[n] = *(const v8bf*)(smem + boff + n * 1024);
        #pragma unroll
        for (int m = 0; m < 4; ++m)
            #pragma unroll
            for (int n = 0; n < 4; ++n)
                acc1[m][n] = __builtin_amdgcn_mfma_f32_16x16x32_bf16(af[m], bfr[n], acc1[m][n], 0, 0, 0);
        __syncthreads();
    }
    float b1c[4];
    #pragma unroll
    for (int n = 0; n < 4; ++n) b1c[n] = b1[wc * 64 + n * 16 + l15];
    #pragma unroll
    for (int m = 0; m < 4; ++m) {
        #pragma unroll
        for (int j = 0; j < 4; ++j) {
            int row = wr * 64 + m * 16 + l4 * 4 + j;
            int rx = (row & 7) << 4;
            #pragma unroll
            for (int n = 0; n < 4; ++n) {
                int colb = (wc * 64 + n * 16 + l15) * 2;
                float v = elu_f(acc1[m][n][j] + b1c[n]);
                *(__bf16*)(smem + TOFF + row * 256 + (colb ^ rx)) = (__bf16)v;
            }
        }
    }
    __syncthreads();

    // ---- stage B: GEMM2 128x64, K=128 ----
    const int wr2 = wave >> 1, wc2 = wave & 1;
    v4f acc2[4][2] = {};
    #pragma unroll
    for (int ks = 0; ks < 4; ++ks) {
        v8bf af2[4], bf2[2];
        #pragma unroll
        for (int m2 = 0; m2 < 4; ++m2) {
            int row = wr2 * 64 + m2 * 16 + l15;
            af2[m2] = *(const v8bf*)(smem + TOFF + row * 256 + ((ks * 64 + l4 * 16) ^ ((row & 7) << 4)));
        }
        #pragma unroll
        for (int n2 = 0; n2 < 2; ++n2) {
            int nn = wc2 * 32 + n2 * 16 + l15;
            bf2[n2] = *(const v8bf*)(w2t + nn * 128 + ks * 32 + l4 * 8);
        }
        #pragma unroll
        for (int m2 = 0; m2 < 4; ++m2)
            #pragma unroll
            for (int n2 = 0; n2 < 2; ++n2)
                acc2[m2][n2] = __builtin_amdgcn_mfma_f32_16x16x32_bf16(af2[m2], bf2[n2], acc2[m2][n2], 0, 0, 0);
    }
    __syncthreads();
    float b2c[2];
    #pragma unroll
    for (int n2 = 0; n2 < 2; ++n2) b2c[n2] = b2[wc2 * 32 + n2 * 16 + l15];
    #pragma unroll
    for (int m2 = 0; m2 < 4; ++m2) {
        #pragma unroll
        for (int j = 0; j < 4; ++j) {
            int row = wr2 * 64 + m2 * 16 + l4 * 4 + j;
            int rx = (row & 7) << 4;
            #pragma unroll
            for (int n2 = 0; n2 < 2; ++n2) {
                int col = wc2 * 32 + n2 * 16 + l15;
                float v = elu_f(acc2[m2][n2][j] + b2c[n2]);
                *(float*)(smem + row * 256 + ((col * 4) ^ rx)) = v;
            }
        }
    }
    __syncthreads();

    // ---- stage C: xw1b[r][n] = bf16( dis * sum_k H3[r][k] * g1w[k][n] ) ----
    int r = tid >> 1;
    int nb = (tid & 1) * 16;
    int gr = m0 + r;
    float o[16] = {};
    int rx = (r & 7) << 4;
    #pragma unroll 4
    for (int k4 = 0; k4 < 16; ++k4) {
        float4 h4 = *(const float4*)(smem + r * 256 + ((k4 * 16) ^ rx));
        #pragma unroll
        for (int e = 0; e < 4; ++e) {
            const float4* gp = (const float4*)(smem + G1OFF + (k4 * 4 + e) * 128 + nb * 4);
            float hv = (e == 0) ? h4.x : (e == 1) ? h4.y : (e == 2) ? h4.z : h4.w;
            #pragma unroll
            for (int q = 0; q < 4; ++q) {
                float4 g = gp[q];
                o[4 * q + 0] += hv * g.x;
                o[4 * q + 1] += hv * g.y;
                o[4 * q + 2] += hv * g.z;
                o[4 * q + 3] += hv * g.w;
            }
        }
    }
    if (gr < M) {
        float d = dis[gr];
        v8bf pk0, pk1;
        #pragma unroll
        for (int j2 = 0; j2 < 8; ++j2) {
            pk0[j2] = (__bf16)(o[j2] * d);
            pk1[j2] = (__bf16)(o[8 + j2] * d);
        }
        *(v8bf*)(xw1b + (size_t)gr * 32 + nb) = pk0;
        *(v8bf*)(xw1b + (size_t)gr * 32 + nb + 8) = pk1;
    }
}

// ---------------- gather1 + GCN2 transform fused ----------------------------
__global__ void gather1_kernel(const unsigned short* __restrict__ xw1b,
                               const int* __restrict__ csr, const int* __restrict__ ptr,
                               const float* __restrict__ dis, const float* __restrict__ g1b,
                               const float* __restrict__ g2w, __bf16* __restrict__ xw2b) {
    __shared__ float g2t[512];  // transposed: g2t[n*32+k] = g2w[k*16+n]
    int t = threadIdx.x;
    {
        int k = t >> 4, n = t & 15;
        g2t[n * 32 + k] = g2w[t];
        int j = t + 256;
        k = j >> 4; n = j & 15;
        g2t[n * 32 + k] = g2w[j];
    }
    __syncthreads();
    int idx = blockIdx.x * 256 + t;
    int node = idx >> 3, q = idx & 7;
    if (node >= N_NODES) return;
    int s = ptr[node], e = ptr[node + 1];
    const ushort4* base = (const ushort4*)xw1b;
    float4 acc = bf4f(base[(size_t)node * 8 + q]);  // self-loop
    int i = s;
    for (; i + 4 <= e; i += 4) {
        float4 a = bf4f(base[(size_t)csr[i] * 8 + q]);
        float4 b = bf4f(base[(size_t)csr[i + 1] * 8 + q]);
        float4 c = bf4f(base[(size_t)csr[i + 2] * 8 + q]);
        float4 d4 = bf4f(base[(size_t)csr[i + 3] * 8 + q]);
        acc.x += (a.x + b.x) + (c.x + d4.x);
        acc.y += (a.y + b.y) + (c.y + d4.y);
        acc.z += (a.z + b.z) + (c.z + d4.z);
        acc.w += (a.w + b.w) + (c.w + d4.w);
    }
    for (; i < e; ++i) {
        float4 v = bf4f(base[(size_t)csr[i] * 8 + q]);
        acc.x += v.x; acc.y += v.y; acc.z += v.z; acc.w += v.w;
    }
    float d = dis[node];
    float4 bb = ((const float4*)g1b)[q];
    float a0 = elu_f(d * acc.x + bb.x);
    float a1 = elu_f(d * acc.y + bb.y);
    float a2 = elu_f(d * acc.z + bb.z);
    float a3 = elu_f(d * acc.w + bb.w);
    float p[16];
    const int k0 = 4 * q;
    #pragma unroll
    for (int n = 0; n < 16; ++n) {
        const float* g = &g2t[n * 32 + k0];
        p[n] = a0 * g[0] + a1 * g[1] + a2 * g[2] + a3 * g[3];
    }
    #pragma unroll
    for (int off = 1; off < 8; off <<= 1)
        #pragma unroll
        for (int n = 0; n < 16; ++n)
            p[n] += __shfl_xor(p[n], off);
    v2bf o2;
    o2[0] = (__bf16)(d * p[2 * q]);
    o2[1] = (__bf16)(d * p[2 * q + 1]);
    *(v2bf*)(xw2b + (size_t)node * 16 + 2 * q) = o2;
}

// ---------------- gather2: final aggregation into out -----------------------
__global__ void gather2_kernel(const unsigned short* __restrict__ xw2b,
                               const int* __restrict__ csr, const int* __restrict__ ptr,
                               const float* __restrict__ dis, const float* __restrict__ g2b,
                               float* __restrict__ out) {
    int idx = blockIdx.x * 256 + threadIdx.x;
    int node = idx >> 2, q = idx & 3;
    if (node >= N_NODES) return;
    int s = ptr[node], e = ptr[node + 1];
    const ushort4* base = (const ushort4*)xw2b;
    float4 acc = bf4f(base[(size_t)node * 4 + q]);  // self-loop
    int i = s;
    for (; i + 4 <= e; i += 4) {
        float4 a = bf4f(base[(size_t)csr[i] * 4 + q]);
        float4 b = bf4f(base[(size_t)csr[i + 1] * 4 + q]);
        float4 c = bf4f(base[(size_t)csr[i + 2] * 4 + q]);
        float4 d4 = bf4f(base[(size_t)csr[i + 3] * 4 + q]);
        acc.x += (a.x + b.x) + (c.x + d4.x);
        acc.y += (a.y + b.y) + (c.y + d4.y);
        acc.z += (a.z + b.z) + (c.z + d4.z);
        acc.w += (a.w + b.w) + (c.w + d4.w);
    }
    for (; i < e; ++i) {
        float4 v = bf4f(base[(size_t)csr[i] * 4 + q]);
        acc.x += v.x; acc.y += v.y; acc.z += v.z; acc.w += v.w;
    }
    float d = dis[node];
    float4 bb = ((const float4*)g2b)[q];
    float4 o;
    o.x = d * acc.x + bb.x; o.y = d * acc.y + bb.y;
    o.z = d * acc.z + bb.z; o.w = d * acc.w + bb.w;
    ((float4*)out)[idx] = o;
}

extern "C" void kernel_launch(void* const* d_in, const int* in_sizes, int n_in,
                              void* d_out, int out_size, void* d_ws, size_t ws_size,
                              hipStream_t stream) {
    const float* x    = (const float*)d_in[0];
    const int*   ei   = (const int*)d_in[1];
    const int*   row  = ei;
    const int*   col  = ei + N_EDGES;
    const float* ln_w = (const float*)d_in[2];
    const float* ln_b = (const float*)d_in[3];
    const float* w0   = (const float*)d_in[4];
    const float* b0   = (const float*)d_in[5];
    const float* w1   = (const float*)d_in[6];
    const float* b1   = (const float*)d_in[7];
    const float* w2   = (const float*)d_in[8];
    const float* b2   = (const float*)d_in[9];
    const float* g1w  = (const float*)d_in[10];
    const float* g1b  = (const float*)d_in[11];
    const float* g2w  = (const float*)d_in[12];
    const float* g2b  = (const float*)d_in[13];
    float* out = (float*)d_out;

    char* W = (char*)d_ws;
    __bf16* h0   = (__bf16*)(W + 0);          // 50000*1024 bf16
    __bf16* h1   = (__bf16*)(W + 102400000);  // 50000*512 bf16
    float*  dis  = (float*) (W + 179200000);  // 50000 f32
    __bf16* xw1b = (__bf16*)(W + 179400192);  // 50000*32 bf16 (dis-scaled)
    __bf16* xw2b = (__bf16*)(W + 185800192);  // 50000*16 bf16 (dis-scaled)
    __bf16* w0t  = (__bf16*)(W + 195400192);  // 512*1024 bf16
    __bf16* w1t  = (__bf16*)(W + 196448768);  // 128*512 bf16
    __bf16* w2t  = (__bf16*)(W + 196579840);  // 64*128 bf16
    int*    csr  = (int*)(W + 200000000);     // 3.2M int
    int*    ptr  = (int*)(W + 213000192);     // 50001 int
    unsigned int* tmp = (unsigned int*)(W + 214000128);  // NB1*CAP u32
    int*    fill196 = (int*)(W + 231000064);  // 196 int (zero-based counts)

    // fill196 <- 0 (p1 reservations are t*CAP + count)
    hipMemsetAsync(fill196, 0, NB1 * sizeof(int), stream);

    // 1. pool+LN (wave per node) + wt prep + p1 bucket scatter side-work
    pool_ln_kernel<<<N_NODES / 4, 256, 0, stream>>>(
        x, ln_w, ln_b, h0, w0, w1, w2, w0t, w1t, w2t, fill196, row, col, tmp);

    // 2. GEMM0 (h0 -> h1, XCD-swizzled) + p2 tail blocks (csr + ptr + dis)
    gemm0_p2_kernel<<<G0_BLKS + NB1, 512, 0, stream>>>(
        h0, w0t, b0, h1, N_NODES, tmp, fill196, csr, ptr, dis);

    // 3. fused MLP tail: h1 -> xw1b
    mlp_tail_kernel<<<(N_NODES + 127) / 128, 256, 73728, stream>>>(
        h1, w1t, b1, w2t, b2, g1w, dis, xw1b, N_NODES);

    // 4. gather1 + GCN1 bias/ELU + GCN2 transform -> xw2b
    gather1_kernel<<<((N_NODES * 8) + 255) / 256, 256, 0, stream>>>(
        (const unsigned short*)xw1b, csr, ptr, dis, g1b, g2w, xw2b);

    // 5. gather2 -> out (+g2b)
    gather2_kernel<<<((N_NODES * 4) + 255) / 256, 256, 0, stream>>>(
        (const unsigned short*)xw2b, csr, ptr, dis, g2b, out);
}

// Round 11
// 341.379 us; speedup vs baseline: 2.7506x; 1.0438x over previous
//
#include <hip/hip_runtime.h>
#include <hip/hip_bf16.h>

#define N_NODES 50000
#define N_EDGES 3200000
#define NB1 196            // (N_NODES-1)>>8 + 1
#define NBLK1 782          // ceil(N_EDGES/4096)
#define CAP 20480          // per-bin tmp capacity (avg 16327, sigma ~128)
#define WT_BLKS 2336       // weight-transpose side-work blocks
#define G0_BLKS 782        // GEMM0 blocks (391 x 2)

typedef __bf16 v8bf __attribute__((ext_vector_type(8)));
typedef __bf16 v2bf __attribute__((ext_vector_type(2)));
typedef float v4f __attribute__((ext_vector_type(4)));
typedef unsigned short us8 __attribute__((ext_vector_type(8)));
typedef unsigned short us4 __attribute__((ext_vector_type(4)));

__device__ __forceinline__ float elu_f(float x) { return x > 0.f ? x : (expf(x) - 1.f); }

__device__ __forceinline__ void bf8acc(float* a, us8 u) {
    #pragma unroll
    for (int j = 0; j < 8; ++j) a[j] += __uint_as_float(((unsigned)u[j]) << 16);
}

// async global->LDS, 16B per lane; LDS dest = wave-uniform base + lane*16
#define GL16(gp, lp) __builtin_amdgcn_global_load_lds( \
    (const __attribute__((address_space(1))) void*)(gp), \
    (__attribute__((address_space(3))) void*)(lp), 16, 0, 0)

// ---------------- fused maxpool(2)+LayerNorm -> bf16 ; + wt prep + p1 -------
// one WAVE per node. Side work hidden under the 409MB x stream:
//   blocks [0, 2336):      w0/w1/w2 transpose -> bf16
//   blocks [2336, 3118):   p1 bucket scatter chunk (edges -> tmp, binned)
__global__ void pool_ln_kernel(const float* __restrict__ x,
                               const float* __restrict__ ln_w,
                               const float* __restrict__ ln_b,
                               __bf16* __restrict__ h0,
                               const float* __restrict__ w0, const float* __restrict__ w1,
                               const float* __restrict__ w2,
                               __bf16* __restrict__ w0t, __bf16* __restrict__ w1t,
                               __bf16* __restrict__ w2t, int* __restrict__ fill196,
                               const int* __restrict__ erow, const int* __restrict__ ecol,
                               unsigned int* __restrict__ tmp) {
    __shared__ int h[NB1], bl[NB1];
    int t = threadIdx.x;
    // --- pool + LN (all blocks) ---
    {
        int wave = t >> 6, lane = t & 63;
        int node = blockIdx.x * 4 + wave;
        const float4* xr = (const float4*)(x + (size_t)node * 2048);
        float4 v[8];
        #pragma unroll
        for (int j = 0; j < 8; ++j) v[j] = xr[j * 64 + lane];
        float p[16];
        float sum = 0.f, sq = 0.f;
        #pragma unroll
        for (int j = 0; j < 8; ++j) {
            p[2 * j]     = fmaxf(v[j].x, v[j].y);
            p[2 * j + 1] = fmaxf(v[j].z, v[j].w);
            sum += p[2 * j] + p[2 * j + 1];
            sq  += p[2 * j] * p[2 * j] + p[2 * j + 1] * p[2 * j + 1];
        }
        #pragma unroll
        for (int off = 32; off > 0; off >>= 1) {
            sum += __shfl_xor(sum, off);
            sq  += __shfl_xor(sq, off);
        }
        float mu = sum * (1.f / 1024.f);
        float var = sq * (1.f / 1024.f) - mu * mu;
        float rstd = rsqrtf(var + 1e-5f);
        const float2* w2p = (const float2*)ln_w;
        const float2* b2p = (const float2*)ln_b;
        #pragma unroll
        for (int j = 0; j < 8; ++j) {
            int c2 = j * 64 + lane;
            float2 w = w2p[c2], b = b2p[c2];
            v2bf o;
            o[0] = (__bf16)((p[2 * j]     - mu) * rstd * w.x + b.x);
            o[1] = (__bf16)((p[2 * j + 1] - mu) * rstd * w.y + b.y);
            *(v2bf*)(h0 + (size_t)node * 1024 + 2 * c2) = o;
        }
    }
    // --- side work ---
    if (blockIdx.x < WT_BLKS) {
        int idx = blockIdx.x * 256 + t;
        if (idx < 524288) {            // w0: 1024x512
            int k = idx >> 9, n = idx & 511;
            w0t[(size_t)n * 1024 + k] = (__bf16)w0[idx];
        } else if (idx < 524288 + 65536) {  // w1: 512x128
            int j = idx - 524288;
            int k = j >> 7, n = j & 127;
            w1t[(size_t)n * 512 + k] = (__bf16)w1[j];
        } else if (idx < 524288 + 65536 + 8192) {  // w2: 128x64
            int j = idx - 524288 - 65536;
            int k = j >> 6, n = j & 63;
            w2t[(size_t)n * 128 + k] = (__bf16)w2[j];
        }
    } else if (blockIdx.x < WT_BLKS + NBLK1) {
        int cb = blockIdx.x - WT_BLKS;  // edge chunk id (4096 edges)
        if (t < NB1) h[t] = 0;
        __syncthreads();
        const int4* col4 = (const int4*)ecol;
        const int4* row4 = (const int4*)erow;
        int base4 = cb * 1024;  // int4 units
        int cc[16];
        #pragma unroll
        for (int j = 0; j < 4; ++j) {
            int i4 = base4 + j * 256 + t;
            if (i4 * 4 < N_EDGES) {
                int4 c = col4[i4];
                cc[4 * j] = c.x; cc[4 * j + 1] = c.y;
                cc[4 * j + 2] = c.z; cc[4 * j + 3] = c.w;
            } else {
                cc[4 * j] = cc[4 * j + 1] = cc[4 * j + 2] = cc[4 * j + 3] = -1;
            }
        }
        #pragma unroll
        for (int j = 0; j < 16; ++j)
            if (cc[j] >= 0) atomicAdd(&h[cc[j] >> 8], 1);
        __syncthreads();
        if (t < NB1 && h[t] > 0)
            bl[t] = t * CAP + atomicAdd(&fill196[t], h[t]);  // fill196 zero-init
        __syncthreads();
        #pragma unroll
        for (int j = 0; j < 4; ++j) {
            int i4 = base4 + j * 256 + t;
            if (i4 * 4 < N_EDGES) {
                int4 r4 = row4[i4];
                int rr[4] = {r4.x, r4.y, r4.z, r4.w};
                #pragma unroll
                for (int u = 0; u < 4; ++u) {
                    int c = cc[4 * j + u];
                    int pos = atomicAdd(&bl[c >> 8], 1);
                    tmp[pos] = ((unsigned int)c << 16) | (unsigned int)rr[u];
                }
            }
        }
    }
}

// ---------------- GEMM0 (XCD-swizzled 128x256 tiles) + p2 tail blocks -------
__global__ __launch_bounds__(512) void gemm0_p2_kernel(
    const __bf16* __restrict__ A, const __bf16* __restrict__ BT,
    const float* __restrict__ bias, __bf16* __restrict__ C, int M,
    const unsigned int* __restrict__ tmp, const int* __restrict__ fill196,
    int* __restrict__ csr, int* __restrict__ ptr, float* __restrict__ dis)
{
    __shared__ char smem[24576];
    const int tid = threadIdx.x;
    int b = blockIdx.x;

    if (b >= G0_BLKS) {
        // ---- p2: group bin by col&255; emit csr + ptr + dis ----
        int seg = b - G0_BLKS;
        int* h2 = (int*)smem;          // 256
        int* b2 = (int*)smem + 256;    // 256
        int* s2 = (int*)smem + 512;    // 256
        int* shp = (int*)smem + 768;   // 1
        int start = seg * CAP;
        int cnt = fill196[seg];
        int end = start + cnt;
        int t = tid;
        if (t < 256) s2[t] = (t < seg) ? fill196[t] : 0;
        __syncthreads();
        for (int off = 128; off > 0; off >>= 1) {
            if (t < off) s2[t] += s2[t + off];
            __syncthreads();
        }
        if (t == 0) shp[0] = s2[0];
        if (t < 256) h2[t] = 0;
        __syncthreads();
        int ng = cnt >> 2;  // full uint4 groups
        for (int g = t; g < ng; g += 512) {
            uint4 v = *(const uint4*)&tmp[start + g * 4];
            atomicAdd(&h2[(v.x >> 16) & 255], 1);
            atomicAdd(&h2[(v.y >> 16) & 255], 1);
            atomicAdd(&h2[(v.z >> 16) & 255], 1);
            atomicAdd(&h2[(v.w >> 16) & 255], 1);
        }
        for (int i = start + (ng << 2) + t; i < end; i += 512)
            atomicAdd(&h2[(tmp[i] >> 16) & 255], 1);
        __syncthreads();
        if (t < 256) s2[t] = h2[t];
        __syncthreads();
        for (int off = 1; off < 256; off <<= 1) {
            int u = 0;
            if (t < 256 && t >= off) u = s2[t - off];
            __syncthreads();
            if (t < 256) s2[t] += u;
            __syncthreads();
        }
        if (t < 256) {
            int p = shp[0] + s2[t] - h2[t];
            b2[t] = p;
            int node = (seg << 8) + t;
            if (node < N_NODES) {
                ptr[node] = p;
                dis[node] = rsqrtf((float)(h2[t] + 1));
            }
        }
        if (seg == NB1 - 1 && t == 0) ptr[N_NODES] = N_EDGES;
        __syncthreads();
        for (int g = t; g < ng; g += 512) {
            uint4 v = *(const uint4*)&tmp[start + g * 4];
            int p0 = atomicAdd(&b2[(v.x >> 16) & 255], 1); csr[p0] = (int)(v.x & 0xFFFFu);
            int p1 = atomicAdd(&b2[(v.y >> 16) & 255], 1); csr[p1] = (int)(v.y & 0xFFFFu);
            int p2_ = atomicAdd(&b2[(v.z >> 16) & 255], 1); csr[p2_] = (int)(v.z & 0xFFFFu);
            int p3 = atomicAdd(&b2[(v.w >> 16) & 255], 1); csr[p3] = (int)(v.w & 0xFFFFu);
        }
        for (int i = start + (ng << 2) + t; i < end; i += 512) {
            unsigned int v = tmp[i];
            int pos = atomicAdd(&b2[(v >> 16) & 255], 1);
            csr[pos] = (int)(v & 0xFFFFu);
        }
        return;
    }

    // ---- GEMM0: bijective XCD-chunk swizzle (782 = 8*97+6), pairs share A ----
    {
        const int q = 97, r = 6;
        int xcd = b & 7, pos = b >> 3;
        int wg = (xcd < r ? xcd * (q + 1) : r * (q + 1) + (xcd - r) * q) + pos;
        b = wg;
    }
    const int K = 1024, N = 512;
    unsigned short* lds = (unsigned short*)smem;
    const int lane = tid & 63, w = tid >> 6;
    const int wr = w >> 2, wc = w & 3;
    const int m0 = (b >> 1) * 128, n0 = (b & 1) * 256;

    int grA = m0 + (tid >> 2); if (grA > M - 1) grA = M - 1;
    const __bf16* aP = A + (size_t)grA * K + (tid & 3) * 8;
    char* ldsA = (char*)lds + tid * 16;
    const __bf16* bP0 = BT + (size_t)(n0 + (tid >> 2)) * K + (tid & 3) * 8;
    const __bf16* bP1 = BT + (size_t)(n0 + ((tid + 512) >> 2)) * K + (tid & 3) * 8;
    char* ldsB0 = (char*)lds + 8192 + tid * 16;
    char* ldsB1 = (char*)lds + 16384 + tid * 16;

    v4f acc[4][4] = {};
    const int l15 = lane & 15, l4 = lane >> 4;
    const int abase = (wr * 64 + l15) * 32 + l4 * 8;
    const int bbase = 4096 + (wc * 64 + l15) * 32 + l4 * 8;

    for (int k0 = 0; k0 < K; k0 += 32) {
        GL16(aP + k0, ldsA);
        GL16(bP0 + k0, ldsB0);
        GL16(bP1 + k0, ldsB1);
        __syncthreads();
        v8bf af[4], bfr[4];
        #pragma unroll
        for (int m = 0; m < 4; ++m) af[m]  = *(const v8bf*)&lds[abase + m * 16 * 32];
        #pragma unroll
        for (int n = 0; n < 4; ++n) bfr[n] = *(const v8bf*)&lds[bbase + n * 16 * 32];
        #pragma unroll
        for (int m = 0; m < 4; ++m)
            #pragma unroll
            for (int n = 0; n < 4; ++n)
                acc[m][n] = __builtin_amdgcn_mfma_f32_16x16x32_bf16(af[m], bfr[n], acc[m][n], 0, 0, 0);
        __syncthreads();
    }

    #pragma unroll
    for (int m = 0; m < 4; ++m) {
        #pragma unroll
        for (int j = 0; j < 4; ++j) {
            int row = m0 + wr * 64 + m * 16 + l4 * 4 + j;
            if (row >= M) continue;
            #pragma unroll
            for (int n = 0; n < 4; ++n) {
                int col = n0 + wc * 64 + n * 16 + l15;
                float v = acc[m][n][j] + bias[col];
                C[(size_t)row * N + col] = (__bf16)elu_f(v);
            }
        }
    }
}

// ---------------- fused MLP tail: h1 -> xw1b = bf16(dis*(elu(elu(h1@W1)@W2)@g1w))
__global__ __launch_bounds__(256) void mlp_tail_kernel(
    const __bf16* __restrict__ h1, const __bf16* __restrict__ w1t,
    const float* __restrict__ b1, const __bf16* __restrict__ w2t,
    const float* __restrict__ b2, const float* __restrict__ g1w,
    const float* __restrict__ dis, __bf16* __restrict__ xw1b, int M)
{
    extern __shared__ char smem[];
    const int G1OFF = 32768, TOFF = 40960;
    const int tid = threadIdx.x;
    const int lane = tid & 63, wave = tid >> 6;
    const int l15 = lane & 15, l4 = lane >> 4;
    const int m0 = blockIdx.x * 128;

    {
        const float4* g4 = (const float4*)g1w;
        float4* d4 = (float4*)(smem + G1OFF);
        d4[tid] = g4[tid];
        d4[tid + 256] = g4[tid + 256];
    }

    // ---- stage A: GEMM1 rows m0..m0+127, N=128, K=512 ----
    const int wr = wave >> 1, wc = wave & 1;
    const int s0 = tid, s1 = tid + 256;
    int gr0 = m0 + (s0 >> 2); if (gr0 > M - 1) gr0 = M - 1;
    int gr1 = m0 + (s1 >> 2); if (gr1 > M - 1) gr1 = M - 1;
    const __bf16* a0p = h1 + (size_t)gr0 * 512 + (s0 & 3) * 8;
    const __bf16* a1p = h1 + (size_t)gr1 * 512 + (s1 & 3) * 8;
    const __bf16* b0p = w1t + (size_t)(s0 >> 2) * 512 + (s0 & 3) * 8;
    const __bf16* b1p = w1t + (size_t)(s1 >> 2) * 512 + (s1 & 3) * 8;
    char* stA0 = smem + s0 * 16;
    char* stA1 = smem + s1 * 16;
    char* stB0 = smem + 8192 + s0 * 16;
    char* stB1 = smem + 8192 + s1 * 16;
    const int aoff = (wr * 64 + l15) * 64 + l4 * 16;
    const int boff = 8192 + (wc * 64 + l15) * 64 + l4 * 16;

    v4f acc1[4][4] = {};
    for (int k0 = 0; k0 < 512; k0 += 32) {
        GL16(a0p + k0, stA0);
        GL16(a1p + k0, stA1);
        GL16(b0p + k0, stB0);
        GL16(b1p + k0, stB1);
        __syncthreads();
        v8bf af[4], bfr[4];
        #pragma unroll
        for (int m = 0; m < 4; ++m) af[m]  = *(const v8bf*)(smem + aoff + m * 1024);
        #pragma unroll
        for (int n = 0; n < 4; ++n) bfr[n] = *(const v8bf*)(smem + boff + n * 1024);
        #pragma unroll
        for (int m = 0; m < 4; ++m)
            #pragma unroll
            for (int n = 0; n < 4; ++n)
                acc1[m][n] = __builtin_amdgcn_mfma_f32_16x16x32_bf16(af[m], bfr[n], acc1[m][n], 0, 0, 0);
        __syncthreads();
    }
    float b1c[4];
    #pragma unroll
    for (int n = 0; n < 4; ++n) b1c[n] = b1[wc * 64 + n * 16 + l15];
    #pragma unroll
    for (int m = 0; m < 4; ++m) {
        #pragma unroll
        for (int j = 0; j < 4; ++j) {
            int row = wr * 64 + m * 16 + l4 * 4 + j;
            int rx = (row & 7) << 4;
            #pragma unroll
            for (int n = 0; n < 4; ++n) {
                int colb = (wc * 64 + n * 16 + l15) * 2;
                float v = elu_f(acc1[m][n][j] + b1c[n]);
                *(__bf16*)(smem + TOFF + row * 256 + (colb ^ rx)) = (__bf16)v;
            }
        }
    }
    __syncthreads();

    // ---- stage B: GEMM2 128x64, K=128 ----
    const int wr2 = wave >> 1, wc2 = wave & 1;
    v4f acc2[4][2] = {};
    #pragma unroll
    for (int ks = 0; ks < 4; ++ks) {
        v8bf af2[4], bf2[2];
        #pragma unroll
        for (int m2 = 0; m2 < 4; ++m2) {
            int row = wr2 * 64 + m2 * 16 + l15;
            af2[m2] = *(const v8bf*)(smem + TOFF + row * 256 + ((ks * 64 + l4 * 16) ^ ((row & 7) << 4)));
        }
        #pragma unroll
        for (int n2 = 0; n2 < 2; ++n2) {
            int nn = wc2 * 32 + n2 * 16 + l15;
            bf2[n2] = *(const v8bf*)(w2t + nn * 128 + ks * 32 + l4 * 8);
        }
        #pragma unroll
        for (int m2 = 0; m2 < 4; ++m2)
            #pragma unroll
            for (int n2 = 0; n2 < 2; ++n2)
                acc2[m2][n2] = __builtin_amdgcn_mfma_f32_16x16x32_bf16(af2[m2], bf2[n2], acc2[m2][n2], 0, 0, 0);
    }
    __syncthreads();
    float b2c[2];
    #pragma unroll
    for (int n2 = 0; n2 < 2; ++n2) b2c[n2] = b2[wc2 * 32 + n2 * 16 + l15];
    #pragma unroll
    for (int m2 = 0; m2 < 4; ++m2) {
        #pragma unroll
        for (int j = 0; j < 4; ++j) {
            int row = wr2 * 64 + m2 * 16 + l4 * 4 + j;
            int rx = (row & 7) << 4;
            #pragma unroll
            for (int n2 = 0; n2 < 2; ++n2) {
                int col = wc2 * 32 + n2 * 16 + l15;
                float v = elu_f(acc2[m2][n2][j] + b2c[n2]);
                *(float*)(smem + row * 256 + ((col * 4) ^ rx)) = v;
            }
        }
    }
    __syncthreads();

    // ---- stage C: xw1b[r][n] = bf16( dis * sum_k H3[r][k] * g1w[k][n] ) ----
    int r = tid >> 1;
    int nb = (tid & 1) * 16;
    int gr = m0 + r;
    float o[16] = {};
    int rx = (r & 7) << 4;
    #pragma unroll 4
    for (int k4 = 0; k4 < 16; ++k4) {
        float4 h4 = *(const float4*)(smem + r * 256 + ((k4 * 16) ^ rx));
        #pragma unroll
        for (int e = 0; e < 4; ++e) {
            const float4* gp = (const float4*)(smem + G1OFF + (k4 * 4 + e) * 128 + nb * 4);
            float hv = (e == 0) ? h4.x : (e == 1) ? h4.y : (e == 2) ? h4.z : h4.w;
            #pragma unroll
            for (int q = 0; q < 4; ++q) {
                float4 g = gp[q];
                o[4 * q + 0] += hv * g.x;
                o[4 * q + 1] += hv * g.y;
                o[4 * q + 2] += hv * g.z;
                o[4 * q + 3] += hv * g.w;
            }
        }
    }
    if (gr < M) {
        float d = dis[gr];
        v8bf pk0, pk1;
        #pragma unroll
        for (int j2 = 0; j2 < 8; ++j2) {
            pk0[j2] = (__bf16)(o[j2] * d);
            pk1[j2] = (__bf16)(o[8 + j2] * d);
        }
        *(v8bf*)(xw1b + (size_t)gr * 32 + nb) = pk0;
        *(v8bf*)(xw1b + (size_t)gr * 32 + nb + 8) = pk1;
    }
}

// ---------------- gather1 + GCN2 transform fused ----------------------------
// 4 lanes/node, each owns 8 feats (16B loads); csr read as int4 (4 edges/load)
__global__ void gather1_kernel(const unsigned short* __restrict__ xw1b,
                               const int* __restrict__ csr, const int* __restrict__ ptr,
                               const float* __restrict__ dis, const float* __restrict__ g1b,
                               const float* __restrict__ g2w, __bf16* __restrict__ xw2b) {
    __shared__ float g2t[512];  // transposed: g2t[n*32+k] = g2w[k*16+n]
    int t = threadIdx.x;
    {
        int k = t >> 4, n = t & 15;
        g2t[n * 32 + k] = g2w[t];
        int j = t + 256;
        k = j >> 4; n = j & 15;
        g2t[n * 32 + k] = g2w[j];
    }
    __syncthreads();
    int idx = blockIdx.x * 256 + t;
    int node = idx >> 2, q = idx & 3;
    if (node >= N_NODES) return;
    int s = ptr[node], e = ptr[node + 1];
    const char* xwb = (const char*)xw1b;  // row stride 64B; lane offset q*16
    float a[8];
    {
        us8 u = *(const us8*)(xwb + (size_t)node * 64 + q * 16);
        #pragma unroll
        for (int j = 0; j < 8; ++j) a[j] = __uint_as_float(((unsigned)u[j]) << 16);
    }
    int i = s;
    for (; (i & 3) && i < e; ++i)
        bf8acc(a, *(const us8*)(xwb + (size_t)csr[i] * 64 + q * 16));
    for (; i + 4 <= e; i += 4) {
        int4 rr = *(const int4*)&csr[i];
        us8 u0 = *(const us8*)(xwb + (size_t)rr.x * 64 + q * 16);
        us8 u1 = *(const us8*)(xwb + (size_t)rr.y * 64 + q * 16);
        us8 u2 = *(const us8*)(xwb + (size_t)rr.z * 64 + q * 16);
        us8 u3 = *(const us8*)(xwb + (size_t)rr.w * 64 + q * 16);
        bf8acc(a, u0); bf8acc(a, u1); bf8acc(a, u2); bf8acc(a, u3);
    }
    for (; i < e; ++i)
        bf8acc(a, *(const us8*)(xwb + (size_t)csr[i] * 64 + q * 16));
    float d = dis[node];
    float4 bb0 = ((const float4*)g1b)[2 * q];
    float4 bb1 = ((const float4*)g1b)[2 * q + 1];
    a[0] = elu_f(d * a[0] + bb0.x); a[1] = elu_f(d * a[1] + bb0.y);
    a[2] = elu_f(d * a[2] + bb0.z); a[3] = elu_f(d * a[3] + bb0.w);
    a[4] = elu_f(d * a[4] + bb1.x); a[5] = elu_f(d * a[5] + bb1.y);
    a[6] = elu_f(d * a[6] + bb1.z); a[7] = elu_f(d * a[7] + bb1.w);
    // xw2[n] = d * sum_k agg[k]*g2w[k][n]; lane owns k = 8q..8q+7
    float p[16];
    const int k0 = 8 * q;
    #pragma unroll
    for (int n = 0; n < 16; ++n) {
        const float* g = &g2t[n * 32 + k0];
        float acc = a[0] * g[0];
        #pragma unroll
        for (int j = 1; j < 8; ++j) acc += a[j] * g[j];
        p[n] = acc;
    }
    #pragma unroll
    for (int off = 1; off < 4; off <<= 1)
        #pragma unroll
        for (int n = 0; n < 16; ++n)
            p[n] += __shfl_xor(p[n], off);
    us4 o4;
    #pragma unroll
    for (int u = 0; u < 4; ++u)
        o4[u] = (unsigned short)(__float_as_uint(
            (float)((__bf16)(d * p[4 * q + u])) ) >> 16);
    // store via bf16 conversion (round-to-nearest) then bit-pack
    __bf16 c0 = (__bf16)(d * p[4 * q + 0]);
    __bf16 c1 = (__bf16)(d * p[4 * q + 1]);
    __bf16 c2 = (__bf16)(d * p[4 * q + 2]);
    __bf16 c3 = (__bf16)(d * p[4 * q + 3]);
    __bf16 pk[4] = {c0, c1, c2, c3};
    *(us4*)(xw2b + (size_t)node * 16 + 4 * q) = *(us4*)pk;
}

// ---------------- gather2: final aggregation into out -----------------------
// 2 lanes/node, each owns 8 feats (16B loads); csr as int4.
__global__ void gather2_kernel(const unsigned short* __restrict__ xw2b,
                               const int* __restrict__ csr, const int* __restrict__ ptr,
                               const float* __restrict__ dis, const float* __restrict__ g2b,
                               float* __restrict__ out) {
    int idx = blockIdx.x * 256 + threadIdx.x;
    int node = idx >> 1, q = idx & 1;
    if (node >= N_NODES) return;
    int s = ptr[node], e = ptr[node + 1];
    const char* xwb = (const char*)xw2b;  // row stride 32B; lane offset q*16
    float a[8];
    {
        us8 u = *(const us8*)(xwb + (size_t)node * 32 + q * 16);
        #pragma unroll
        for (int j = 0; j < 8; ++j) a[j] = __uint_as_float(((unsigned)u[j]) << 16);
    }
    int i = s;
    for (; (i & 3) && i < e; ++i)
        bf8acc(a, *(const us8*)(xwb + (size_t)csr[i] * 32 + q * 16));
    for (; i + 4 <= e; i += 4) {
        int4 rr = *(const int4*)&csr[i];
        us8 u0 = *(const us8*)(xwb + (size_t)rr.x * 32 + q * 16);
        us8 u1 = *(const us8*)(xwb + (size_t)rr.y * 32 + q * 16);
        us8 u2 = *(const us8*)(xwb + (size_t)rr.z * 32 + q * 16);
        us8 u3 = *(const us8*)(xwb + (size_t)rr.w * 32 + q * 16);
        bf8acc(a, u0); bf8acc(a, u1); bf8acc(a, u2); bf8acc(a, u3);
    }
    for (; i < e; ++i)
        bf8acc(a, *(const us8*)(xwb + (size_t)csr[i] * 32 + q * 16));
    float d = dis[node];
    float4 bb0 = ((const float4*)g2b)[2 * q];
    float4 bb1 = ((const float4*)g2b)[2 * q + 1];
    float4 o0, o1;
    o0.x = d * a[0] + bb0.x; o0.y = d * a[1] + bb0.y;
    o0.z = d * a[2] + bb0.z; o0.w = d * a[3] + bb0.w;
    o1.x = d * a[4] + bb1.x; o1.y = d * a[5] + bb1.y;
    o1.z = d * a[6] + bb1.z; o1.w = d * a[7] + bb1.w;
    ((float4*)out)[(size_t)node * 4 + 2 * q] = o0;
    ((float4*)out)[(size_t)node * 4 + 2 * q + 1] = o1;
}

extern "C" void kernel_launch(void* const* d_in, const int* in_sizes, int n_in,
                              void* d_out, int out_size, void* d_ws, size_t ws_size,
                              hipStream_t stream) {
    const float* x    = (const float*)d_in[0];
    const int*   ei   = (const int*)d_in[1];
    const int*   row  = ei;
    const int*   col  = ei + N_EDGES;
    const float* ln_w = (const float*)d_in[2];
    const float* ln_b = (const float*)d_in[3];
    const float* w0   = (const float*)d_in[4];
    const float* b0   = (const float*)d_in[5];
    const float* w1   = (const float*)d_in[6];
    const float* b1   = (const float*)d_in[7];
    const float* w2   = (const float*)d_in[8];
    const float* b2   = (const float*)d_in[9];
    const float* g1w  = (const float*)d_in[10];
    const float* g1b  = (const float*)d_in[11];
    const float* g2w  = (const float*)d_in[12];
    const float* g2b  = (const float*)d_in[13];
    float* out = (float*)d_out;

    char* W = (char*)d_ws;
    __bf16* h0   = (__bf16*)(W + 0);          // 50000*1024 bf16
    __bf16* h1   = (__bf16*)(W + 102400000);  // 50000*512 bf16
    float*  dis  = (float*) (W + 179200000);  // 50000 f32
    __bf16* xw1b = (__bf16*)(W + 179400192);  // 50000*32 bf16 (dis-scaled)
    __bf16* xw2b = (__bf16*)(W + 185800192);  // 50000*16 bf16 (dis-scaled)
    __bf16* w0t  = (__bf16*)(W + 195400192);  // 512*1024 bf16
    __bf16* w1t  = (__bf16*)(W + 196448768);  // 128*512 bf16
    __bf16* w2t  = (__bf16*)(W + 196579840);  // 64*128 bf16
    int*    csr  = (int*)(W + 200000000);     // 3.2M int
    int*    ptr  = (int*)(W + 213000192);     // 50001 int
    unsigned int* tmp = (unsigned int*)(W + 214000128);  // NB1*CAP u32
    int*    fill196 = (int*)(W + 231000064);  // 196 int (zero-based counts)

    // fill196 <- 0 (p1 reservations are t*CAP + count)
    hipMemsetAsync(fill196, 0, NB1 * sizeof(int), stream);

    // 1. pool+LN (wave per node) + wt prep + p1 bucket scatter side-work
    pool_ln_kernel<<<N_NODES / 4, 256, 0, stream>>>(
        x, ln_w, ln_b, h0, w0, w1, w2, w0t, w1t, w2t, fill196, row, col, tmp);

    // 2. GEMM0 (h0 -> h1, XCD-swizzled) + p2 tail blocks (csr + ptr + dis)
    gemm0_p2_kernel<<<G0_BLKS + NB1, 512, 0, stream>>>(
        h0, w0t, b0, h1, N_NODES, tmp, fill196, csr, ptr, dis);

    // 3. fused MLP tail: h1 -> xw1b
    mlp_tail_kernel<<<(N_NODES + 127) / 128, 256, 73728, stream>>>(
        h1, w1t, b1, w2t, b2, g1w, dis, xw1b, N_NODES);

    // 4. gather1 + GCN1 bias/ELU + GCN2 transform -> xw2b
    gather1_kernel<<<((N_NODES * 4) + 255) / 256, 256, 0, stream>>>(
        (const unsigned short*)xw1b, csr, ptr, dis, g1b, g2w, xw2b);

    // 5. gather2 -> out (+g2b)
    gather2_kernel<<<((N_NODES * 2) + 255) / 256, 256, 0, stream>>>(
        (const unsigned short*)xw2b, csr, ptr, dis, g2b, out);
}

// Round 12
// 333.034 us; speedup vs baseline: 2.8195x; 1.0251x over previous
//
#include <hip/hip_runtime.h>
#include <hip/hip_bf16.h>

#define N_NODES 50000
#define N_EDGES 3200000
#define NB1 196            // (N_NODES-1)>>8 + 1
#define NBLK1 782          // ceil(N_EDGES/4096)
#define CAP 20480          // per-bin tmp capacity (avg 16327, sigma ~128)
#define WT_BLKS 2336       // weight-transpose side-work blocks
#define G0_BLKS 782        // GEMM0 blocks (391 x 2)

typedef __bf16 v8bf __attribute__((ext_vector_type(8)));
typedef __bf16 v2bf __attribute__((ext_vector_type(2)));
typedef float v4f __attribute__((ext_vector_type(4)));
typedef unsigned short us8 __attribute__((ext_vector_type(8)));

__device__ __forceinline__ float elu_f(float x) { return x > 0.f ? x : (expf(x) - 1.f); }

__device__ __forceinline__ void bf8acc(float* a, us8 u) {
    #pragma unroll
    for (int j = 0; j < 8; ++j) a[j] += __uint_as_float(((unsigned)u[j]) << 16);
}

// async global->LDS, 16B per lane; LDS dest = wave-uniform base + lane*16
#define GL16(gp, lp) __builtin_amdgcn_global_load_lds( \
    (const __attribute__((address_space(1))) void*)(gp), \
    (__attribute__((address_space(3))) void*)(lp), 16, 0, 0)

// ---------------- fused maxpool(2)+LayerNorm -> bf16 ; + wt prep + p1 -------
__global__ void pool_ln_kernel(const float* __restrict__ x,
                               const float* __restrict__ ln_w,
                               const float* __restrict__ ln_b,
                               __bf16* __restrict__ h0,
                               const float* __restrict__ w0, const float* __restrict__ w1,
                               const float* __restrict__ w2,
                               __bf16* __restrict__ w0t, __bf16* __restrict__ w1t,
                               __bf16* __restrict__ w2t, int* __restrict__ fill196,
                               const int* __restrict__ erow, const int* __restrict__ ecol,
                               unsigned int* __restrict__ tmp) {
    __shared__ int h[NB1], bl[NB1];
    int t = threadIdx.x;
    // --- pool + LN (all blocks) ---
    {
        int wave = t >> 6, lane = t & 63;
        int node = blockIdx.x * 4 + wave;
        const float4* xr = (const float4*)(x + (size_t)node * 2048);
        float4 v[8];
        #pragma unroll
        for (int j = 0; j < 8; ++j) v[j] = xr[j * 64 + lane];
        float p[16];
        float sum = 0.f, sq = 0.f;
        #pragma unroll
        for (int j = 0; j < 8; ++j) {
            p[2 * j]     = fmaxf(v[j].x, v[j].y);
            p[2 * j + 1] = fmaxf(v[j].z, v[j].w);
            sum += p[2 * j] + p[2 * j + 1];
            sq  += p[2 * j] * p[2 * j] + p[2 * j + 1] * p[2 * j + 1];
        }
        #pragma unroll
        for (int off = 32; off > 0; off >>= 1) {
            sum += __shfl_xor(sum, off);
            sq  += __shfl_xor(sq, off);
        }
        float mu = sum * (1.f / 1024.f);
        float var = sq * (1.f / 1024.f) - mu * mu;
        float rstd = rsqrtf(var + 1e-5f);
        const float2* w2p = (const float2*)ln_w;
        const float2* b2p = (const float2*)ln_b;
        #pragma unroll
        for (int j = 0; j < 8; ++j) {
            int c2 = j * 64 + lane;
            float2 w = w2p[c2], b = b2p[c2];
            v2bf o;
            o[0] = (__bf16)((p[2 * j]     - mu) * rstd * w.x + b.x);
            o[1] = (__bf16)((p[2 * j + 1] - mu) * rstd * w.y + b.y);
            *(v2bf*)(h0 + (size_t)node * 1024 + 2 * c2) = o;
        }
    }
    // --- side work ---
    if (blockIdx.x < WT_BLKS) {
        int idx = blockIdx.x * 256 + t;
        if (idx < 524288) {            // w0: 1024x512
            int k = idx >> 9, n = idx & 511;
            w0t[(size_t)n * 1024 + k] = (__bf16)w0[idx];
        } else if (idx < 524288 + 65536) {  // w1: 512x128
            int j = idx - 524288;
            int k = j >> 7, n = j & 127;
            w1t[(size_t)n * 512 + k] = (__bf16)w1[j];
        } else if (idx < 524288 + 65536 + 8192) {  // w2: 128x64
            int j = idx - 524288 - 65536;
            int k = j >> 6, n = j & 63;
            w2t[(size_t)n * 128 + k] = (__bf16)w2[j];
        }
    } else if (blockIdx.x < WT_BLKS + NBLK1) {
        int cb = blockIdx.x - WT_BLKS;  // edge chunk id (4096 edges)
        if (t < NB1) h[t] = 0;
        __syncthreads();
        const int4* col4 = (const int4*)ecol;
        const int4* row4 = (const int4*)erow;
        int base4 = cb * 1024;  // int4 units
        int cc[16];
        #pragma unroll
        for (int j = 0; j < 4; ++j) {
            int i4 = base4 + j * 256 + t;
            if (i4 * 4 < N_EDGES) {
                int4 c = col4[i4];
                cc[4 * j] = c.x; cc[4 * j + 1] = c.y;
                cc[4 * j + 2] = c.z; cc[4 * j + 3] = c.w;
            } else {
                cc[4 * j] = cc[4 * j + 1] = cc[4 * j + 2] = cc[4 * j + 3] = -1;
            }
        }
        #pragma unroll
        for (int j = 0; j < 16; ++j)
            if (cc[j] >= 0) atomicAdd(&h[cc[j] >> 8], 1);
        __syncthreads();
        if (t < NB1 && h[t] > 0)
            bl[t] = t * CAP + atomicAdd(&fill196[t], h[t]);  // fill196 zero-init
        __syncthreads();
        #pragma unroll
        for (int j = 0; j < 4; ++j) {
            int i4 = base4 + j * 256 + t;
            if (i4 * 4 < N_EDGES) {
                int4 r4 = row4[i4];
                int rr[4] = {r4.x, r4.y, r4.z, r4.w};
                #pragma unroll
                for (int u = 0; u < 4; ++u) {
                    int c = cc[4 * j + u];
                    int pos = atomicAdd(&bl[c >> 8], 1);
                    tmp[pos] = ((unsigned int)c << 16) | (unsigned int)rr[u];
                }
            }
        }
    }
}

// ---------------- GEMM0 (XCD-swizzled 128x256 tiles) + p2 tail blocks -------
__global__ __launch_bounds__(512) void gemm0_p2_kernel(
    const __bf16* __restrict__ A, const __bf16* __restrict__ BT,
    const float* __restrict__ bias, __bf16* __restrict__ C, int M,
    const unsigned int* __restrict__ tmp, const int* __restrict__ fill196,
    unsigned short* __restrict__ csr16, int* __restrict__ ptr, float* __restrict__ dis)
{
    __shared__ char smem[24576];
    const int tid = threadIdx.x;
    int b = blockIdx.x;

    if (b >= G0_BLKS) {
        // ---- p2: group bin by col&255; emit csr16 + ptr + dis ----
        int seg = b - G0_BLKS;
        int* h2 = (int*)smem;          // 256
        int* b2 = (int*)smem + 256;    // 256
        int* s2 = (int*)smem + 512;    // 256
        int* shp = (int*)smem + 768;   // 1
        int start = seg * CAP;
        int cnt = fill196[seg];
        int end = start + cnt;
        int t = tid;
        if (t < 256) s2[t] = (t < seg) ? fill196[t] : 0;
        __syncthreads();
        for (int off = 128; off > 0; off >>= 1) {
            if (t < off) s2[t] += s2[t + off];
            __syncthreads();
        }
        if (t == 0) shp[0] = s2[0];
        if (t < 256) h2[t] = 0;
        __syncthreads();
        int ng = cnt >> 2;  // full uint4 groups
        for (int g = t; g < ng; g += 512) {
            uint4 v = *(const uint4*)&tmp[start + g * 4];
            atomicAdd(&h2[(v.x >> 16) & 255], 1);
            atomicAdd(&h2[(v.y >> 16) & 255], 1);
            atomicAdd(&h2[(v.z >> 16) & 255], 1);
            atomicAdd(&h2[(v.w >> 16) & 255], 1);
        }
        for (int i = start + (ng << 2) + t; i < end; i += 512)
            atomicAdd(&h2[(tmp[i] >> 16) & 255], 1);
        __syncthreads();
        if (t < 256) s2[t] = h2[t];
        __syncthreads();
        for (int off = 1; off < 256; off <<= 1) {
            int u = 0;
            if (t < 256 && t >= off) u = s2[t - off];
            __syncthreads();
            if (t < 256) s2[t] += u;
            __syncthreads();
        }
        if (t < 256) {
            int p = shp[0] + s2[t] - h2[t];
            b2[t] = p;
            int node = (seg << 8) + t;
            if (node < N_NODES) {
                ptr[node] = p;
                dis[node] = rsqrtf((float)(h2[t] + 1));
            }
        }
        if (seg == NB1 - 1 && t == 0) ptr[N_NODES] = N_EDGES;
        __syncthreads();
        for (int g = t; g < ng; g += 512) {
            uint4 v = *(const uint4*)&tmp[start + g * 4];
            int p0 = atomicAdd(&b2[(v.x >> 16) & 255], 1); csr16[p0] = (unsigned short)(v.x & 0xFFFFu);
            int p1 = atomicAdd(&b2[(v.y >> 16) & 255], 1); csr16[p1] = (unsigned short)(v.y & 0xFFFFu);
            int p2_ = atomicAdd(&b2[(v.z >> 16) & 255], 1); csr16[p2_] = (unsigned short)(v.z & 0xFFFFu);
            int p3 = atomicAdd(&b2[(v.w >> 16) & 255], 1); csr16[p3] = (unsigned short)(v.w & 0xFFFFu);
        }
        for (int i = start + (ng << 2) + t; i < end; i += 512) {
            unsigned int v = tmp[i];
            int pos = atomicAdd(&b2[(v >> 16) & 255], 1);
            csr16[pos] = (unsigned short)(v & 0xFFFFu);
        }
        return;
    }

    // ---- GEMM0: bijective XCD-chunk swizzle (782 = 8*97+6), pairs share A ----
    {
        const int q = 97, r = 6;
        int xcd = b & 7, pos = b >> 3;
        int wg = (xcd < r ? xcd * (q + 1) : r * (q + 1) + (xcd - r) * q) + pos;
        b = wg;
    }
    const int K = 1024, N = 512;
    unsigned short* lds = (unsigned short*)smem;
    const int lane = tid & 63, w = tid >> 6;
    const int wr = w >> 2, wc = w & 3;
    const int m0 = (b >> 1) * 128, n0 = (b & 1) * 256;

    int grA = m0 + (tid >> 2); if (grA > M - 1) grA = M - 1;
    const __bf16* aP = A + (size_t)grA * K + (tid & 3) * 8;
    char* ldsA = (char*)lds + tid * 16;
    const __bf16* bP0 = BT + (size_t)(n0 + (tid >> 2)) * K + (tid & 3) * 8;
    const __bf16* bP1 = BT + (size_t)(n0 + ((tid + 512) >> 2)) * K + (tid & 3) * 8;
    char* ldsB0 = (char*)lds + 8192 + tid * 16;
    char* ldsB1 = (char*)lds + 16384 + tid * 16;

    v4f acc[4][4] = {};
    const int l15 = lane & 15, l4 = lane >> 4;
    const int abase = (wr * 64 + l15) * 32 + l4 * 8;
    const int bbase = 4096 + (wc * 64 + l15) * 32 + l4 * 8;

    for (int k0 = 0; k0 < K; k0 += 32) {
        GL16(aP + k0, ldsA);
        GL16(bP0 + k0, ldsB0);
        GL16(bP1 + k0, ldsB1);
        __syncthreads();
        v8bf af[4], bfr[4];
        #pragma unroll
        for (int m = 0; m < 4; ++m) af[m]  = *(const v8bf*)&lds[abase + m * 16 * 32];
        #pragma unroll
        for (int n = 0; n < 4; ++n) bfr[n] = *(const v8bf*)&lds[bbase + n * 16 * 32];
        #pragma unroll
        for (int m = 0; m < 4; ++m)
            #pragma unroll
            for (int n = 0; n < 4; ++n)
                acc[m][n] = __builtin_amdgcn_mfma_f32_16x16x32_bf16(af[m], bfr[n], acc[m][n], 0, 0, 0);
        __syncthreads();
    }

    #pragma unroll
    for (int m = 0; m < 4; ++m) {
        #pragma unroll
        for (int j = 0; j < 4; ++j) {
            int row = m0 + wr * 64 + m * 16 + l4 * 4 + j;
            if (row >= M) continue;
            #pragma unroll
            for (int n = 0; n < 4; ++n) {
                int col = n0 + wc * 64 + n * 16 + l15;
                float v = acc[m][n][j] + bias[col];
                C[(size_t)row * N + col] = (__bf16)elu_f(v);
            }
        }
    }
}

// ---------------- fused MLP tail: h1 -> xw1b = bf16(dis*(elu(elu(h1@W1)@W2)@g1w))
__global__ __launch_bounds__(256) void mlp_tail_kernel(
    const __bf16* __restrict__ h1, const __bf16* __restrict__ w1t,
    const float* __restrict__ b1, const __bf16* __restrict__ w2t,
    const float* __restrict__ b2, const float* __restrict__ g1w,
    const float* __restrict__ dis, __bf16* __restrict__ xw1b, int M)
{
    extern __shared__ char smem[];
    const int G1OFF = 32768, TOFF = 40960;
    const int tid = threadIdx.x;
    const int lane = tid & 63, wave = tid >> 6;
    const int l15 = lane & 15, l4 = lane >> 4;
    const int m0 = blockIdx.x * 128;

    {
        const float4* g4 = (const float4*)g1w;
        float4* d4 = (float4*)(smem + G1OFF);
        d4[tid] = g4[tid];
        d4[tid + 256] = g4[tid + 256];
    }

    // ---- stage A: GEMM1 rows m0..m0+127, N=128, K=512 ----
    const int wr = wave >> 1, wc = wave & 1;
    const int s0 = tid, s1 = tid + 256;
    int gr0 = m0 + (s0 >> 2); if (gr0 > M - 1) gr0 = M - 1;
    int gr1 = m0 + (s1 >> 2); if (gr1 > M - 1) gr1 = M - 1;
    const __bf16* a0p = h1 + (size_t)gr0 * 512 + (s0 & 3) * 8;
    const __bf16* a1p = h1 + (size_t)gr1 * 512 + (s1 & 3) * 8;
    const __bf16* b0p = w1t + (size_t)(s0 >> 2) * 512 + (s0 & 3) * 8;
    const __bf16* b1p = w1t + (size_t)(s1 >> 2) * 512 + (s1 & 3) * 8;
    char* stA0 = smem + s0 * 16;
    char* stA1 = smem + s1 * 16;
    char* stB0 = smem + 8192 + s0 * 16;
    char* stB1 = smem + 8192 + s1 * 16;
    const int aoff = (wr * 64 + l15) * 64 + l4 * 16;
    const int boff = 8192 + (wc * 64 + l15) * 64 + l4 * 16;

    v4f acc1[4][4] = {};
    for (int k0 = 0; k0 < 512; k0 += 32) {
        GL16(a0p + k0, stA0);
        GL16(a1p + k0, stA1);
        GL16(b0p + k0, stB0);
        GL16(b1p + k0, stB1);
        __syncthreads();
        v8bf af[4], bfr[4];
        #pragma unroll
        for (int m = 0; m < 4; ++m) af[m]  = *(const v8bf*)(smem + aoff + m * 1024);
        #pragma unroll
        for (int n = 0; n < 4; ++n) bfr[n] = *(const v8bf*)(smem + boff + n * 1024);
        #pragma unroll
        for (int m = 0; m < 4; ++m)
            #pragma unroll
            for (int n = 0; n < 4; ++n)
                acc1[m][n] = __builtin_amdgcn_mfma_f32_16x16x32_bf16(af[m], bfr[n], acc1[m][n], 0, 0, 0);
        __syncthreads();
    }
    float b1c[4];
    #pragma unroll
    for (int n = 0; n < 4; ++n) b1c[n] = b1[wc * 64 + n * 16 + l15];
    #pragma unroll
    for (int m = 0; m < 4; ++m) {
        #pragma unroll
        for (int j = 0; j < 4; ++j) {
            int row = wr * 64 + m * 16 + l4 * 4 + j;
            int rx = (row & 7) << 4;
            #pragma unroll
            for (int n = 0; n < 4; ++n) {
                int colb = (wc * 64 + n * 16 + l15) * 2;
                float v = elu_f(acc1[m][n][j] + b1c[n]);
                *(__bf16*)(smem + TOFF + row * 256 + (colb ^ rx)) = (__bf16)v;
            }
        }
    }
    __syncthreads();

    // ---- stage B: GEMM2 128x64, K=128 ----
    const int wr2 = wave >> 1, wc2 = wave & 1;
    v4f acc2[4][2] = {};
    #pragma unroll
    for (int ks = 0; ks < 4; ++ks) {
        v8bf af2[4], bf2[2];
        #pragma unroll
        for (int m2 = 0; m2 < 4; ++m2) {
            int row = wr2 * 64 + m2 * 16 + l15;
            af2[m2] = *(const v8bf*)(smem + TOFF + row * 256 + ((ks * 64 + l4 * 16) ^ ((row & 7) << 4)));
        }
        #pragma unroll
        for (int n2 = 0; n2 < 2; ++n2) {
            int nn = wc2 * 32 + n2 * 16 + l15;
            bf2[n2] = *(const v8bf*)(w2t + nn * 128 + ks * 32 + l4 * 8);
        }
        #pragma unroll
        for (int m2 = 0; m2 < 4; ++m2)
            #pragma unroll
            for (int n2 = 0; n2 < 2; ++n2)
                acc2[m2][n2] = __builtin_amdgcn_mfma_f32_16x16x32_bf16(af2[m2], bf2[n2], acc2[m2][n2], 0, 0, 0);
    }
    __syncthreads();
    float b2c[2];
    #pragma unroll
    for (int n2 = 0; n2 < 2; ++n2) b2c[n2] = b2[wc2 * 32 + n2 * 16 + l15];
    #pragma unroll
    for (int m2 = 0; m2 < 4; ++m2) {
        #pragma unroll
        for (int j = 0; j < 4; ++j) {
            int row = wr2 * 64 + m2 * 16 + l4 * 4 + j;
            int rx = (row & 7) << 4;
            #pragma unroll
            for (int n2 = 0; n2 < 2; ++n2) {
                int col = wc2 * 32 + n2 * 16 + l15;
                float v = elu_f(acc2[m2][n2][j] + b2c[n2]);
                *(float*)(smem + row * 256 + ((col * 4) ^ rx)) = v;
            }
        }
    }
    __syncthreads();

    // ---- stage C: xw1b[r][n] = bf16( dis * sum_k H3[r][k] * g1w[k][n] ) ----
    int r = tid >> 1;
    int nb = (tid & 1) * 16;
    int gr = m0 + r;
    float o[16] = {};
    int rx = (r & 7) << 4;
    #pragma unroll 4
    for (int k4 = 0; k4 < 16; ++k4) {
        float4 h4 = *(const float4*)(smem + r * 256 + ((k4 * 16) ^ rx));
        #pragma unroll
        for (int e = 0; e < 4; ++e) {
            const float4* gp = (const float4*)(smem + G1OFF + (k4 * 4 + e) * 128 + nb * 4);
            float hv = (e == 0) ? h4.x : (e == 1) ? h4.y : (e == 2) ? h4.z : h4.w;
            #pragma unroll
            for (int q = 0; q < 4; ++q) {
                float4 g = gp[q];
                o[4 * q + 0] += hv * g.x;
                o[4 * q + 1] += hv * g.y;
                o[4 * q + 2] += hv * g.z;
                o[4 * q + 3] += hv * g.w;
            }
        }
    }
    if (gr < M) {
        float d = dis[gr];
        v8bf pk0, pk1;
        #pragma unroll
        for (int j2 = 0; j2 < 8; ++j2) {
            pk0[j2] = (__bf16)(o[j2] * d);
            pk1[j2] = (__bf16)(o[8 + j2] * d);
        }
        *(v8bf*)(xw1b + (size_t)gr * 32 + nb) = pk0;
        *(v8bf*)(xw1b + (size_t)gr * 32 + nb + 8) = pk1;
    }
}

// ---------------- gather1 + GCN2 transform fused ----------------------------
// 4 lanes/node, each owns 8 feats (16B loads); csr16 read as us8 (8 edges/load)
__global__ void gather1_kernel(const unsigned short* __restrict__ xw1b,
                               const unsigned short* __restrict__ csr16,
                               const int* __restrict__ ptr,
                               const float* __restrict__ dis, const float* __restrict__ g1b,
                               const float* __restrict__ g2w, __bf16* __restrict__ xw2b) {
    __shared__ float g2t[512];  // transposed: g2t[n*32+k] = g2w[k*16+n]
    int t = threadIdx.x;
    {
        int k = t >> 4, n = t & 15;
        g2t[n * 32 + k] = g2w[t];
        int j = t + 256;
        k = j >> 4; n = j & 15;
        g2t[n * 32 + k] = g2w[j];
    }
    __syncthreads();
    int idx = blockIdx.x * 256 + t;
    int node = idx >> 2, q = idx & 3;
    if (node >= N_NODES) return;
    int s = ptr[node], e = ptr[node + 1];
    const char* xwb = (const char*)xw1b;  // row stride 64B; lane offset q*16
    float a[8];
    {
        us8 u = *(const us8*)(xwb + (size_t)node * 64 + q * 16);
        #pragma unroll
        for (int j = 0; j < 8; ++j) a[j] = __uint_as_float(((unsigned)u[j]) << 16);
    }
    int i = s;
    for (; (i & 7) && i < e; ++i)
        bf8acc(a, *(const us8*)(xwb + (size_t)csr16[i] * 64 + q * 16));
    for (; i + 8 <= e; i += 8) {
        us8 rr = *(const us8*)&csr16[i];
        us8 u0 = *(const us8*)(xwb + (size_t)rr[0] * 64 + q * 16);
        us8 u1 = *(const us8*)(xwb + (size_t)rr[1] * 64 + q * 16);
        us8 u2 = *(const us8*)(xwb + (size_t)rr[2] * 64 + q * 16);
        us8 u3 = *(const us8*)(xwb + (size_t)rr[3] * 64 + q * 16);
        us8 u4 = *(const us8*)(xwb + (size_t)rr[4] * 64 + q * 16);
        us8 u5 = *(const us8*)(xwb + (size_t)rr[5] * 64 + q * 16);
        us8 u6 = *(const us8*)(xwb + (size_t)rr[6] * 64 + q * 16);
        us8 u7 = *(const us8*)(xwb + (size_t)rr[7] * 64 + q * 16);
        bf8acc(a, u0); bf8acc(a, u1); bf8acc(a, u2); bf8acc(a, u3);
        bf8acc(a, u4); bf8acc(a, u5); bf8acc(a, u6); bf8acc(a, u7);
    }
    for (; i < e; ++i)
        bf8acc(a, *(const us8*)(xwb + (size_t)csr16[i] * 64 + q * 16));
    float d = dis[node];
    float4 bb0 = ((const float4*)g1b)[2 * q];
    float4 bb1 = ((const float4*)g1b)[2 * q + 1];
    a[0] = elu_f(d * a[0] + bb0.x); a[1] = elu_f(d * a[1] + bb0.y);
    a[2] = elu_f(d * a[2] + bb0.z); a[3] = elu_f(d * a[3] + bb0.w);
    a[4] = elu_f(d * a[4] + bb1.x); a[5] = elu_f(d * a[5] + bb1.y);
    a[6] = elu_f(d * a[6] + bb1.z); a[7] = elu_f(d * a[7] + bb1.w);
    // xw2[n] = d * sum_k agg[k]*g2w[k][n]; lane owns k = 8q..8q+7
    float p[16];
    const int k0 = 8 * q;
    #pragma unroll
    for (int n = 0; n < 16; ++n) {
        const float* g = &g2t[n * 32 + k0];
        float acc = a[0] * g[0];
        #pragma unroll
        for (int j = 1; j < 8; ++j) acc += a[j] * g[j];
        p[n] = acc;
    }
    #pragma unroll
    for (int off = 1; off < 4; off <<= 1)
        #pragma unroll
        for (int n = 0; n < 16; ++n)
            p[n] += __shfl_xor(p[n], off);
    __bf16 pk[4];
    pk[0] = (__bf16)(d * p[4 * q + 0]);
    pk[1] = (__bf16)(d * p[4 * q + 1]);
    pk[2] = (__bf16)(d * p[4 * q + 2]);
    pk[3] = (__bf16)(d * p[4 * q + 3]);
    *(ushort4*)(xw2b + (size_t)node * 16 + 4 * q) = *(ushort4*)pk;
}

// ---------------- gather2: final aggregation into out -----------------------
// 2 lanes/node, each owns 8 feats (16B loads); csr16 as us8 (8 edges/load).
__global__ void gather2_kernel(const unsigned short* __restrict__ xw2b,
                               const unsigned short* __restrict__ csr16,
                               const int* __restrict__ ptr,
                               const float* __restrict__ dis, const float* __restrict__ g2b,
                               float* __restrict__ out) {
    int idx = blockIdx.x * 256 + threadIdx.x;
    int node = idx >> 1, q = idx & 1;
    if (node >= N_NODES) return;
    int s = ptr[node], e = ptr[node + 1];
    const char* xwb = (const char*)xw2b;  // row stride 32B; lane offset q*16
    float a[8];
    {
        us8 u = *(const us8*)(xwb + (size_t)node * 32 + q * 16);
        #pragma unroll
        for (int j = 0; j < 8; ++j) a[j] = __uint_as_float(((unsigned)u[j]) << 16);
    }
    int i = s;
    for (; (i & 7) && i < e; ++i)
        bf8acc(a, *(const us8*)(xwb + (size_t)csr16[i] * 32 + q * 16));
    for (; i + 8 <= e; i += 8) {
        us8 rr = *(const us8*)&csr16[i];
        us8 u0 = *(const us8*)(xwb + (size_t)rr[0] * 32 + q * 16);
        us8 u1 = *(const us8*)(xwb + (size_t)rr[1] * 32 + q * 16);
        us8 u2 = *(const us8*)(xwb + (size_t)rr[2] * 32 + q * 16);
        us8 u3 = *(const us8*)(xwb + (size_t)rr[3] * 32 + q * 16);
        us8 u4 = *(const us8*)(xwb + (size_t)rr[4] * 32 + q * 16);
        us8 u5 = *(const us8*)(xwb + (size_t)rr[5] * 32 + q * 16);
        us8 u6 = *(const us8*)(xwb + (size_t)rr[6] * 32 + q * 16);
        us8 u7 = *(const us8*)(xwb + (size_t)rr[7] * 32 + q * 16);
        bf8acc(a, u0); bf8acc(a, u1); bf8acc(a, u2); bf8acc(a, u3);
        bf8acc(a, u4); bf8acc(a, u5); bf8acc(a, u6); bf8acc(a, u7);
    }
    for (; i < e; ++i)
        bf8acc(a, *(const us8*)(xwb + (size_t)csr16[i] * 32 + q * 16));
    float d = dis[node];
    float4 bb0 = ((const float4*)g2b)[2 * q];
    float4 bb1 = ((const float4*)g2b)[2 * q + 1];
    float4 o0, o1;
    o0.x = d * a[0] + bb0.x; o0.y = d * a[1] + bb0.y;
    o0.z = d * a[2] + bb0.z; o0.w = d * a[3] + bb0.w;
    o1.x = d * a[4] + bb1.x; o1.y = d * a[5] + bb1.y;
    o1.z = d * a[6] + bb1.z; o1.w = d * a[7] + bb1.w;
    ((float4*)out)[(size_t)node * 4 + 2 * q] = o0;
    ((float4*)out)[(size_t)node * 4 + 2 * q + 1] = o1;
}

extern "C" void kernel_launch(void* const* d_in, const int* in_sizes, int n_in,
                              void* d_out, int out_size, void* d_ws, size_t ws_size,
                              hipStream_t stream) {
    const float* x    = (const float*)d_in[0];
    const int*   ei   = (const int*)d_in[1];
    const int*   row  = ei;
    const int*   col  = ei + N_EDGES;
    const float* ln_w = (const float*)d_in[2];
    const float* ln_b = (const float*)d_in[3];
    const float* w0   = (const float*)d_in[4];
    const float* b0   = (const float*)d_in[5];
    const float* w1   = (const float*)d_in[6];
    const float* b1   = (const float*)d_in[7];
    const float* w2   = (const float*)d_in[8];
    const float* b2   = (const float*)d_in[9];
    const float* g1w  = (const float*)d_in[10];
    const float* g1b  = (const float*)d_in[11];
    const float* g2w  = (const float*)d_in[12];
    const float* g2b  = (const float*)d_in[13];
    float* out = (float*)d_out;

    char* W = (char*)d_ws;
    __bf16* h0   = (__bf16*)(W + 0);          // 50000*1024 bf16
    __bf16* h1   = (__bf16*)(W + 102400000);  // 50000*512 bf16
    float*  dis  = (float*) (W + 179200000);  // 50000 f32
    __bf16* xw1b = (__bf16*)(W + 179400192);  // 50000*32 bf16 (dis-scaled)
    __bf16* xw2b = (__bf16*)(W + 185800192);  // 50000*16 bf16 (dis-scaled)
    __bf16* w0t  = (__bf16*)(W + 195400192);  // 512*1024 bf16
    __bf16* w1t  = (__bf16*)(W + 196448768);  // 128*512 bf16
    __bf16* w2t  = (__bf16*)(W + 196579840);  // 64*128 bf16
    unsigned short* csr16 = (unsigned short*)(W + 200000000);  // 3.2M u16
    int*    ptr  = (int*)(W + 213000192);     // 50001 int
    unsigned int* tmp = (unsigned int*)(W + 214000128);  // NB1*CAP u32
    int*    fill196 = (int*)(W + 231000064);  // 196 int (zero-based counts)

    // fill196 <- 0 (p1 reservations are t*CAP + count)
    hipMemsetAsync(fill196, 0, NB1 * sizeof(int), stream);

    // 1. pool+LN (wave per node) + wt prep + p1 bucket scatter side-work
    pool_ln_kernel<<<N_NODES / 4, 256, 0, stream>>>(
        x, ln_w, ln_b, h0, w0, w1, w2, w0t, w1t, w2t, fill196, row, col, tmp);

    // 2. GEMM0 (h0 -> h1, XCD-swizzled) + p2 tail blocks (csr16 + ptr + dis)
    gemm0_p2_kernel<<<G0_BLKS + NB1, 512, 0, stream>>>(
        h0, w0t, b0, h1, N_NODES, tmp, fill196, csr16, ptr, dis);

    // 3. fused MLP tail: h1 -> xw1b
    mlp_tail_kernel<<<(N_NODES + 127) / 128, 256, 73728, stream>>>(
        h1, w1t, b1, w2t, b2, g1w, dis, xw1b, N_NODES);

    // 4. gather1 + GCN1 bias/ELU + GCN2 transform -> xw2b
    gather1_kernel<<<((N_NODES * 4) + 255) / 256, 256, 0, stream>>>(
        (const unsigned short*)xw1b, csr16, ptr, dis, g1b, g2w, xw2b);

    // 5. gather2 -> out (+g2b)
    gather2_kernel<<<((N_NODES * 2) + 255) / 256, 256, 0, stream>>>(
        (const unsigned short*)xw2b, csr16, ptr, dis, g2b, out);
}

// Round 13
// 331.187 us; speedup vs baseline: 2.8352x; 1.0056x over previous
//
#include <hip/hip_runtime.h>
#include <hip/hip_bf16.h>

#define N_NODES 50000
#define N_EDGES 3200000
#define NB1 196            // (N_NODES-1)>>8 + 1
#define NBLK1 782          // ceil(N_EDGES/4096)
#define CAP 20480          // per-bin tmp capacity (avg 16327, sigma ~128)
#define WT_BLKS 2336       // weight-transpose side-work blocks
#define G0_BLKS 782        // GEMM0 blocks (391 x 2)
#define MT_BLKS 391        // mlp_tail main blocks
#define WARM_BLKS 25       // csr16 L2-warm tail blocks on mlp_tail grid

typedef __bf16 v8bf __attribute__((ext_vector_type(8)));
typedef __bf16 v2bf __attribute__((ext_vector_type(2)));
typedef float v4f __attribute__((ext_vector_type(4)));
typedef unsigned short us8 __attribute__((ext_vector_type(8)));

__device__ __forceinline__ float elu_f(float x) { return x > 0.f ? x : (expf(x) - 1.f); }

__device__ __forceinline__ void bf8acc(float* a, us8 u) {
    #pragma unroll
    for (int j = 0; j < 8; ++j) a[j] += __uint_as_float(((unsigned)u[j]) << 16);
}

// async global->LDS, 16B per lane; LDS dest = wave-uniform base + lane*16
#define GL16(gp, lp) __builtin_amdgcn_global_load_lds( \
    (const __attribute__((address_space(1))) void*)(gp), \
    (__attribute__((address_space(3))) void*)(lp), 16, 0, 0)

// ---------------- fused maxpool(2)+LayerNorm -> bf16 ; + wt prep + p1 -------
__global__ void pool_ln_kernel(const float* __restrict__ x,
                               const float* __restrict__ ln_w,
                               const float* __restrict__ ln_b,
                               __bf16* __restrict__ h0,
                               const float* __restrict__ w0, const float* __restrict__ w1,
                               const float* __restrict__ w2,
                               __bf16* __restrict__ w0t, __bf16* __restrict__ w1t,
                               __bf16* __restrict__ w2t, int* __restrict__ fill196,
                               const int* __restrict__ erow, const int* __restrict__ ecol,
                               unsigned int* __restrict__ tmp) {
    __shared__ int h[NB1], bl[NB1];
    int t = threadIdx.x;
    // --- pool + LN (all blocks) ---
    {
        int wave = t >> 6, lane = t & 63;
        int node = blockIdx.x * 4 + wave;
        const float4* xr = (const float4*)(x + (size_t)node * 2048);
        float4 v[8];
        #pragma unroll
        for (int j = 0; j < 8; ++j) v[j] = xr[j * 64 + lane];
        float p[16];
        float sum = 0.f, sq = 0.f;
        #pragma unroll
        for (int j = 0; j < 8; ++j) {
            p[2 * j]     = fmaxf(v[j].x, v[j].y);
            p[2 * j + 1] = fmaxf(v[j].z, v[j].w);
            sum += p[2 * j] + p[2 * j + 1];
            sq  += p[2 * j] * p[2 * j] + p[2 * j + 1] * p[2 * j + 1];
        }
        #pragma unroll
        for (int off = 32; off > 0; off >>= 1) {
            sum += __shfl_xor(sum, off);
            sq  += __shfl_xor(sq, off);
        }
        float mu = sum * (1.f / 1024.f);
        float var = sq * (1.f / 1024.f) - mu * mu;
        float rstd = rsqrtf(var + 1e-5f);
        const float2* w2p = (const float2*)ln_w;
        const float2* b2p = (const float2*)ln_b;
        #pragma unroll
        for (int j = 0; j < 8; ++j) {
            int c2 = j * 64 + lane;
            float2 w = w2p[c2], b = b2p[c2];
            v2bf o;
            o[0] = (__bf16)((p[2 * j]     - mu) * rstd * w.x + b.x);
            o[1] = (__bf16)((p[2 * j + 1] - mu) * rstd * w.y + b.y);
            *(v2bf*)(h0 + (size_t)node * 1024 + 2 * c2) = o;
        }
    }
    // --- side work ---
    if (blockIdx.x < WT_BLKS) {
        int idx = blockIdx.x * 256 + t;
        if (idx < 524288) {            // w0: 1024x512
            int k = idx >> 9, n = idx & 511;
            w0t[(size_t)n * 1024 + k] = (__bf16)w0[idx];
        } else if (idx < 524288 + 65536) {  // w1: 512x128
            int j = idx - 524288;
            int k = j >> 7, n = j & 127;
            w1t[(size_t)n * 512 + k] = (__bf16)w1[j];
        } else if (idx < 524288 + 65536 + 8192) {  // w2: 128x64
            int j = idx - 524288 - 65536;
            int k = j >> 6, n = j & 63;
            w2t[(size_t)n * 128 + k] = (__bf16)w2[j];
        }
    } else if (blockIdx.x < WT_BLKS + NBLK1) {
        int cb = blockIdx.x - WT_BLKS;  // edge chunk id (4096 edges)
        if (t < NB1) h[t] = 0;
        __syncthreads();
        const int4* col4 = (const int4*)ecol;
        const int4* row4 = (const int4*)erow;
        int base4 = cb * 1024;  // int4 units
        int cc[16];
        #pragma unroll
        for (int j = 0; j < 4; ++j) {
            int i4 = base4 + j * 256 + t;
            if (i4 * 4 < N_EDGES) {
                int4 c = col4[i4];
                cc[4 * j] = c.x; cc[4 * j + 1] = c.y;
                cc[4 * j + 2] = c.z; cc[4 * j + 3] = c.w;
            } else {
                cc[4 * j] = cc[4 * j + 1] = cc[4 * j + 2] = cc[4 * j + 3] = -1;
            }
        }
        #pragma unroll
        for (int j = 0; j < 16; ++j)
            if (cc[j] >= 0) atomicAdd(&h[cc[j] >> 8], 1);
        __syncthreads();
        if (t < NB1 && h[t] > 0)
            bl[t] = t * CAP + atomicAdd(&fill196[t], h[t]);  // fill196 zero-init
        __syncthreads();
        #pragma unroll
        for (int j = 0; j < 4; ++j) {
            int i4 = base4 + j * 256 + t;
            if (i4 * 4 < N_EDGES) {
                int4 r4 = row4[i4];
                int rr[4] = {r4.x, r4.y, r4.z, r4.w};
                #pragma unroll
                for (int u = 0; u < 4; ++u) {
                    int c = cc[4 * j + u];
                    int pos = atomicAdd(&bl[c >> 8], 1);
                    tmp[pos] = ((unsigned int)c << 16) | (unsigned int)rr[u];
                }
            }
        }
    }
}

// ---------------- GEMM0 (XCD-swizzled 128x256 tiles) + p2 tail blocks -------
__global__ __launch_bounds__(512) void gemm0_p2_kernel(
    const __bf16* __restrict__ A, const __bf16* __restrict__ BT,
    const float* __restrict__ bias, __bf16* __restrict__ C, int M,
    const unsigned int* __restrict__ tmp, const int* __restrict__ fill196,
    unsigned short* __restrict__ csr16, int* __restrict__ ptr, float* __restrict__ dis)
{
    __shared__ char smem[24576];
    const int tid = threadIdx.x;
    int b = blockIdx.x;

    if (b >= G0_BLKS) {
        // ---- p2: group bin by col&255; emit csr16 + ptr + dis ----
        int seg = b - G0_BLKS;
        int* h2 = (int*)smem;          // 256
        int* b2 = (int*)smem + 256;    // 256
        int* s2 = (int*)smem + 512;    // 256
        int* shp = (int*)smem + 768;   // 1
        int start = seg * CAP;
        int cnt = fill196[seg];
        int end = start + cnt;
        int t = tid;
        if (t < 256) s2[t] = (t < seg) ? fill196[t] : 0;
        __syncthreads();
        for (int off = 128; off > 0; off >>= 1) {
            if (t < off) s2[t] += s2[t + off];
            __syncthreads();
        }
        if (t == 0) shp[0] = s2[0];
        if (t < 256) h2[t] = 0;
        __syncthreads();
        int ng = cnt >> 2;  // full uint4 groups
        for (int g = t; g < ng; g += 512) {
            uint4 v = *(const uint4*)&tmp[start + g * 4];
            atomicAdd(&h2[(v.x >> 16) & 255], 1);
            atomicAdd(&h2[(v.y >> 16) & 255], 1);
            atomicAdd(&h2[(v.z >> 16) & 255], 1);
            atomicAdd(&h2[(v.w >> 16) & 255], 1);
        }
        for (int i = start + (ng << 2) + t; i < end; i += 512)
            atomicAdd(&h2[(tmp[i] >> 16) & 255], 1);
        __syncthreads();
        if (t < 256) s2[t] = h2[t];
        __syncthreads();
        for (int off = 1; off < 256; off <<= 1) {
            int u = 0;
            if (t < 256 && t >= off) u = s2[t - off];
            __syncthreads();
            if (t < 256) s2[t] += u;
            __syncthreads();
        }
        if (t < 256) {
            int p = shp[0] + s2[t] - h2[t];
            b2[t] = p;
            int node = (seg << 8) + t;
            if (node < N_NODES) {
                ptr[node] = p;
                dis[node] = rsqrtf((float)(h2[t] + 1));
            }
        }
        if (seg == NB1 - 1 && t == 0) ptr[N_NODES] = N_EDGES;
        __syncthreads();
        for (int g = t; g < ng; g += 512) {
            uint4 v = *(const uint4*)&tmp[start + g * 4];
            int p0 = atomicAdd(&b2[(v.x >> 16) & 255], 1); csr16[p0] = (unsigned short)(v.x & 0xFFFFu);
            int p1 = atomicAdd(&b2[(v.y >> 16) & 255], 1); csr16[p1] = (unsigned short)(v.y & 0xFFFFu);
            int p2_ = atomicAdd(&b2[(v.z >> 16) & 255], 1); csr16[p2_] = (unsigned short)(v.z & 0xFFFFu);
            int p3 = atomicAdd(&b2[(v.w >> 16) & 255], 1); csr16[p3] = (unsigned short)(v.w & 0xFFFFu);
        }
        for (int i = start + (ng << 2) + t; i < end; i += 512) {
            unsigned int v = tmp[i];
            int pos = atomicAdd(&b2[(v >> 16) & 255], 1);
            csr16[pos] = (unsigned short)(v & 0xFFFFu);
        }
        return;
    }

    // ---- GEMM0: bijective XCD-chunk swizzle (782 = 8*97+6), pairs share A ----
    {
        const int q = 97, r = 6;
        int xcd = b & 7, pos = b >> 3;
        int wg = (xcd < r ? xcd * (q + 1) : r * (q + 1) + (xcd - r) * q) + pos;
        b = wg;
    }
    const int K = 1024, N = 512;
    unsigned short* lds = (unsigned short*)smem;
    const int lane = tid & 63, w = tid >> 6;
    const int wr = w >> 2, wc = w & 3;
    const int m0 = (b >> 1) * 128, n0 = (b & 1) * 256;

    int grA = m0 + (tid >> 2); if (grA > M - 1) grA = M - 1;
    const __bf16* aP = A + (size_t)grA * K + (tid & 3) * 8;
    char* ldsA = (char*)lds + tid * 16;
    const __bf16* bP0 = BT + (size_t)(n0 + (tid >> 2)) * K + (tid & 3) * 8;
    const __bf16* bP1 = BT + (size_t)(n0 + ((tid + 512) >> 2)) * K + (tid & 3) * 8;
    char* ldsB0 = (char*)lds + 8192 + tid * 16;
    char* ldsB1 = (char*)lds + 16384 + tid * 16;

    v4f acc[4][4] = {};
    const int l15 = lane & 15, l4 = lane >> 4;
    const int abase = (wr * 64 + l15) * 32 + l4 * 8;
    const int bbase = 4096 + (wc * 64 + l15) * 32 + l4 * 8;

    for (int k0 = 0; k0 < K; k0 += 32) {
        GL16(aP + k0, ldsA);
        GL16(bP0 + k0, ldsB0);
        GL16(bP1 + k0, ldsB1);
        __syncthreads();
        v8bf af[4], bfr[4];
        #pragma unroll
        for (int m = 0; m < 4; ++m) af[m]  = *(const v8bf*)&lds[abase + m * 16 * 32];
        #pragma unroll
        for (int n = 0; n < 4; ++n) bfr[n] = *(const v8bf*)&lds[bbase + n * 16 * 32];
        #pragma unroll
        for (int m = 0; m < 4; ++m)
            #pragma unroll
            for (int n = 0; n < 4; ++n)
                acc[m][n] = __builtin_amdgcn_mfma_f32_16x16x32_bf16(af[m], bfr[n], acc[m][n], 0, 0, 0);
        __syncthreads();
    }

    #pragma unroll
    for (int m = 0; m < 4; ++m) {
        #pragma unroll
        for (int j = 0; j < 4; ++j) {
            int row = m0 + wr * 64 + m * 16 + l4 * 4 + j;
            if (row >= M) continue;
            #pragma unroll
            for (int n = 0; n < 4; ++n) {
                int col = n0 + wc * 64 + n * 16 + l15;
                float v = acc[m][n][j] + bias[col];
                C[(size_t)row * N + col] = (__bf16)elu_f(v);
            }
        }
    }
}

// ---------------- fused MLP tail + csr16 L2-warm tail blocks ----------------
__global__ __launch_bounds__(256) void mlp_tail_kernel(
    const __bf16* __restrict__ h1, const __bf16* __restrict__ w1t,
    const float* __restrict__ b1, const __bf16* __restrict__ w2t,
    const float* __restrict__ b2, const float* __restrict__ g1w,
    const float* __restrict__ dis, __bf16* __restrict__ xw1b, int M,
    const unsigned short* __restrict__ csr16)
{
    extern __shared__ char smem[];
    const int tid = threadIdx.x;

    if (blockIdx.x >= MT_BLKS) {
        // warm csr16 (6.4MB) into LLC ahead of gather1; keep-alive via asm
        int wb = blockIdx.x - MT_BLKS;
        const uint4* c4 = (const uint4*)csr16;  // 400000 uint4 total
        unsigned acc = 0;
        for (int i = wb * 256 + tid; i < 400000; i += WARM_BLKS * 256) {
            uint4 v = c4[i];
            acc ^= v.x ^ v.y ^ v.z ^ v.w;
        }
        asm volatile("" :: "v"(acc));  // prevent DCE of the warm loads
        return;
    }

    const int G1OFF = 32768, TOFF = 40960;
    const int lane = tid & 63, wave = tid >> 6;
    const int l15 = lane & 15, l4 = lane >> 4;
    const int m0 = blockIdx.x * 128;

    {
        const float4* g4 = (const float4*)g1w;
        float4* d4 = (float4*)(smem + G1OFF);
        d4[tid] = g4[tid];
        d4[tid + 256] = g4[tid + 256];
    }

    // ---- stage A: GEMM1 rows m0..m0+127, N=128, K=512 ----
    const int wr = wave >> 1, wc = wave & 1;
    const int s0 = tid, s1 = tid + 256;
    int gr0 = m0 + (s0 >> 2); if (gr0 > M - 1) gr0 = M - 1;
    int gr1 = m0 + (s1 >> 2); if (gr1 > M - 1) gr1 = M - 1;
    const __bf16* a0p = h1 + (size_t)gr0 * 512 + (s0 & 3) * 8;
    const __bf16* a1p = h1 + (size_t)gr1 * 512 + (s1 & 3) * 8;
    const __bf16* b0p = w1t + (size_t)(s0 >> 2) * 512 + (s0 & 3) * 8;
    const __bf16* b1p = w1t + (size_t)(s1 >> 2) * 512 + (s1 & 3) * 8;
    char* stA0 = smem + s0 * 16;
    char* stA1 = smem + s1 * 16;
    char* stB0 = smem + 8192 + s0 * 16;
    char* stB1 = smem + 8192 + s1 * 16;
    const int aoff = (wr * 64 + l15) * 64 + l4 * 16;
    const int boff = 8192 + (wc * 64 + l15) * 64 + l4 * 16;

    v4f acc1[4][4] = {};
    for (int k0 = 0; k0 < 512; k0 += 32) {
        GL16(a0p + k0, stA0);
        GL16(a1p + k0, stA1);
        GL16(b0p + k0, stB0);
        GL16(b1p + k0, stB1);
        __syncthreads();
        v8bf af[4], bfr[4];
        #pragma unroll
        for (int m = 0; m < 4; ++m) af[m]  = *(const v8bf*)(smem + aoff + m * 1024);
        #pragma unroll
        for (int n = 0; n < 4; ++n) bfr[n] = *(const v8bf*)(smem + boff + n * 1024);
        #pragma unroll
        for (int m = 0; m < 4; ++m)
            #pragma unroll
            for (int n = 0; n < 4; ++n)
                acc1[m][n] = __builtin_amdgcn_mfma_f32_16x16x32_bf16(af[m], bfr[n], acc1[m][n], 0, 0, 0);
        __syncthreads();
    }
    float b1c[4];
    #pragma unroll
    for (int n = 0; n < 4; ++n) b1c[n] = b1[wc * 64 + n * 16 + l15];
    #pragma unroll
    for (int m = 0; m < 4; ++m) {
        #pragma unroll
        for (int j = 0; j < 4; ++j) {
            int row = wr * 64 + m * 16 + l4 * 4 + j;
            int rx = (row & 7) << 4;
            #pragma unroll
            for (int n = 0; n < 4; ++n) {
                int colb = (wc * 64 + n * 16 + l15) * 2;
                float v = elu_f(acc1[m][n][j] + b1c[n]);
                *(__bf16*)(smem + TOFF + row * 256 + (colb ^ rx)) = (__bf16)v;
            }
        }
    }
    __syncthreads();

    // ---- stage B: GEMM2 128x64, K=128 ----
    const int wr2 = wave >> 1, wc2 = wave & 1;
    v4f acc2[4][2] = {};
    #pragma unroll
    for (int ks = 0; ks < 4; ++ks) {
        v8bf af2[4], bf2[2];
        #pragma unroll
        for (int m2 = 0; m2 < 4; ++m2) {
            int row = wr2 * 64 + m2 * 16 + l15;
            af2[m2] = *(const v8bf*)(smem + TOFF + row * 256 + ((ks * 64 + l4 * 16) ^ ((row & 7) << 4)));
        }
        #pragma unroll
        for (int n2 = 0; n2 < 2; ++n2) {
            int nn = wc2 * 32 + n2 * 16 + l15;
            bf2[n2] = *(const v8bf*)(w2t + nn * 128 + ks * 32 + l4 * 8);
        }
        #pragma unroll
        for (int m2 = 0; m2 < 4; ++m2)
            #pragma unroll
            for (int n2 = 0; n2 < 2; ++n2)
                acc2[m2][n2] = __builtin_amdgcn_mfma_f32_16x16x32_bf16(af2[m2], bf2[n2], acc2[m2][n2], 0, 0, 0);
    }
    __syncthreads();
    float b2c[2];
    #pragma unroll
    for (int n2 = 0; n2 < 2; ++n2) b2c[n2] = b2[wc2 * 32 + n2 * 16 + l15];
    #pragma unroll
    for (int m2 = 0; m2 < 4; ++m2) {
        #pragma unroll
        for (int j = 0; j < 4; ++j) {
            int row = wr2 * 64 + m2 * 16 + l4 * 4 + j;
            int rx = (row & 7) << 4;
            #pragma unroll
            for (int n2 = 0; n2 < 2; ++n2) {
                int col = wc2 * 32 + n2 * 16 + l15;
                float v = elu_f(acc2[m2][n2][j] + b2c[n2]);
                *(float*)(smem + row * 256 + ((col * 4) ^ rx)) = v;
            }
        }
    }
    __syncthreads();

    // ---- stage C: xw1b[r][n] = bf16( dis * sum_k H3[r][k] * g1w[k][n] ) ----
    int r = tid >> 1;
    int nb = (tid & 1) * 16;
    int gr = m0 + r;
    float o[16] = {};
    int rx = (r & 7) << 4;
    #pragma unroll 4
    for (int k4 = 0; k4 < 16; ++k4) {
        float4 h4 = *(const float4*)(smem + r * 256 + ((k4 * 16) ^ rx));
        #pragma unroll
        for (int e = 0; e < 4; ++e) {
            const float4* gp = (const float4*)(smem + G1OFF + (k4 * 4 + e) * 128 + nb * 4);
            float hv = (e == 0) ? h4.x : (e == 1) ? h4.y : (e == 2) ? h4.z : h4.w;
            #pragma unroll
            for (int q = 0; q < 4; ++q) {
                float4 g = gp[q];
                o[4 * q + 0] += hv * g.x;
                o[4 * q + 1] += hv * g.y;
                o[4 * q + 2] += hv * g.z;
                o[4 * q + 3] += hv * g.w;
            }
        }
    }
    if (gr < M) {
        float d = dis[gr];
        v8bf pk0, pk1;
        #pragma unroll
        for (int j2 = 0; j2 < 8; ++j2) {
            pk0[j2] = (__bf16)(o[j2] * d);
            pk1[j2] = (__bf16)(o[8 + j2] * d);
        }
        *(v8bf*)(xw1b + (size_t)gr * 32 + nb) = pk0;
        *(v8bf*)(xw1b + (size_t)gr * 32 + nb + 8) = pk1;
    }
}

// ---------------- gather1 + GCN2 transform fused ----------------------------
// 4 lanes/node, each owns 8 feats (16B loads); csr16 in 16-edge groups.
__global__ void gather1_kernel(const unsigned short* __restrict__ xw1b,
                               const unsigned short* __restrict__ csr16,
                               const int* __restrict__ ptr,
                               const float* __restrict__ dis, const float* __restrict__ g1b,
                               const float* __restrict__ g2w, __bf16* __restrict__ xw2b) {
    __shared__ float g2t[512];  // transposed: g2t[n*32+k] = g2w[k*16+n]
    int t = threadIdx.x;
    {
        int k = t >> 4, n = t & 15;
        g2t[n * 32 + k] = g2w[t];
        int j = t + 256;
        k = j >> 4; n = j & 15;
        g2t[n * 32 + k] = g2w[j];
    }
    __syncthreads();
    int idx = blockIdx.x * 256 + t;
    int node = idx >> 2, q = idx & 3;
    if (node >= N_NODES) return;
    int2 se = *(const int2*)&ptr[node];
    int s = se.x, e = se.y;
    const char* xwb = (const char*)xw1b;  // row stride 64B; lane offset q*16
    float a[8];
    {
        us8 u = *(const us8*)(xwb + (size_t)node * 64 + q * 16);
        #pragma unroll
        for (int j = 0; j < 8; ++j) a[j] = __uint_as_float(((unsigned)u[j]) << 16);
    }
    int i = s;
    for (; (i & 7) && i < e; ++i)
        bf8acc(a, *(const us8*)(xwb + (size_t)csr16[i] * 64 + q * 16));
    for (; i + 16 <= e; i += 16) {
        us8 ra = *(const us8*)&csr16[i];
        us8 rb = *(const us8*)&csr16[i + 8];
        us8 u0 = *(const us8*)(xwb + (size_t)ra[0] * 64 + q * 16);
        us8 u1 = *(const us8*)(xwb + (size_t)ra[1] * 64 + q * 16);
        us8 u2 = *(const us8*)(xwb + (size_t)ra[2] * 64 + q * 16);
        us8 u3 = *(const us8*)(xwb + (size_t)ra[3] * 64 + q * 16);
        us8 u4 = *(const us8*)(xwb + (size_t)ra[4] * 64 + q * 16);
        us8 u5 = *(const us8*)(xwb + (size_t)ra[5] * 64 + q * 16);
        us8 u6 = *(const us8*)(xwb + (size_t)ra[6] * 64 + q * 16);
        us8 u7 = *(const us8*)(xwb + (size_t)ra[7] * 64 + q * 16);
        us8 w0 = *(const us8*)(xwb + (size_t)rb[0] * 64 + q * 16);
        us8 w1 = *(const us8*)(xwb + (size_t)rb[1] * 64 + q * 16);
        us8 w2 = *(const us8*)(xwb + (size_t)rb[2] * 64 + q * 16);
        us8 w3 = *(const us8*)(xwb + (size_t)rb[3] * 64 + q * 16);
        us8 w4 = *(const us8*)(xwb + (size_t)rb[4] * 64 + q * 16);
        us8 w5 = *(const us8*)(xwb + (size_t)rb[5] * 64 + q * 16);
        us8 w6 = *(const us8*)(xwb + (size_t)rb[6] * 64 + q * 16);
        us8 w7 = *(const us8*)(xwb + (size_t)rb[7] * 64 + q * 16);
        bf8acc(a, u0); bf8acc(a, u1); bf8acc(a, u2); bf8acc(a, u3);
        bf8acc(a, u4); bf8acc(a, u5); bf8acc(a, u6); bf8acc(a, u7);
        bf8acc(a, w0); bf8acc(a, w1); bf8acc(a, w2); bf8acc(a, w3);
        bf8acc(a, w4); bf8acc(a, w5); bf8acc(a, w6); bf8acc(a, w7);
    }
    for (; i + 8 <= e; i += 8) {
        us8 rr = *(const us8*)&csr16[i];
        us8 u0 = *(const us8*)(xwb + (size_t)rr[0] * 64 + q * 16);
        us8 u1 = *(const us8*)(xwb + (size_t)rr[1] * 64 + q * 16);
        us8 u2 = *(const us8*)(xwb + (size_t)rr[2] * 64 + q * 16);
        us8 u3 = *(const us8*)(xwb + (size_t)rr[3] * 64 + q * 16);
        us8 u4 = *(const us8*)(xwb + (size_t)rr[4] * 64 + q * 16);
        us8 u5 = *(const us8*)(xwb + (size_t)rr[5] * 64 + q * 16);
        us8 u6 = *(const us8*)(xwb + (size_t)rr[6] * 64 + q * 16);
        us8 u7 = *(const us8*)(xwb + (size_t)rr[7] * 64 + q * 16);
        bf8acc(a, u0); bf8acc(a, u1); bf8acc(a, u2); bf8acc(a, u3);
        bf8acc(a, u4); bf8acc(a, u5); bf8acc(a, u6); bf8acc(a, u7);
    }
    for (; i < e; ++i)
        bf8acc(a, *(const us8*)(xwb + (size_t)csr16[i] * 64 + q * 16));
    float d = dis[node];
    float4 bb0 = ((const float4*)g1b)[2 * q];
    float4 bb1 = ((const float4*)g1b)[2 * q + 1];
    a[0] = elu_f(d * a[0] + bb0.x); a[1] = elu_f(d * a[1] + bb0.y);
    a[2] = elu_f(d * a[2] + bb0.z); a[3] = elu_f(d * a[3] + bb0.w);
    a[4] = elu_f(d * a[4] + bb1.x); a[5] = elu_f(d * a[5] + bb1.y);
    a[6] = elu_f(d * a[6] + bb1.z); a[7] = elu_f(d * a[7] + bb1.w);
    // xw2[n] = d * sum_k agg[k]*g2w[k][n]; lane owns k = 8q..8q+7
    float p[16];
    const int k0 = 8 * q;
    #pragma unroll
    for (int n = 0; n < 16; ++n) {
        const float* g = &g2t[n * 32 + k0];
        float acc = a[0] * g[0];
        #pragma unroll
        for (int j = 1; j < 8; ++j) acc += a[j] * g[j];
        p[n] = acc;
    }
    #pragma unroll
    for (int off = 1; off < 4; off <<= 1)
        #pragma unroll
        for (int n = 0; n < 16; ++n)
            p[n] += __shfl_xor(p[n], off);
    __bf16 pk[4];
    pk[0] = (__bf16)(d * p[4 * q + 0]);
    pk[1] = (__bf16)(d * p[4 * q + 1]);
    pk[2] = (__bf16)(d * p[4 * q + 2]);
    pk[3] = (__bf16)(d * p[4 * q + 3]);
    *(ushort4*)(xw2b + (size_t)node * 16 + 4 * q) = *(ushort4*)pk;
}

// ---------------- gather2: final aggregation into out -----------------------
// 2 lanes/node, each owns 8 feats (16B loads); csr16 in 16-edge groups.
__global__ void gather2_kernel(const unsigned short* __restrict__ xw2b,
                               const unsigned short* __restrict__ csr16,
                               const int* __restrict__ ptr,
                               const float* __restrict__ dis, const float* __restrict__ g2b,
                               float* __restrict__ out) {
    int idx = blockIdx.x * 256 + threadIdx.x;
    int node = idx >> 1, q = idx & 1;
    if (node >= N_NODES) return;
    int2 se = *(const int2*)&ptr[node];
    int s = se.x, e = se.y;
    const char* xwb = (const char*)xw2b;  // row stride 32B; lane offset q*16
    float a[8];
    {
        us8 u = *(const us8*)(xwb + (size_t)node * 32 + q * 16);
        #pragma unroll
        for (int j = 0; j < 8; ++j) a[j] = __uint_as_float(((unsigned)u[j]) << 16);
    }
    int i = s;
    for (; (i & 7) && i < e; ++i)
        bf8acc(a, *(const us8*)(xwb + (size_t)csr16[i] * 32 + q * 16));
    for (; i + 16 <= e; i += 16) {
        us8 ra = *(const us8*)&csr16[i];
        us8 rb = *(const us8*)&csr16[i + 8];
        us8 u0 = *(const us8*)(xwb + (size_t)ra[0] * 32 + q * 16);
        us8 u1 = *(const us8*)(xwb + (size_t)ra[1] * 32 + q * 16);
        us8 u2 = *(const us8*)(xwb + (size_t)ra[2] * 32 + q * 16);
        us8 u3 = *(const us8*)(xwb + (size_t)ra[3] * 32 + q * 16);
        us8 u4 = *(const us8*)(xwb + (size_t)ra[4] * 32 + q * 16);
        us8 u5 = *(const us8*)(xwb + (size_t)ra[5] * 32 + q * 16);
        us8 u6 = *(const us8*)(xwb + (size_t)ra[6] * 32 + q * 16);
        us8 u7 = *(const us8*)(xwb + (size_t)ra[7] * 32 + q * 16);
        us8 w0 = *(const us8*)(xwb + (size_t)rb[0] * 32 + q * 16);
        us8 w1 = *(const us8*)(xwb + (size_t)rb[1] * 32 + q * 16);
        us8 w2 = *(const us8*)(xwb + (size_t)rb[2] * 32 + q * 16);
        us8 w3 = *(const us8*)(xwb + (size_t)rb[3] * 32 + q * 16);
        us8 w4 = *(const us8*)(xwb + (size_t)rb[4] * 32 + q * 16);
        us8 w5 = *(const us8*)(xwb + (size_t)rb[5] * 32 + q * 16);
        us8 w6 = *(const us8*)(xwb + (size_t)rb[6] * 32 + q * 16);
        us8 w7 = *(const us8*)(xwb + (size_t)rb[7] * 32 + q * 16);
        bf8acc(a, u0); bf8acc(a, u1); bf8acc(a, u2); bf8acc(a, u3);
        bf8acc(a, u4); bf8acc(a, u5); bf8acc(a, u6); bf8acc(a, u7);
        bf8acc(a, w0); bf8acc(a, w1); bf8acc(a, w2); bf8acc(a, w3);
        bf8acc(a, w4); bf8acc(a, w5); bf8acc(a, w6); bf8acc(a, w7);
    }
    for (; i + 8 <= e; i += 8) {
        us8 rr = *(const us8*)&csr16[i];
        us8 u0 = *(const us8*)(xwb + (size_t)rr[0] * 32 + q * 16);
        us8 u1 = *(const us8*)(xwb + (size_t)rr[1] * 32 + q * 16);
        us8 u2 = *(const us8*)(xwb + (size_t)rr[2] * 32 + q * 16);
        us8 u3 = *(const us8*)(xwb + (size_t)rr[3] * 32 + q * 16);
        us8 u4 = *(const us8*)(xwb + (size_t)rr[4] * 32 + q * 16);
        us8 u5 = *(const us8*)(xwb + (size_t)rr[5] * 32 + q * 16);
        us8 u6 = *(const us8*)(xwb + (size_t)rr[6] * 32 + q * 16);
        us8 u7 = *(const us8*)(xwb + (size_t)rr[7] * 32 + q * 16);
        bf8acc(a, u0); bf8acc(a, u1); bf8acc(a, u2); bf8acc(a, u3);
        bf8acc(a, u4); bf8acc(a, u5); bf8acc(a, u6); bf8acc(a, u7);
    }
    for (; i < e; ++i)
        bf8acc(a, *(const us8*)(xwb + (size_t)csr16[i] * 32 + q * 16));
    float d = dis[node];
    float4 bb0 = ((const float4*)g2b)[2 * q];
    float4 bb1 = ((const float4*)g2b)[2 * q + 1];
    float4 o0, o1;
    o0.x = d * a[0] + bb0.x; o0.y = d * a[1] + bb0.y;
    o0.z = d * a[2] + bb0.z; o0.w = d * a[3] + bb0.w;
    o1.x = d * a[4] + bb1.x; o1.y = d * a[5] + bb1.y;
    o1.z = d * a[6] + bb1.z; o1.w = d * a[7] + bb1.w;
    ((float4*)out)[(size_t)node * 4 + 2 * q] = o0;
    ((float4*)out)[(size_t)node * 4 + 2 * q + 1] = o1;
}

extern "C" void kernel_launch(void* const* d_in, const int* in_sizes, int n_in,
                              void* d_out, int out_size, void* d_ws, size_t ws_size,
                              hipStream_t stream) {
    const float* x    = (const float*)d_in[0];
    const int*   ei   = (const int*)d_in[1];
    const int*   row  = ei;
    const int*   col  = ei + N_EDGES;
    const float* ln_w = (const float*)d_in[2];
    const float* ln_b = (const float*)d_in[3];
    const float* w0   = (const float*)d_in[4];
    const float* b0   = (const float*)d_in[5];
    const float* w1   = (const float*)d_in[6];
    const float* b1   = (const float*)d_in[7];
    const float* w2   = (const float*)d_in[8];
    const float* b2   = (const float*)d_in[9];
    const float* g1w  = (const float*)d_in[10];
    const float* g1b  = (const float*)d_in[11];
    const float* g2w  = (const float*)d_in[12];
    const float* g2b  = (const float*)d_in[13];
    float* out = (float*)d_out;

    char* W = (char*)d_ws;
    __bf16* h0   = (__bf16*)(W + 0);          // 50000*1024 bf16
    __bf16* h1   = (__bf16*)(W + 102400000);  // 50000*512 bf16
    float*  dis  = (float*) (W + 179200000);  // 50000 f32
    __bf16* xw1b = (__bf16*)(W + 179400192);  // 50000*32 bf16 (dis-scaled)
    __bf16* xw2b = (__bf16*)(W + 185800192);  // 50000*16 bf16 (dis-scaled)
    __bf16* w0t  = (__bf16*)(W + 195400192);  // 512*1024 bf16
    __bf16* w1t  = (__bf16*)(W + 196448768);  // 128*512 bf16
    __bf16* w2t  = (__bf16*)(W + 196579840);  // 64*128 bf16
    unsigned short* csr16 = (unsigned short*)(W + 200000000);  // 3.2M u16
    int*    ptr  = (int*)(W + 213000192);     // 50001 int
    unsigned int* tmp = (unsigned int*)(W + 214000128);  // NB1*CAP u32
    int*    fill196 = (int*)(W + 231000064);  // 196 int (zero-based counts)

    // fill196 <- 0 (p1 reservations are t*CAP + count)
    hipMemsetAsync(fill196, 0, NB1 * sizeof(int), stream);

    // 1. pool+LN (wave per node) + wt prep + p1 bucket scatter side-work
    pool_ln_kernel<<<N_NODES / 4, 256, 0, stream>>>(
        x, ln_w, ln_b, h0, w0, w1, w2, w0t, w1t, w2t, fill196, row, col, tmp);

    // 2. GEMM0 (h0 -> h1, XCD-swizzled) + p2 tail blocks (csr16 + ptr + dis)
    gemm0_p2_kernel<<<G0_BLKS + NB1, 512, 0, stream>>>(
        h0, w0t, b0, h1, N_NODES, tmp, fill196, csr16, ptr, dis);

    // 3. fused MLP tail: h1 -> xw1b  (+ csr16 LLC-warm tail blocks)
    mlp_tail_kernel<<<MT_BLKS + WARM_BLKS, 256, 73728, stream>>>(
        h1, w1t, b1, w2t, b2, g1w, dis, xw1b, N_NODES, csr16);

    // 4. gather1 + GCN1 bias/ELU + GCN2 transform -> xw2b
    gather1_kernel<<<((N_NODES * 4) + 255) / 256, 256, 0, stream>>>(
        (const unsigned short*)xw1b, csr16, ptr, dis, g1b, g2w, xw2b);

    // 5. gather2 -> out (+g2b)
    gather2_kernel<<<((N_NODES * 2) + 255) / 256, 256, 0, stream>>>(
        (const unsigned short*)xw2b, csr16, ptr, dis, g2b, out);
}